// Round 1
// baseline (2755.786 us; speedup 1.0000x reference)
//
#include <hip/hip_runtime.h>
#include <hip/hip_bf16.h>

#define NN 100000
#define EE 1600000

// ---------------- K1: emh = relu(cat(h_feat, e_feat) @ W_trans) ----------------
__global__ __launch_bounds__(256) void trans_k(const float* __restrict__ h_feat,
                                               const float* __restrict__ e_feat,
                                               const float* __restrict__ W_trans,
                                               float* __restrict__ emh) {
    __shared__ float Wl[48 * 32];
    for (int i = threadIdx.x; i < 48 * 32; i += 256) Wl[i] = W_trans[i];
    __syncthreads();
    int t = blockIdx.x * 256 + threadIdx.x;
    if (t >= NN * 32) return;
    int n = t >> 5, j = t & 31;
    const float* hrow = h_feat + (size_t)n * 32;
    const float* erow = e_feat + (size_t)n * 16;
    float acc = 0.f;
#pragma unroll 8
    for (int k = 0; k < 32; ++k) acc = fmaf(hrow[k], Wl[k * 32 + j], acc);
#pragma unroll 8
    for (int k = 0; k < 16; ++k) acc = fmaf(erow[k], Wl[(32 + k) * 32 + j], acc);
    emh[t] = fmaxf(acc, 0.f);
}

// ---------------- K2: first-order edge pass (both edge types merged) ----------------
// 8 threads per edge: all 8 scatter emh (32 feats), first 4 also do grad (16 feats).
__global__ __launch_bounds__(256) void edge_first(const float* __restrict__ emh,
                                                  const float* __restrict__ e_feat,
                                                  const int* __restrict__ src_a,
                                                  const int* __restrict__ dst_a,
                                                  const float* __restrict__ w_a,
                                                  const int* __restrict__ src_b,
                                                  const int* __restrict__ dst_b,
                                                  const float* __restrict__ w_b,
                                                  float* __restrict__ h_acc,
                                                  float* __restrict__ gx,
                                                  float* __restrict__ gy) {
    int t = blockIdx.x * 256 + threadIdx.x;
    const int total = EE * 8;
    const int* src;
    const int* dst;
    const float* wv;
    float* grad;
    if (t >= total) {
        t -= total;
        if (t >= total) return;
        src = src_b; dst = dst_b; wv = w_b; grad = gy;
    } else {
        src = src_a; dst = dst_a; wv = w_a; grad = gx;
    }
    int e = t >> 3, sub = t & 7;
    int s = src[e], d = dst[e];
    const float4 v = *reinterpret_cast<const float4*>(emh + (size_t)s * 32 + sub * 4);
    float* hp = h_acc + (size_t)d * 32 + sub * 4;
    atomicAdd(hp + 0, v.x);
    atomicAdd(hp + 1, v.y);
    atomicAdd(hp + 2, v.z);
    atomicAdd(hp + 3, v.w);
    if (sub < 4) {
        float w = wv[e];
        const float4 es = *reinterpret_cast<const float4*>(e_feat + (size_t)s * 16 + sub * 4);
        const float4 ed = *reinterpret_cast<const float4*>(e_feat + (size_t)d * 16 + sub * 4);
        float* gp = grad + (size_t)d * 16 + sub * 4;
        atomicAdd(gp + 0, w * (es.x - ed.x));
        atomicAdd(gp + 1, w * (es.y - ed.y));
        atomicAdd(gp + 2, w * (es.z - ed.z));
        atomicAdd(gp + 3, w * (es.w - ed.w));
    }
}

// ---------------- K3: second-order edge pass (both edge types merged) ----------------
// 4 threads per edge (16 feats).
__global__ __launch_bounds__(256) void edge_second(const float* __restrict__ gx,
                                                   const float* __restrict__ gy,
                                                   const int* __restrict__ src_a,
                                                   const int* __restrict__ dst_a,
                                                   const float* __restrict__ w_a,
                                                   const int* __restrict__ src_b,
                                                   const int* __restrict__ dst_b,
                                                   const float* __restrict__ w_b,
                                                   float* __restrict__ g2x,
                                                   float* __restrict__ g2y) {
    int t = blockIdx.x * 256 + threadIdx.x;
    const int total = EE * 4;
    const int* src;
    const int* dst;
    const float* wv;
    const float* g;
    float* g2;
    if (t >= total) {
        t -= total;
        if (t >= total) return;
        src = src_b; dst = dst_b; wv = w_b; g = gy; g2 = g2y;
    } else {
        src = src_a; dst = dst_a; wv = w_a; g = gx; g2 = g2x;
    }
    int e = t >> 2, sub = t & 3;
    int s = src[e], d = dst[e];
    float w = wv[e];
    const float4 gs = *reinterpret_cast<const float4*>(g + (size_t)s * 16 + sub * 4);
    const float4 gd = *reinterpret_cast<const float4*>(g + (size_t)d * 16 + sub * 4);
    float* p = g2 + (size_t)d * 16 + sub * 4;
    atomicAdd(p + 0, w * (gs.x - gd.x));
    atomicAdd(p + 1, w * (gs.y - gd.y));
    atomicAdd(p + 2, w * (gs.z - gd.z));
    atomicAdd(p + 3, w * (gs.w - gd.w));
}

// ---------------- K4: fused head ----------------
// h = relu(h_acc)  -> out_h ; h_cat = [h, gx, gy, g2x, g2y] (96)
// rain = rain0 + relu(h_cat @ W_rin) @ W_rout
// One wave per node; lane computes cols (lane, lane+64); wave-reduce for W_rout dot.
__global__ __launch_bounds__(256) void final_k(const float* __restrict__ h_acc,
                                               const float* __restrict__ gx,
                                               const float* __restrict__ gy,
                                               const float* __restrict__ g2x,
                                               const float* __restrict__ g2y,
                                               const float* __restrict__ rain0,
                                               const float* __restrict__ W_rin,
                                               const float* __restrict__ W_rout,
                                               float* __restrict__ out_rain,
                                               float* __restrict__ out_h) {
    __shared__ float Wl[96 * 128];
    __shared__ float Wo[128];
    __shared__ float hc[4][96];
    for (int i = threadIdx.x; i < 96 * 128; i += 256) Wl[i] = W_rin[i];
    if (threadIdx.x < 128) Wo[threadIdx.x] = W_rout[threadIdx.x];
    __syncthreads();
    const int wave = threadIdx.x >> 6;
    const int lane = threadIdx.x & 63;
    for (int base = blockIdx.x * 4; base < NN; base += gridDim.x * 4) {
        int n = base + wave;
        bool valid = n < NN;
        if (valid) {
            if (lane < 32) {
                float v0 = fmaxf(h_acc[(size_t)n * 32 + lane], 0.f);
                out_h[(size_t)n * 32 + lane] = v0;
                hc[wave][lane] = v0;
                float v1 = (lane < 16) ? g2x[(size_t)n * 16 + lane]
                                       : g2y[(size_t)n * 16 + lane - 16];
                hc[wave][64 + lane] = v1;
            } else {
                int l = lane - 32;
                float v = (l < 16) ? gx[(size_t)n * 16 + l]
                                   : gy[(size_t)n * 16 + l - 16];
                hc[wave][lane] = v;
            }
        }
        __syncthreads();
        if (valid) {
            float acc0 = 0.f, acc1 = 0.f;
#pragma unroll 8
            for (int k = 0; k < 96; ++k) {
                float h = hc[wave][k];
                acc0 = fmaf(h, Wl[k * 128 + lane], acc0);
                acc1 = fmaf(h, Wl[k * 128 + 64 + lane], acc1);
            }
            float sum = fmaxf(acc0, 0.f) * Wo[lane] + fmaxf(acc1, 0.f) * Wo[64 + lane];
#pragma unroll
            for (int off = 32; off; off >>= 1) sum += __shfl_down(sum, off);
            if (lane == 0) out_rain[n] = rain0[n] + sum;
        }
        __syncthreads();
    }
}

extern "C" void kernel_launch(void* const* d_in, const int* in_sizes, int n_in,
                              void* d_out, int out_size, void* d_ws, size_t ws_size,
                              hipStream_t stream) {
    const float* h_feat  = (const float*)d_in[0];
    const float* e_feat  = (const float*)d_in[1];
    const float* rain0   = (const float*)d_in[2];
    const float* w_xx    = (const float*)d_in[3];
    const float* w_yy    = (const float*)d_in[4];
    const float* W_trans = (const float*)d_in[5];
    const float* W_rin   = (const float*)d_in[6];
    const float* W_rout  = (const float*)d_in[7];
    const int* src_xx    = (const int*)d_in[8];
    const int* dst_xx    = (const int*)d_in[9];
    const int* src_yy    = (const int*)d_in[10];
    const int* dst_yy    = (const int*)d_in[11];

    float* ws   = (float*)d_ws;
    float* emh   = ws;                         // N*32
    float* h_acc = emh + (size_t)NN * 32;      // N*32
    float* gx    = h_acc + (size_t)NN * 32;    // N*16
    float* gy    = gx + (size_t)NN * 16;       // N*16
    float* g2x   = gy + (size_t)NN * 16;       // N*16
    float* g2y   = g2x + (size_t)NN * 16;      // N*16

    float* out_rain = (float*)d_out;           // N
    float* out_h    = out_rain + NN;           // N*32

    // zero all accumulators (h_acc..g2y contiguous, N*96 floats)
    hipMemsetAsync(h_acc, 0, (size_t)NN * 96 * sizeof(float), stream);

    trans_k<<<(NN * 32 + 255) / 256, 256, 0, stream>>>(h_feat, e_feat, W_trans, emh);

    edge_first<<<(2 * EE * 8 + 255) / 256, 256, 0, stream>>>(
        emh, e_feat, src_xx, dst_xx, w_xx, src_yy, dst_yy, w_yy, h_acc, gx, gy);

    edge_second<<<(2 * EE * 4 + 255) / 256, 256, 0, stream>>>(
        gx, gy, src_xx, dst_xx, w_xx, src_yy, dst_yy, w_yy, g2x, g2y);

    final_k<<<1024, 256, 0, stream>>>(h_acc, gx, gy, g2x, g2y, rain0, W_rin, W_rout,
                                      out_rain, out_h);
}

// Round 2
// 1244.146 us; speedup vs baseline: 2.2150x; 2.2150x over previous
//
#include <hip/hip_runtime.h>
#include <hip/hip_bf16.h>

#define NN 100000
#define EE 1600000

// ---------------- K1: emh = relu(cat(h_feat, e_feat) @ W_trans) ----------------
__global__ __launch_bounds__(256) void trans_k(const float* __restrict__ h_feat,
                                               const float* __restrict__ e_feat,
                                               const float* __restrict__ W_trans,
                                               float* __restrict__ emh) {
    __shared__ float Wl[48 * 32];
    for (int i = threadIdx.x; i < 48 * 32; i += 256) Wl[i] = W_trans[i];
    __syncthreads();
    int t = blockIdx.x * 256 + threadIdx.x;
    if (t >= NN * 32) return;
    int n = t >> 5, j = t & 31;
    const float* hrow = h_feat + (size_t)n * 32;
    const float* erow = e_feat + (size_t)n * 16;
    float acc = 0.f;
#pragma unroll 8
    for (int k = 0; k < 32; ++k) acc = fmaf(hrow[k], Wl[k * 32 + j], acc);
#pragma unroll 8
    for (int k = 0; k < 16; ++k) acc = fmaf(erow[k], Wl[(32 + k) * 32 + j], acc);
    emh[t] = fmaxf(acc, 0.f);
}

// ---------------- CSR build: histogram ----------------
__global__ __launch_bounds__(256) void hist_k(const int* __restrict__ dst_a,
                                              const int* __restrict__ dst_b,
                                              int* __restrict__ cur_a,
                                              int* __restrict__ cur_b) {
    int t = blockIdx.x * 256 + threadIdx.x;
    if (t < EE) {
        atomicAdd(&cur_a[dst_a[t]], 1);
    } else if (t < 2 * EE) {
        atomicAdd(&cur_b[dst_b[t - EE]], 1);
    }
}

// ---------------- CSR build: single-block exclusive scan ----------------
// deg_cur holds degrees on entry; on exit both off[] and deg_cur[] hold the
// exclusive prefix (deg_cur becomes the scatter cursor). off[n] = total.
__global__ __launch_bounds__(1024) void scan_k(int* __restrict__ deg_cur,
                                               int* __restrict__ off, int n) {
    __shared__ int wsum[16];
    __shared__ int running_s;
    const int t = threadIdx.x;
    const int lane = t & 63;
    const int w = t >> 6;
    if (t == 0) running_s = 0;
    __syncthreads();
    for (int base = 0; base < n; base += 1024) {
        int runbase = running_s;
        int i = base + t;
        int v = (i < n) ? deg_cur[i] : 0;
        int incl = v;
#pragma unroll
        for (int d = 1; d < 64; d <<= 1) {
            int x = __shfl_up(incl, d);
            if (lane >= d) incl += x;
        }
        if (lane == 63) wsum[w] = incl;
        __syncthreads();
        if (t == 0) {
            int s = 0;
#pragma unroll
            for (int q = 0; q < 16; ++q) { int x = wsum[q]; wsum[q] = s; s += x; }
            running_s = runbase + s;
        }
        __syncthreads();
        int excl = runbase + wsum[w] + incl - v;
        if (i < n) { off[i] = excl; deg_cur[i] = excl; }
        __syncthreads();
    }
    if (t == 0) off[n] = running_s;
}

// ---------------- CSR build: scatter edge ids ----------------
__global__ __launch_bounds__(256) void scatter_k(const int* __restrict__ dst_a,
                                                 const int* __restrict__ dst_b,
                                                 int* __restrict__ cur_a,
                                                 int* __restrict__ cur_b,
                                                 int* __restrict__ perm_a,
                                                 int* __restrict__ perm_b) {
    int t = blockIdx.x * 256 + threadIdx.x;
    if (t < EE) {
        int p = atomicAdd(&cur_a[dst_a[t]], 1);
        perm_a[p] = t;
    } else if (t < 2 * EE) {
        int e = t - EE;
        int p = atomicAdd(&cur_b[dst_b[e]], 1);
        perm_b[p] = e;
    }
}

// ---------------- Pull pass 1: h, gx, gy (no atomics) ----------------
// 32 lanes per node. Lane j accumulates feature j across incoming edges.
__global__ __launch_bounds__(256) void pull1_k(const float* __restrict__ emh,
                                               const float* __restrict__ e_feat,
                                               const int* __restrict__ src_a,
                                               const float* __restrict__ w_a,
                                               const int* __restrict__ perm_a,
                                               const int* __restrict__ off_a,
                                               const int* __restrict__ src_b,
                                               const float* __restrict__ w_b,
                                               const int* __restrict__ perm_b,
                                               const int* __restrict__ off_b,
                                               float* __restrict__ out_h,
                                               float* __restrict__ gx,
                                               float* __restrict__ gy) {
    int g = blockIdx.x * 256 + threadIdx.x;
    int n = g >> 5;
    int j = g & 31;
    if (n >= NN) return;
    float acc_h = 0.f, acc_g = 0.f, sumw = 0.f;
    int b = off_a[n], e2 = off_a[n + 1];
    for (int k = b; k < e2; ++k) {
        int e = perm_a[k];
        int s = src_a[e];
        acc_h += emh[(size_t)s * 32 + j];
        if (j < 16) {
            float w = w_a[e];
            acc_g = fmaf(w, e_feat[(size_t)s * 16 + j], acc_g);
            sumw += w;
        }
    }
    if (j < 16) gx[(size_t)n * 16 + j] = acc_g - sumw * e_feat[(size_t)n * 16 + j];
    acc_g = 0.f; sumw = 0.f;
    b = off_b[n]; e2 = off_b[n + 1];
    for (int k = b; k < e2; ++k) {
        int e = perm_b[k];
        int s = src_b[e];
        acc_h += emh[(size_t)s * 32 + j];
        if (j < 16) {
            float w = w_b[e];
            acc_g = fmaf(w, e_feat[(size_t)s * 16 + j], acc_g);
            sumw += w;
        }
    }
    if (j < 16) gy[(size_t)n * 16 + j] = acc_g - sumw * e_feat[(size_t)n * 16 + j];
    out_h[(size_t)n * 32 + j] = fmaxf(acc_h, 0.f);
}

// ---------------- Pull pass 2: g2x, g2y (no atomics) ----------------
// 16 lanes per node.
__global__ __launch_bounds__(256) void pull2_k(const float* __restrict__ gx,
                                               const float* __restrict__ gy,
                                               const int* __restrict__ src_a,
                                               const float* __restrict__ w_a,
                                               const int* __restrict__ perm_a,
                                               const int* __restrict__ off_a,
                                               const int* __restrict__ src_b,
                                               const float* __restrict__ w_b,
                                               const int* __restrict__ perm_b,
                                               const int* __restrict__ off_b,
                                               float* __restrict__ g2x,
                                               float* __restrict__ g2y) {
    int g = blockIdx.x * 256 + threadIdx.x;
    int n = g >> 4;
    int j = g & 15;
    if (n >= NN) return;
    float acc = 0.f, sumw = 0.f;
    int b = off_a[n], e2 = off_a[n + 1];
    for (int k = b; k < e2; ++k) {
        int e = perm_a[k];
        int s = src_a[e];
        float w = w_a[e];
        acc = fmaf(w, gx[(size_t)s * 16 + j], acc);
        sumw += w;
    }
    g2x[(size_t)n * 16 + j] = acc - sumw * gx[(size_t)n * 16 + j];
    acc = 0.f; sumw = 0.f;
    b = off_b[n]; e2 = off_b[n + 1];
    for (int k = b; k < e2; ++k) {
        int e = perm_b[k];
        int s = src_b[e];
        float w = w_b[e];
        acc = fmaf(w, gy[(size_t)s * 16 + j], acc);
        sumw += w;
    }
    g2y[(size_t)n * 16 + j] = acc - sumw * gy[(size_t)n * 16 + j];
}

// ---------------- K4: fused head ----------------
__global__ __launch_bounds__(256) void final_k(const float* __restrict__ h,
                                               const float* __restrict__ gx,
                                               const float* __restrict__ gy,
                                               const float* __restrict__ g2x,
                                               const float* __restrict__ g2y,
                                               const float* __restrict__ rain0,
                                               const float* __restrict__ W_rin,
                                               const float* __restrict__ W_rout,
                                               float* __restrict__ out_rain) {
    __shared__ float Wl[96 * 128];
    __shared__ float Wo[128];
    __shared__ float hc[4][96];
    for (int i = threadIdx.x; i < 96 * 128; i += 256) Wl[i] = W_rin[i];
    if (threadIdx.x < 128) Wo[threadIdx.x] = W_rout[threadIdx.x];
    __syncthreads();
    const int wave = threadIdx.x >> 6;
    const int lane = threadIdx.x & 63;
    for (int base = blockIdx.x * 4; base < NN; base += gridDim.x * 4) {
        int n = base + wave;
        bool valid = n < NN;
        if (valid) {
            if (lane < 32) {
                hc[wave][lane] = h[(size_t)n * 32 + lane];
                float v1 = (lane < 16) ? g2x[(size_t)n * 16 + lane]
                                       : g2y[(size_t)n * 16 + lane - 16];
                hc[wave][64 + lane] = v1;
            } else {
                int l = lane - 32;
                float v = (l < 16) ? gx[(size_t)n * 16 + l]
                                   : gy[(size_t)n * 16 + l - 16];
                hc[wave][lane] = v;
            }
        }
        __syncthreads();
        if (valid) {
            float acc0 = 0.f, acc1 = 0.f;
#pragma unroll 8
            for (int k = 0; k < 96; ++k) {
                float hv = hc[wave][k];
                acc0 = fmaf(hv, Wl[k * 128 + lane], acc0);
                acc1 = fmaf(hv, Wl[k * 128 + 64 + lane], acc1);
            }
            float sum = fmaxf(acc0, 0.f) * Wo[lane] + fmaxf(acc1, 0.f) * Wo[64 + lane];
#pragma unroll
            for (int off = 32; off; off >>= 1) sum += __shfl_down(sum, off);
            if (lane == 0) out_rain[n] = rain0[n] + sum;
        }
        __syncthreads();
    }
}

extern "C" void kernel_launch(void* const* d_in, const int* in_sizes, int n_in,
                              void* d_out, int out_size, void* d_ws, size_t ws_size,
                              hipStream_t stream) {
    const float* h_feat  = (const float*)d_in[0];
    const float* e_feat  = (const float*)d_in[1];
    const float* rain0   = (const float*)d_in[2];
    const float* w_xx    = (const float*)d_in[3];
    const float* w_yy    = (const float*)d_in[4];
    const float* W_trans = (const float*)d_in[5];
    const float* W_rin   = (const float*)d_in[6];
    const float* W_rout  = (const float*)d_in[7];
    const int* src_xx    = (const int*)d_in[8];
    const int* dst_xx    = (const int*)d_in[9];
    const int* src_yy    = (const int*)d_in[10];
    const int* dst_yy    = (const int*)d_in[11];

    float* ws = (float*)d_ws;
    // float region
    float* emh = ws;                          // N*32   (reused as g2x/g2y later)
    float* gx  = ws + (size_t)NN * 32;        // N*16
    float* gy  = gx + (size_t)NN * 16;        // N*16
    float* g2x = emh;                         // alias: emh dead after pull1
    float* g2y = emh + (size_t)NN * 16;
    // int region
    int* perm_xx = (int*)(ws + (size_t)NN * 64);   // E
    int* perm_yy = perm_xx + EE;                   // E
    int* off_xx  = perm_yy + EE;                   // N+1
    int* off_yy  = off_xx + (NN + 1);              // N+1
    int* cur_xx  = off_yy + (NN + 1);              // N
    int* cur_yy  = cur_xx + NN;                    // N

    float* out_rain = (float*)d_out;          // N
    float* out_h    = out_rain + NN;          // N*32

    // zero degree counters (cur_xx, cur_yy contiguous)
    hipMemsetAsync(cur_xx, 0, (size_t)2 * NN * sizeof(int), stream);

    trans_k<<<(NN * 32 + 255) / 256, 256, 0, stream>>>(h_feat, e_feat, W_trans, emh);

    hist_k<<<(2 * EE + 255) / 256, 256, 0, stream>>>(dst_xx, dst_yy, cur_xx, cur_yy);
    scan_k<<<1, 1024, 0, stream>>>(cur_xx, off_xx, NN);
    scan_k<<<1, 1024, 0, stream>>>(cur_yy, off_yy, NN);
    scatter_k<<<(2 * EE + 255) / 256, 256, 0, stream>>>(dst_xx, dst_yy, cur_xx, cur_yy,
                                                        perm_xx, perm_yy);

    pull1_k<<<(NN * 32 + 255) / 256, 256, 0, stream>>>(
        emh, e_feat, src_xx, w_xx, perm_xx, off_xx, src_yy, w_yy, perm_yy, off_yy,
        out_h, gx, gy);

    pull2_k<<<(NN * 16 + 255) / 256, 256, 0, stream>>>(
        gx, gy, src_xx, w_xx, perm_xx, off_xx, src_yy, w_yy, perm_yy, off_yy,
        g2x, g2y);

    final_k<<<1024, 256, 0, stream>>>(out_h, gx, gy, g2x, g2y, rain0, W_rin, W_rout,
                                      out_rain);
}

// Round 3
// 766.457 us; speedup vs baseline: 3.5955x; 1.6232x over previous
//
#include <hip/hip_runtime.h>
#include <hip/hip_bf16.h>

#define NN 100000
#define EE 1600000
#define SCAN_CHUNK 4096
#define NB ((NN + SCAN_CHUNK - 1) / SCAN_CHUNK)   // 25 blocks per array
#define OFFP (NN + 8)                             // padded off array (alignment)

// ---------------- fused: emh = relu(cat(h,e)@W) in blocks [0,TB); hist in [TB,..) ----
__global__ __launch_bounds__(256) void fused_th_k(const float* __restrict__ h_feat,
                                                  const float* __restrict__ e_feat,
                                                  const float* __restrict__ W_trans,
                                                  float* __restrict__ emh,
                                                  const int* __restrict__ dst_a,
                                                  const int* __restrict__ dst_b,
                                                  int* __restrict__ cur_a,
                                                  int* __restrict__ cur_b, int TB) {
    __shared__ float Wl[48 * 32];
    if ((int)blockIdx.x < TB) {
        for (int i = threadIdx.x; i < 48 * 32; i += 256) Wl[i] = W_trans[i];
        __syncthreads();
        int t = blockIdx.x * 256 + threadIdx.x;
        if (t >= NN * 32) return;
        int n = t >> 5, j = t & 31;
        const float* hrow = h_feat + (size_t)n * 32;
        const float* erow = e_feat + (size_t)n * 16;
        float acc = 0.f;
#pragma unroll 8
        for (int k = 0; k < 32; ++k) acc = fmaf(hrow[k], Wl[k * 32 + j], acc);
#pragma unroll 8
        for (int k = 0; k < 16; ++k) acc = fmaf(erow[k], Wl[(32 + k) * 32 + j], acc);
        emh[t] = fmaxf(acc, 0.f);
    } else {
        int t = (blockIdx.x - TB) * 256 + threadIdx.x;
        if (t < EE) {
            atomicAdd(&cur_a[dst_a[t]], 1);
        } else {
            t -= EE;
            if (t < EE) atomicAdd(&cur_b[dst_b[t]], 1);
        }
    }
}

// ---------------- scan phase A: per-block (4096-chunk) totals ----------------
__global__ __launch_bounds__(1024) void scanA_k(const int* __restrict__ cur_a,
                                                const int* __restrict__ cur_b,
                                                int* __restrict__ bsum) {
    __shared__ int wsum[16];
    int b = blockIdx.x;
    const int* arr = (b < NB) ? cur_a : cur_b;
    int i = (b % NB) * SCAN_CHUNK + threadIdx.x * 4;
    int4 v = make_int4(0, 0, 0, 0);
    if (i + 3 < NN) {
        v = *reinterpret_cast<const int4*>(arr + i);
    } else {
        if (i < NN) v.x = arr[i];
        if (i + 1 < NN) v.y = arr[i + 1];
        if (i + 2 < NN) v.z = arr[i + 2];
    }
    int tot = v.x + v.y + v.z + v.w;
#pragma unroll
    for (int d = 32; d; d >>= 1) tot += __shfl_down(tot, d);
    int lane = threadIdx.x & 63, w = threadIdx.x >> 6;
    if (lane == 0) wsum[w] = tot;
    __syncthreads();
    if (threadIdx.x == 0) {
        int s = 0;
#pragma unroll
        for (int q = 0; q < 16; ++q) s += wsum[q];
        bsum[b] = s;
    }
}

// ---------------- scan phase B: segmented exclusive scan of 2*NB block sums ------
__global__ __launch_bounds__(64) void scanB_k(const int* __restrict__ bsum,
                                              int* __restrict__ bbase,
                                              int* __restrict__ off_a,
                                              int* __restrict__ off_b) {
    int lane = threadIdx.x;
    int v = (lane < 2 * NB) ? bsum[lane] : 0;
    int seg = lane / NB;
    int inc = v;
#pragma unroll
    for (int d = 1; d < 64; d <<= 1) {
        int x = __shfl_up(inc, d);
        if (lane >= d && (lane - d) / NB == seg) inc += x;
    }
    int excl = inc - v;
    if (lane < 2 * NB) bbase[lane] = excl;
    if (lane == NB - 1) off_a[NN] = inc;
    if (lane == 2 * NB - 1) off_b[NN] = inc;
}

// ---------------- scan phase C: full exclusive scan, writes off[] and cur[] ------
__global__ __launch_bounds__(1024) void scanC_k(int* __restrict__ cur_a,
                                                int* __restrict__ cur_b,
                                                int* __restrict__ off_a,
                                                int* __restrict__ off_b,
                                                const int* __restrict__ bbase) {
    __shared__ int wsum[16];
    int b = blockIdx.x;
    int* cur = (b < NB) ? cur_a : cur_b;
    int* off = (b < NB) ? off_a : off_b;
    int base0 = bbase[b];
    int i = (b % NB) * SCAN_CHUNK + threadIdx.x * 4;
    int4 v = make_int4(0, 0, 0, 0);
    if (i + 3 < NN) {
        v = *reinterpret_cast<const int4*>(cur + i);
    } else {
        if (i < NN) v.x = cur[i];
        if (i + 1 < NN) v.y = cur[i + 1];
        if (i + 2 < NN) v.z = cur[i + 2];
    }
    int s1 = v.x, s2 = s1 + v.y, s3 = s2 + v.z, tot = s3 + v.w;
    int lane = threadIdx.x & 63, w = threadIdx.x >> 6;
    int inc = tot;
#pragma unroll
    for (int d = 1; d < 64; d <<= 1) {
        int x = __shfl_up(inc, d);
        if (lane >= d) inc += x;
    }
    if (lane == 63) wsum[w] = inc;
    int texcl = inc - tot;
    __syncthreads();
    if (threadIdx.x == 0) {
        int r = 0;
#pragma unroll
        for (int q = 0; q < 16; ++q) { int x = wsum[q]; wsum[q] = r; r += x; }
    }
    __syncthreads();
    int base = base0 + wsum[w] + texcl;
    if (i < NN)     { off[i] = base;          cur[i] = base; }
    if (i + 1 < NN) { off[i + 1] = base + s1; cur[i + 1] = base + s1; }
    if (i + 2 < NN) { off[i + 2] = base + s2; cur[i + 2] = base + s2; }
    if (i + 3 < NN) { off[i + 3] = base + s3; cur[i + 3] = base + s3; }
}

// ---------------- scatter: CSR-ordered packed (src, w) ----------------
__global__ __launch_bounds__(256) void scatter_k(const int* __restrict__ dst_a,
                                                 const int* __restrict__ src_a,
                                                 const float* __restrict__ w_a,
                                                 const int* __restrict__ dst_b,
                                                 const int* __restrict__ src_b,
                                                 const float* __restrict__ w_b,
                                                 int* __restrict__ cur_a,
                                                 int* __restrict__ cur_b,
                                                 int2* __restrict__ csr_a,
                                                 int2* __restrict__ csr_b) {
    int t = blockIdx.x * 256 + threadIdx.x;
    if (t < EE) {
        int p = atomicAdd(&cur_a[dst_a[t]], 1);
        csr_a[p] = make_int2(src_a[t], __float_as_int(w_a[t]));
    } else if (t < 2 * EE) {
        int e = t - EE;
        int p = atomicAdd(&cur_b[dst_b[e]], 1);
        csr_b[p] = make_int2(src_b[e], __float_as_int(w_b[e]));
    }
}

// ---------------- pull1: h, gx, gy (32 lanes/node, no atomics) ----------------
__global__ __launch_bounds__(256) void pull1_k(const float* __restrict__ emh,
                                               const float* __restrict__ e_feat,
                                               const int2* __restrict__ csr_a,
                                               const int* __restrict__ off_a,
                                               const int2* __restrict__ csr_b,
                                               const int* __restrict__ off_b,
                                               float* __restrict__ out_h,
                                               float* __restrict__ gx,
                                               float* __restrict__ gy) {
    int g = blockIdx.x * 256 + threadIdx.x;
    int n = g >> 5, j = g & 31;
    if (n >= NN) return;
    float acc_h = 0.f;

    float acc_g = 0.f, sumw = 0.f;
    int k = off_a[n], e2 = off_a[n + 1];
    for (; k + 1 < e2; k += 2) {
        int2 s0 = csr_a[k], s1 = csr_a[k + 1];
        float m0 = emh[(size_t)s0.x * 32 + j];
        float m1 = emh[(size_t)s1.x * 32 + j];
        acc_h += m0 + m1;
        if (j < 16) {
            float w0 = __int_as_float(s0.y), w1 = __int_as_float(s1.y);
            acc_g = fmaf(w0, e_feat[(size_t)s0.x * 16 + j], acc_g);
            acc_g = fmaf(w1, e_feat[(size_t)s1.x * 16 + j], acc_g);
            sumw += w0 + w1;
        }
    }
    if (k < e2) {
        int2 s0 = csr_a[k];
        acc_h += emh[(size_t)s0.x * 32 + j];
        if (j < 16) {
            float w0 = __int_as_float(s0.y);
            acc_g = fmaf(w0, e_feat[(size_t)s0.x * 16 + j], acc_g);
            sumw += w0;
        }
    }
    if (j < 16) gx[(size_t)n * 16 + j] = acc_g - sumw * e_feat[(size_t)n * 16 + j];

    acc_g = 0.f; sumw = 0.f;
    k = off_b[n]; e2 = off_b[n + 1];
    for (; k + 1 < e2; k += 2) {
        int2 s0 = csr_b[k], s1 = csr_b[k + 1];
        float m0 = emh[(size_t)s0.x * 32 + j];
        float m1 = emh[(size_t)s1.x * 32 + j];
        acc_h += m0 + m1;
        if (j < 16) {
            float w0 = __int_as_float(s0.y), w1 = __int_as_float(s1.y);
            acc_g = fmaf(w0, e_feat[(size_t)s0.x * 16 + j], acc_g);
            acc_g = fmaf(w1, e_feat[(size_t)s1.x * 16 + j], acc_g);
            sumw += w0 + w1;
        }
    }
    if (k < e2) {
        int2 s0 = csr_b[k];
        acc_h += emh[(size_t)s0.x * 32 + j];
        if (j < 16) {
            float w0 = __int_as_float(s0.y);
            acc_g = fmaf(w0, e_feat[(size_t)s0.x * 16 + j], acc_g);
            sumw += w0;
        }
    }
    if (j < 16) gy[(size_t)n * 16 + j] = acc_g - sumw * e_feat[(size_t)n * 16 + j];

    out_h[(size_t)n * 32 + j] = fmaxf(acc_h, 0.f);
}

// ---------------- pull2: g2x, g2y (16 lanes/node) ----------------
__global__ __launch_bounds__(256) void pull2_k(const float* __restrict__ gx,
                                               const float* __restrict__ gy,
                                               const int2* __restrict__ csr_a,
                                               const int* __restrict__ off_a,
                                               const int2* __restrict__ csr_b,
                                               const int* __restrict__ off_b,
                                               float* __restrict__ g2x,
                                               float* __restrict__ g2y) {
    int g = blockIdx.x * 256 + threadIdx.x;
    int n = g >> 4, j = g & 15;
    if (n >= NN) return;

    float acc = 0.f, sumw = 0.f;
    int k = off_a[n], e2 = off_a[n + 1];
    for (; k + 1 < e2; k += 2) {
        int2 s0 = csr_a[k], s1 = csr_a[k + 1];
        float w0 = __int_as_float(s0.y), w1 = __int_as_float(s1.y);
        acc = fmaf(w0, gx[(size_t)s0.x * 16 + j], acc);
        acc = fmaf(w1, gx[(size_t)s1.x * 16 + j], acc);
        sumw += w0 + w1;
    }
    if (k < e2) {
        int2 s0 = csr_a[k];
        float w0 = __int_as_float(s0.y);
        acc = fmaf(w0, gx[(size_t)s0.x * 16 + j], acc);
        sumw += w0;
    }
    g2x[(size_t)n * 16 + j] = acc - sumw * gx[(size_t)n * 16 + j];

    acc = 0.f; sumw = 0.f;
    k = off_b[n]; e2 = off_b[n + 1];
    for (; k + 1 < e2; k += 2) {
        int2 s0 = csr_b[k], s1 = csr_b[k + 1];
        float w0 = __int_as_float(s0.y), w1 = __int_as_float(s1.y);
        acc = fmaf(w0, gy[(size_t)s0.x * 16 + j], acc);
        acc = fmaf(w1, gy[(size_t)s1.x * 16 + j], acc);
        sumw += w0 + w1;
    }
    if (k < e2) {
        int2 s0 = csr_b[k];
        float w0 = __int_as_float(s0.y);
        acc = fmaf(w0, gy[(size_t)s0.x * 16 + j], acc);
        sumw += w0;
    }
    g2y[(size_t)n * 16 + j] = acc - sumw * gy[(size_t)n * 16 + j];
}

// ---------------- final head ----------------
__global__ __launch_bounds__(256) void final_k(const float* __restrict__ h,
                                               const float* __restrict__ gx,
                                               const float* __restrict__ gy,
                                               const float* __restrict__ g2x,
                                               const float* __restrict__ g2y,
                                               const float* __restrict__ rain0,
                                               const float* __restrict__ W_rin,
                                               const float* __restrict__ W_rout,
                                               float* __restrict__ out_rain) {
    __shared__ float Wl[96 * 128];
    __shared__ float Wo[128];
    __shared__ float hc[4][96];
    for (int i = threadIdx.x; i < 96 * 128; i += 256) Wl[i] = W_rin[i];
    if (threadIdx.x < 128) Wo[threadIdx.x] = W_rout[threadIdx.x];
    __syncthreads();
    const int wave = threadIdx.x >> 6;
    const int lane = threadIdx.x & 63;
    for (int base = blockIdx.x * 4; base < NN; base += gridDim.x * 4) {
        int n = base + wave;
        bool valid = n < NN;
        if (valid) {
            if (lane < 32) {
                hc[wave][lane] = h[(size_t)n * 32 + lane];
                float v1 = (lane < 16) ? g2x[(size_t)n * 16 + lane]
                                       : g2y[(size_t)n * 16 + lane - 16];
                hc[wave][64 + lane] = v1;
            } else {
                int l = lane - 32;
                float v = (l < 16) ? gx[(size_t)n * 16 + l]
                                   : gy[(size_t)n * 16 + l - 16];
                hc[wave][lane] = v;
            }
        }
        __syncthreads();
        if (valid) {
            float acc0 = 0.f, acc1 = 0.f;
#pragma unroll 8
            for (int k = 0; k < 96; ++k) {
                float hv = hc[wave][k];
                acc0 = fmaf(hv, Wl[k * 128 + lane], acc0);
                acc1 = fmaf(hv, Wl[k * 128 + 64 + lane], acc1);
            }
            float sum = fmaxf(acc0, 0.f) * Wo[lane] + fmaxf(acc1, 0.f) * Wo[64 + lane];
#pragma unroll
            for (int off = 32; off; off >>= 1) sum += __shfl_down(sum, off);
            if (lane == 0) out_rain[n] = rain0[n] + sum;
        }
        __syncthreads();
    }
}

extern "C" void kernel_launch(void* const* d_in, const int* in_sizes, int n_in,
                              void* d_out, int out_size, void* d_ws, size_t ws_size,
                              hipStream_t stream) {
    const float* h_feat  = (const float*)d_in[0];
    const float* e_feat  = (const float*)d_in[1];
    const float* rain0   = (const float*)d_in[2];
    const float* w_xx    = (const float*)d_in[3];
    const float* w_yy    = (const float*)d_in[4];
    const float* W_trans = (const float*)d_in[5];
    const float* W_rin   = (const float*)d_in[6];
    const float* W_rout  = (const float*)d_in[7];
    const int* src_xx    = (const int*)d_in[8];
    const int* dst_xx    = (const int*)d_in[9];
    const int* src_yy    = (const int*)d_in[10];
    const int* dst_yy    = (const int*)d_in[11];

    float* ws = (float*)d_ws;
    float* emh = ws;                           // NN*32 floats (reused as g2x/g2y)
    float* gx  = emh + (size_t)NN * 32;        // NN*16
    float* gy  = gx + (size_t)NN * 16;         // NN*16
    float* g2x = emh;                          // alias (emh dead after pull1)
    float* g2y = emh + (size_t)NN * 16;

    int2* csr_xx = (int2*)(gy + (size_t)NN * 16);  // EE int2 (8B-aligned: 25.6MB offset)
    int2* csr_yy = csr_xx + EE;                    // EE int2
    int* off_xx  = (int*)(csr_yy + EE);            // OFFP ints
    int* off_yy  = off_xx + OFFP;                  // OFFP ints
    int* cur_xx  = off_yy + OFFP;                  // NN ints (16B-aligned)
    int* cur_yy  = cur_xx + NN;                    // NN ints
    int* bsum    = cur_yy + NN;                    // 64
    int* bbase   = bsum + 64;                      // 64

    float* out_rain = (float*)d_out;           // NN
    float* out_h    = out_rain + NN;           // NN*32

    hipMemsetAsync(cur_xx, 0, (size_t)2 * NN * sizeof(int), stream);

    const int TB = (NN * 32 + 255) / 256;      // 12500 trans blocks
    const int HB = (2 * EE + 255) / 256;       // 12500 hist blocks
    fused_th_k<<<TB + HB, 256, 0, stream>>>(h_feat, e_feat, W_trans, emh,
                                            dst_xx, dst_yy, cur_xx, cur_yy, TB);

    scanA_k<<<2 * NB, 1024, 0, stream>>>(cur_xx, cur_yy, bsum);
    scanB_k<<<1, 64, 0, stream>>>(bsum, bbase, off_xx, off_yy);
    scanC_k<<<2 * NB, 1024, 0, stream>>>(cur_xx, cur_yy, off_xx, off_yy, bbase);

    scatter_k<<<(2 * EE + 255) / 256, 256, 0, stream>>>(
        dst_xx, src_xx, w_xx, dst_yy, src_yy, w_yy, cur_xx, cur_yy, csr_xx, csr_yy);

    pull1_k<<<(NN * 32 + 255) / 256, 256, 0, stream>>>(
        emh, e_feat, csr_xx, off_xx, csr_yy, off_yy, out_h, gx, gy);

    pull2_k<<<(NN * 16 + 255) / 256, 256, 0, stream>>>(
        gx, gy, csr_xx, off_xx, csr_yy, off_yy, g2x, g2y);

    final_k<<<1024, 256, 0, stream>>>(out_h, gx, gy, g2x, g2y, rain0, W_rin, W_rout,
                                      out_rain);
}

// Round 4
// 720.220 us; speedup vs baseline: 3.8263x; 1.0642x over previous
//
#include <hip/hip_runtime.h>
#include <hip/hip_bf16.h>

#define NN 100000
#define EE 1600000
#define SCAN_CHUNK 4096
#define NB ((NN + SCAN_CHUNK - 1) / SCAN_CHUNK)   // 25 blocks per array
#define OFFP (NN + 8)                             // padded off array (alignment)
#define EPT 8                                     // edges per thread (hist/scatter)

// ---------------- fused: emh = relu(cat(h,e)@W) in blocks [0,TB); hist in [TB,..) ----
__global__ __launch_bounds__(256) void fused_th_k(const float* __restrict__ h_feat,
                                                  const float* __restrict__ e_feat,
                                                  const float* __restrict__ W_trans,
                                                  float* __restrict__ emh,
                                                  const int* __restrict__ dst_a,
                                                  const int* __restrict__ dst_b,
                                                  int* __restrict__ cur_a,
                                                  int* __restrict__ cur_b, int TB) {
    __shared__ float Wl[48 * 32];
    if ((int)blockIdx.x < TB) {
        for (int i = threadIdx.x; i < 48 * 32; i += 256) Wl[i] = W_trans[i];
        __syncthreads();
        int t = blockIdx.x * 256 + threadIdx.x;
        if (t >= NN * 32) return;
        int n = t >> 5, j = t & 31;
        const float* hrow = h_feat + (size_t)n * 32;
        const float* erow = e_feat + (size_t)n * 16;
        float acc = 0.f;
#pragma unroll 8
        for (int k = 0; k < 32; ++k) acc = fmaf(hrow[k], Wl[k * 32 + j], acc);
#pragma unroll 8
        for (int k = 0; k < 16; ++k) acc = fmaf(erow[k], Wl[(32 + k) * 32 + j], acc);
        emh[t] = fmaxf(acc, 0.f);
    } else {
        long t0 = ((long)(blockIdx.x - TB) * 256 + threadIdx.x) * EPT;
        const int* dst;
        int* cur;
        if (t0 < EE) {
            dst = dst_a; cur = cur_a;
        } else {
            t0 -= EE;
            if (t0 >= EE) return;
            dst = dst_b; cur = cur_b;
        }
        int4 d0 = *reinterpret_cast<const int4*>(dst + t0);
        int4 d1 = *reinterpret_cast<const int4*>(dst + t0 + 4);
        atomicAdd(&cur[d0.x], 1); atomicAdd(&cur[d0.y], 1);
        atomicAdd(&cur[d0.z], 1); atomicAdd(&cur[d0.w], 1);
        atomicAdd(&cur[d1.x], 1); atomicAdd(&cur[d1.y], 1);
        atomicAdd(&cur[d1.z], 1); atomicAdd(&cur[d1.w], 1);
    }
}

// ---------------- scan phase A: per-block (4096-chunk) totals ----------------
__global__ __launch_bounds__(1024) void scanA_k(const int* __restrict__ cur_a,
                                                const int* __restrict__ cur_b,
                                                int* __restrict__ bsum) {
    __shared__ int wsum[16];
    int b = blockIdx.x;
    const int* arr = (b < NB) ? cur_a : cur_b;
    int i = (b % NB) * SCAN_CHUNK + threadIdx.x * 4;
    int4 v = make_int4(0, 0, 0, 0);
    if (i + 3 < NN) {
        v = *reinterpret_cast<const int4*>(arr + i);
    } else {
        if (i < NN) v.x = arr[i];
        if (i + 1 < NN) v.y = arr[i + 1];
        if (i + 2 < NN) v.z = arr[i + 2];
    }
    int tot = v.x + v.y + v.z + v.w;
#pragma unroll
    for (int d = 32; d; d >>= 1) tot += __shfl_down(tot, d);
    int lane = threadIdx.x & 63, w = threadIdx.x >> 6;
    if (lane == 0) wsum[w] = tot;
    __syncthreads();
    if (threadIdx.x == 0) {
        int s = 0;
#pragma unroll
        for (int q = 0; q < 16; ++q) s += wsum[q];
        bsum[b] = s;
    }
}

// ---------------- scan phase B: segmented exclusive scan of 2*NB block sums ------
__global__ __launch_bounds__(64) void scanB_k(const int* __restrict__ bsum,
                                              int* __restrict__ bbase,
                                              int* __restrict__ off_a,
                                              int* __restrict__ off_b) {
    int lane = threadIdx.x;
    int v = (lane < 2 * NB) ? bsum[lane] : 0;
    int seg = lane / NB;
    int inc = v;
#pragma unroll
    for (int d = 1; d < 64; d <<= 1) {
        int x = __shfl_up(inc, d);
        if (lane >= d && (lane - d) / NB == seg) inc += x;
    }
    int excl = inc - v;
    if (lane < 2 * NB) bbase[lane] = excl;
    if (lane == NB - 1) off_a[NN] = inc;
    if (lane == 2 * NB - 1) off_b[NN] = inc;
}

// ---------------- scan phase C: full exclusive scan, writes off[] and cur[] ------
__global__ __launch_bounds__(1024) void scanC_k(int* __restrict__ cur_a,
                                                int* __restrict__ cur_b,
                                                int* __restrict__ off_a,
                                                int* __restrict__ off_b,
                                                const int* __restrict__ bbase) {
    __shared__ int wsum[16];
    int b = blockIdx.x;
    int* cur = (b < NB) ? cur_a : cur_b;
    int* off = (b < NB) ? off_a : off_b;
    int base0 = bbase[b];
    int i = (b % NB) * SCAN_CHUNK + threadIdx.x * 4;
    int4 v = make_int4(0, 0, 0, 0);
    if (i + 3 < NN) {
        v = *reinterpret_cast<const int4*>(cur + i);
    } else {
        if (i < NN) v.x = cur[i];
        if (i + 1 < NN) v.y = cur[i + 1];
        if (i + 2 < NN) v.z = cur[i + 2];
    }
    int s1 = v.x, s2 = s1 + v.y, s3 = s2 + v.z, tot = s3 + v.w;
    int lane = threadIdx.x & 63, w = threadIdx.x >> 6;
    int inc = tot;
#pragma unroll
    for (int d = 1; d < 64; d <<= 1) {
        int x = __shfl_up(inc, d);
        if (lane >= d) inc += x;
    }
    if (lane == 63) wsum[w] = inc;
    int texcl = inc - tot;
    __syncthreads();
    if (threadIdx.x == 0) {
        int r = 0;
#pragma unroll
        for (int q = 0; q < 16; ++q) { int x = wsum[q]; wsum[q] = r; r += x; }
    }
    __syncthreads();
    int base = base0 + wsum[w] + texcl;
    if (i < NN)     { off[i] = base;          cur[i] = base; }
    if (i + 1 < NN) { off[i + 1] = base + s1; cur[i + 1] = base + s1; }
    if (i + 2 < NN) { off[i + 2] = base + s2; cur[i + 2] = base + s2; }
    if (i + 3 < NN) { off[i + 3] = base + s3; cur[i + 3] = base + s3; }
}

// ---------------- scatter: CSR-ordered packed (src, w), 8 edges/thread ----------
__global__ __launch_bounds__(256) void scatter_k(const int* __restrict__ dst_a,
                                                 const int* __restrict__ src_a,
                                                 const float* __restrict__ w_a,
                                                 const int* __restrict__ dst_b,
                                                 const int* __restrict__ src_b,
                                                 const float* __restrict__ w_b,
                                                 int* __restrict__ cur_a,
                                                 int* __restrict__ cur_b,
                                                 int2* __restrict__ csr_a,
                                                 int2* __restrict__ csr_b) {
    long t0 = ((long)blockIdx.x * 256 + threadIdx.x) * EPT;
    const int* dst;
    const int* src;
    const float* wv;
    int* cur;
    int2* csr;
    if (t0 < EE) {
        dst = dst_a; src = src_a; wv = w_a; cur = cur_a; csr = csr_a;
    } else {
        t0 -= EE;
        if (t0 >= EE) return;
        dst = dst_b; src = src_b; wv = w_b; cur = cur_b; csr = csr_b;
    }
    int4 d0 = *reinterpret_cast<const int4*>(dst + t0);
    int4 d1 = *reinterpret_cast<const int4*>(dst + t0 + 4);
    int4 s0 = *reinterpret_cast<const int4*>(src + t0);
    int4 s1 = *reinterpret_cast<const int4*>(src + t0 + 4);
    float4 w0 = *reinterpret_cast<const float4*>(wv + t0);
    float4 w1 = *reinterpret_cast<const float4*>(wv + t0 + 4);
    int p0 = atomicAdd(&cur[d0.x], 1);
    int p1 = atomicAdd(&cur[d0.y], 1);
    int p2 = atomicAdd(&cur[d0.z], 1);
    int p3 = atomicAdd(&cur[d0.w], 1);
    int p4 = atomicAdd(&cur[d1.x], 1);
    int p5 = atomicAdd(&cur[d1.y], 1);
    int p6 = atomicAdd(&cur[d1.z], 1);
    int p7 = atomicAdd(&cur[d1.w], 1);
    csr[p0] = make_int2(s0.x, __float_as_int(w0.x));
    csr[p1] = make_int2(s0.y, __float_as_int(w0.y));
    csr[p2] = make_int2(s0.z, __float_as_int(w0.z));
    csr[p3] = make_int2(s0.w, __float_as_int(w0.w));
    csr[p4] = make_int2(s1.x, __float_as_int(w1.x));
    csr[p5] = make_int2(s1.y, __float_as_int(w1.y));
    csr[p6] = make_int2(s1.z, __float_as_int(w1.z));
    csr[p7] = make_int2(s1.w, __float_as_int(w1.w));
}

// ---------------- pull1: h, gx, gy (32 lanes/node, no atomics, unroll 4) --------
__global__ __launch_bounds__(256) void pull1_k(const float* __restrict__ emh,
                                               const float* __restrict__ e_feat,
                                               const int2* __restrict__ csr_a,
                                               const int* __restrict__ off_a,
                                               const int2* __restrict__ csr_b,
                                               const int* __restrict__ off_b,
                                               float* __restrict__ out_h,
                                               float* __restrict__ gx,
                                               float* __restrict__ gy) {
    int g = blockIdx.x * 256 + threadIdx.x;
    int n = g >> 5, j = g & 31;
    if (n >= NN) return;
    float acc_h = 0.f;

#pragma unroll
    for (int half = 0; half < 2; ++half) {
        const int2* csr = half ? csr_b : csr_a;
        const int* off = half ? off_b : off_a;
        float* gout = half ? gy : gx;
        float acc_g = 0.f, sumw = 0.f;
        int k = off[n], e2 = off[n + 1];
        for (; k + 3 < e2; k += 4) {
            int2 s0 = csr[k], s1 = csr[k + 1], s2 = csr[k + 2], s3 = csr[k + 3];
            float m0 = emh[(size_t)s0.x * 32 + j];
            float m1 = emh[(size_t)s1.x * 32 + j];
            float m2 = emh[(size_t)s2.x * 32 + j];
            float m3 = emh[(size_t)s3.x * 32 + j];
            acc_h += (m0 + m1) + (m2 + m3);
            if (j < 16) {
                float w0 = __int_as_float(s0.y), w1 = __int_as_float(s1.y);
                float w2 = __int_as_float(s2.y), w3 = __int_as_float(s3.y);
                acc_g = fmaf(w0, e_feat[(size_t)s0.x * 16 + j], acc_g);
                acc_g = fmaf(w1, e_feat[(size_t)s1.x * 16 + j], acc_g);
                acc_g = fmaf(w2, e_feat[(size_t)s2.x * 16 + j], acc_g);
                acc_g = fmaf(w3, e_feat[(size_t)s3.x * 16 + j], acc_g);
                sumw += (w0 + w1) + (w2 + w3);
            }
        }
        for (; k < e2; ++k) {
            int2 s0 = csr[k];
            acc_h += emh[(size_t)s0.x * 32 + j];
            if (j < 16) {
                float w0 = __int_as_float(s0.y);
                acc_g = fmaf(w0, e_feat[(size_t)s0.x * 16 + j], acc_g);
                sumw += w0;
            }
        }
        if (j < 16) gout[(size_t)n * 16 + j] = acc_g - sumw * e_feat[(size_t)n * 16 + j];
    }
    out_h[(size_t)n * 32 + j] = fmaxf(acc_h, 0.f);
}

// ---------------- pull2: g2x, g2y (16 lanes/node, unroll 4) ----------------
__global__ __launch_bounds__(256) void pull2_k(const float* __restrict__ gx,
                                               const float* __restrict__ gy,
                                               const int2* __restrict__ csr_a,
                                               const int* __restrict__ off_a,
                                               const int2* __restrict__ csr_b,
                                               const int* __restrict__ off_b,
                                               float* __restrict__ g2x,
                                               float* __restrict__ g2y) {
    int g = blockIdx.x * 256 + threadIdx.x;
    int n = g >> 4, j = g & 15;
    if (n >= NN) return;

#pragma unroll
    for (int half = 0; half < 2; ++half) {
        const int2* csr = half ? csr_b : csr_a;
        const int* off = half ? off_b : off_a;
        const float* gin = half ? gy : gx;
        float* g2 = half ? g2y : g2x;
        float acc = 0.f, sumw = 0.f;
        int k = off[n], e2 = off[n + 1];
        for (; k + 3 < e2; k += 4) {
            int2 s0 = csr[k], s1 = csr[k + 1], s2 = csr[k + 2], s3 = csr[k + 3];
            float w0 = __int_as_float(s0.y), w1 = __int_as_float(s1.y);
            float w2 = __int_as_float(s2.y), w3 = __int_as_float(s3.y);
            acc = fmaf(w0, gin[(size_t)s0.x * 16 + j], acc);
            acc = fmaf(w1, gin[(size_t)s1.x * 16 + j], acc);
            acc = fmaf(w2, gin[(size_t)s2.x * 16 + j], acc);
            acc = fmaf(w3, gin[(size_t)s3.x * 16 + j], acc);
            sumw += (w0 + w1) + (w2 + w3);
        }
        for (; k < e2; ++k) {
            int2 s0 = csr[k];
            float w0 = __int_as_float(s0.y);
            acc = fmaf(w0, gin[(size_t)s0.x * 16 + j], acc);
            sumw += w0;
        }
        g2[(size_t)n * 16 + j] = acc - sumw * gin[(size_t)n * 16 + j];
    }
}

// ---------------- final head ----------------
__global__ __launch_bounds__(256) void final_k(const float* __restrict__ h,
                                               const float* __restrict__ gx,
                                               const float* __restrict__ gy,
                                               const float* __restrict__ g2x,
                                               const float* __restrict__ g2y,
                                               const float* __restrict__ rain0,
                                               const float* __restrict__ W_rin,
                                               const float* __restrict__ W_rout,
                                               float* __restrict__ out_rain) {
    __shared__ float Wl[96 * 128];
    __shared__ float Wo[128];
    __shared__ float hc[4][96];
    for (int i = threadIdx.x; i < 96 * 128; i += 256) Wl[i] = W_rin[i];
    if (threadIdx.x < 128) Wo[threadIdx.x] = W_rout[threadIdx.x];
    __syncthreads();
    const int wave = threadIdx.x >> 6;
    const int lane = threadIdx.x & 63;
    for (int base = blockIdx.x * 4; base < NN; base += gridDim.x * 4) {
        int n = base + wave;
        bool valid = n < NN;
        if (valid) {
            if (lane < 32) {
                hc[wave][lane] = h[(size_t)n * 32 + lane];
                float v1 = (lane < 16) ? g2x[(size_t)n * 16 + lane]
                                       : g2y[(size_t)n * 16 + lane - 16];
                hc[wave][64 + lane] = v1;
            } else {
                int l = lane - 32;
                float v = (l < 16) ? gx[(size_t)n * 16 + l]
                                   : gy[(size_t)n * 16 + l - 16];
                hc[wave][lane] = v;
            }
        }
        __syncthreads();
        if (valid) {
            float acc0 = 0.f, acc1 = 0.f;
#pragma unroll 8
            for (int k = 0; k < 96; ++k) {
                float hv = hc[wave][k];
                acc0 = fmaf(hv, Wl[k * 128 + lane], acc0);
                acc1 = fmaf(hv, Wl[k * 128 + 64 + lane], acc1);
            }
            float sum = fmaxf(acc0, 0.f) * Wo[lane] + fmaxf(acc1, 0.f) * Wo[64 + lane];
#pragma unroll
            for (int off = 32; off; off >>= 1) sum += __shfl_down(sum, off);
            if (lane == 0) out_rain[n] = rain0[n] + sum;
        }
        __syncthreads();
    }
}

extern "C" void kernel_launch(void* const* d_in, const int* in_sizes, int n_in,
                              void* d_out, int out_size, void* d_ws, size_t ws_size,
                              hipStream_t stream) {
    const float* h_feat  = (const float*)d_in[0];
    const float* e_feat  = (const float*)d_in[1];
    const float* rain0   = (const float*)d_in[2];
    const float* w_xx    = (const float*)d_in[3];
    const float* w_yy    = (const float*)d_in[4];
    const float* W_trans = (const float*)d_in[5];
    const float* W_rin   = (const float*)d_in[6];
    const float* W_rout  = (const float*)d_in[7];
    const int* src_xx    = (const int*)d_in[8];
    const int* dst_xx    = (const int*)d_in[9];
    const int* src_yy    = (const int*)d_in[10];
    const int* dst_yy    = (const int*)d_in[11];

    float* ws = (float*)d_ws;
    float* emh = ws;                           // NN*32 floats (reused as g2x/g2y)
    float* gx  = emh + (size_t)NN * 32;        // NN*16
    float* gy  = gx + (size_t)NN * 16;         // NN*16
    float* g2x = emh;                          // alias (emh dead after pull1)
    float* g2y = emh + (size_t)NN * 16;

    int2* csr_xx = (int2*)(gy + (size_t)NN * 16);  // EE int2
    int2* csr_yy = csr_xx + EE;                    // EE int2
    int* off_xx  = (int*)(csr_yy + EE);            // OFFP ints
    int* off_yy  = off_xx + OFFP;                  // OFFP ints
    int* cur_xx  = off_yy + OFFP;                  // NN ints
    int* cur_yy  = cur_xx + NN;                    // NN ints
    int* bsum    = cur_yy + NN;                    // 64
    int* bbase   = bsum + 64;                      // 64

    float* out_rain = (float*)d_out;           // NN
    float* out_h    = out_rain + NN;           // NN*32

    hipMemsetAsync(cur_xx, 0, (size_t)2 * NN * sizeof(int), stream);

    const int TB = (NN * 32 + 255) / 256;                  // 12500 trans blocks
    const int HB = (2 * EE / EPT + 255) / 256;             // 1563 hist blocks
    fused_th_k<<<TB + HB, 256, 0, stream>>>(h_feat, e_feat, W_trans, emh,
                                            dst_xx, dst_yy, cur_xx, cur_yy, TB);

    scanA_k<<<2 * NB, 1024, 0, stream>>>(cur_xx, cur_yy, bsum);
    scanB_k<<<1, 64, 0, stream>>>(bsum, bbase, off_xx, off_yy);
    scanC_k<<<2 * NB, 1024, 0, stream>>>(cur_xx, cur_yy, off_xx, off_yy, bbase);

    scatter_k<<<(2 * EE / EPT + 255) / 256, 256, 0, stream>>>(
        dst_xx, src_xx, w_xx, dst_yy, src_yy, w_yy, cur_xx, cur_yy, csr_xx, csr_yy);

    pull1_k<<<(NN * 32 + 255) / 256, 256, 0, stream>>>(
        emh, e_feat, csr_xx, off_xx, csr_yy, off_yy, out_h, gx, gy);

    pull2_k<<<(NN * 16 + 255) / 256, 256, 0, stream>>>(
        gx, gy, csr_xx, off_xx, csr_yy, off_yy, g2x, g2y);

    final_k<<<1024, 256, 0, stream>>>(out_h, gx, gy, g2x, g2y, rain0, W_rin, W_rout,
                                      out_rain);
}

// Round 5
// 627.429 us; speedup vs baseline: 4.3922x; 1.1479x over previous
//
#include <hip/hip_runtime.h>
#include <hip/hip_bf16.h>

#define NN 100000
#define EE 1600000
#define SCAN_CHUNK 4096
#define NB ((NN + SCAN_CHUNK - 1) / SCAN_CHUNK)   // 25 blocks per array
#define OFFP (NN + 8)                             // padded off array (alignment)
#define EPT 8                                     // edges per thread (hist/scatter)
#define NRANGE 8                                  // dst ranges (== XCDs)
#define RSZ (NN / NRANGE)                         // 12500, exact

// ---------------- fused: emh = relu(cat(h,e)@W) in blocks [0,TB); hist in [TB,..) ----
__global__ __launch_bounds__(256) void fused_th_k(const float* __restrict__ h_feat,
                                                  const float* __restrict__ e_feat,
                                                  const float* __restrict__ W_trans,
                                                  float* __restrict__ emh,
                                                  const int* __restrict__ dst_a,
                                                  const int* __restrict__ dst_b,
                                                  int* __restrict__ cur_a,
                                                  int* __restrict__ cur_b, int TB) {
    __shared__ float Wl[48 * 32];
    if ((int)blockIdx.x < TB) {
        for (int i = threadIdx.x; i < 48 * 32; i += 256) Wl[i] = W_trans[i];
        __syncthreads();
        int t = blockIdx.x * 256 + threadIdx.x;
        if (t >= NN * 32) return;
        int n = t >> 5, j = t & 31;
        const float* hrow = h_feat + (size_t)n * 32;
        const float* erow = e_feat + (size_t)n * 16;
        float acc = 0.f;
#pragma unroll 8
        for (int k = 0; k < 32; ++k) acc = fmaf(hrow[k], Wl[k * 32 + j], acc);
#pragma unroll 8
        for (int k = 0; k < 16; ++k) acc = fmaf(erow[k], Wl[(32 + k) * 32 + j], acc);
        emh[t] = fmaxf(acc, 0.f);
    } else {
        long t0 = ((long)(blockIdx.x - TB) * 256 + threadIdx.x) * EPT;
        const int* dst;
        int* cur;
        if (t0 < EE) {
            dst = dst_a; cur = cur_a;
        } else {
            t0 -= EE;
            if (t0 >= EE) return;
            dst = dst_b; cur = cur_b;
        }
        int4 d0 = *reinterpret_cast<const int4*>(dst + t0);
        int4 d1 = *reinterpret_cast<const int4*>(dst + t0 + 4);
        atomicAdd(&cur[d0.x], 1); atomicAdd(&cur[d0.y], 1);
        atomicAdd(&cur[d0.z], 1); atomicAdd(&cur[d0.w], 1);
        atomicAdd(&cur[d1.x], 1); atomicAdd(&cur[d1.y], 1);
        atomicAdd(&cur[d1.z], 1); atomicAdd(&cur[d1.w], 1);
    }
}

// ---------------- scan phase A: per-block (4096-chunk) totals ----------------
__global__ __launch_bounds__(1024) void scanA_k(const int* __restrict__ cur_a,
                                                const int* __restrict__ cur_b,
                                                int* __restrict__ bsum) {
    __shared__ int wsum[16];
    int b = blockIdx.x;
    const int* arr = (b < NB) ? cur_a : cur_b;
    int i = (b % NB) * SCAN_CHUNK + threadIdx.x * 4;
    int4 v = make_int4(0, 0, 0, 0);
    if (i + 3 < NN) {
        v = *reinterpret_cast<const int4*>(arr + i);
    } else {
        if (i < NN) v.x = arr[i];
        if (i + 1 < NN) v.y = arr[i + 1];
        if (i + 2 < NN) v.z = arr[i + 2];
    }
    int tot = v.x + v.y + v.z + v.w;
#pragma unroll
    for (int d = 32; d; d >>= 1) tot += __shfl_down(tot, d);
    int lane = threadIdx.x & 63, w = threadIdx.x >> 6;
    if (lane == 0) wsum[w] = tot;
    __syncthreads();
    if (threadIdx.x == 0) {
        int s = 0;
#pragma unroll
        for (int q = 0; q < 16; ++q) s += wsum[q];
        bsum[b] = s;
    }
}

// ---------------- scan phase B: segmented exclusive scan of 2*NB block sums ------
__global__ __launch_bounds__(64) void scanB_k(const int* __restrict__ bsum,
                                              int* __restrict__ bbase,
                                              int* __restrict__ off_a,
                                              int* __restrict__ off_b) {
    int lane = threadIdx.x;
    int v = (lane < 2 * NB) ? bsum[lane] : 0;
    int seg = lane / NB;
    int inc = v;
#pragma unroll
    for (int d = 1; d < 64; d <<= 1) {
        int x = __shfl_up(inc, d);
        if (lane >= d && (lane - d) / NB == seg) inc += x;
    }
    int excl = inc - v;
    if (lane < 2 * NB) bbase[lane] = excl;
    if (lane == NB - 1) off_a[NN] = inc;
    if (lane == 2 * NB - 1) off_b[NN] = inc;
}

// ---------------- scan phase C: full exclusive scan, writes off[] and cur[] ------
__global__ __launch_bounds__(1024) void scanC_k(int* __restrict__ cur_a,
                                                int* __restrict__ cur_b,
                                                int* __restrict__ off_a,
                                                int* __restrict__ off_b,
                                                const int* __restrict__ bbase) {
    __shared__ int wsum[16];
    int b = blockIdx.x;
    int* cur = (b < NB) ? cur_a : cur_b;
    int* off = (b < NB) ? off_a : off_b;
    int base0 = bbase[b];
    int i = (b % NB) * SCAN_CHUNK + threadIdx.x * 4;
    int4 v = make_int4(0, 0, 0, 0);
    if (i + 3 < NN) {
        v = *reinterpret_cast<const int4*>(cur + i);
    } else {
        if (i < NN) v.x = cur[i];
        if (i + 1 < NN) v.y = cur[i + 1];
        if (i + 2 < NN) v.z = cur[i + 2];
    }
    int s1 = v.x, s2 = s1 + v.y, s3 = s2 + v.z, tot = s3 + v.w;
    int lane = threadIdx.x & 63, w = threadIdx.x >> 6;
    int inc = tot;
#pragma unroll
    for (int d = 1; d < 64; d <<= 1) {
        int x = __shfl_up(inc, d);
        if (lane >= d) inc += x;
    }
    if (lane == 63) wsum[w] = inc;
    int texcl = inc - tot;
    __syncthreads();
    if (threadIdx.x == 0) {
        int r = 0;
#pragma unroll
        for (int q = 0; q < 16; ++q) { int x = wsum[q]; wsum[q] = r; r += x; }
    }
    __syncthreads();
    int base = base0 + wsum[w] + texcl;
    if (i < NN)     { off[i] = base;          cur[i] = base; }
    if (i + 1 < NN) { off[i + 1] = base + s1; cur[i + 1] = base + s1; }
    if (i + 2 < NN) { off[i + 2] = base + s2; cur[i + 2] = base + s2; }
    if (i + 3 < NN) { off[i + 3] = base + s3; cur[i + 3] = base + s3; }
}

// ---------------- scatter: dst-range-partitioned (XCD-local under round-robin) ----
// Block (r = bid&7, c = bid>>3): reads edge chunk c, handles only dst in range r.
// Every (c, r) pair exists exactly once -> correct under ANY dispatch mapping;
// if bid%8 == XCD (measured round-robin), csr lines + cur counters become
// single-XCD-owned: merged writebacks, local-L2 atomics, no coherence ping-pong.
__global__ __launch_bounds__(256) void scatter_k(const int* __restrict__ dst_a,
                                                 const int* __restrict__ src_a,
                                                 const float* __restrict__ w_a,
                                                 const int* __restrict__ dst_b,
                                                 const int* __restrict__ src_b,
                                                 const float* __restrict__ w_b,
                                                 int* __restrict__ cur_a,
                                                 int* __restrict__ cur_b,
                                                 int2* __restrict__ csr_a,
                                                 int2* __restrict__ csr_b) {
    const int r = blockIdx.x & (NRANGE - 1);
    const int lo = r * RSZ;
    const int hi = lo + RSZ;
    long t0 = ((long)(blockIdx.x >> 3) * 256 + threadIdx.x) * EPT;
    const int* dst;
    const int* src;
    const float* wv;
    int* cur;
    int2* csr;
    if (t0 < EE) {
        dst = dst_a; src = src_a; wv = w_a; cur = cur_a; csr = csr_a;
    } else {
        t0 -= EE;
        if (t0 >= EE) return;
        dst = dst_b; src = src_b; wv = w_b; cur = cur_b; csr = csr_b;
    }
    int4 d0 = *reinterpret_cast<const int4*>(dst + t0);
    int4 d1 = *reinterpret_cast<const int4*>(dst + t0 + 4);
    const int dd[8] = {d0.x, d0.y, d0.z, d0.w, d1.x, d1.y, d1.z, d1.w};
#pragma unroll
    for (int q = 0; q < 8; ++q) {
        int d = dd[q];
        if (d >= lo && d < hi) {
            int p = atomicAdd(&cur[d], 1);
            csr[p] = make_int2(src[t0 + q], __float_as_int(wv[t0 + q]));
        }
    }
}

// ---------------- pull1: h, gx, gy (32 lanes/node, no atomics, unroll 4) --------
__global__ __launch_bounds__(256) void pull1_k(const float* __restrict__ emh,
                                               const float* __restrict__ e_feat,
                                               const int2* __restrict__ csr_a,
                                               const int* __restrict__ off_a,
                                               const int2* __restrict__ csr_b,
                                               const int* __restrict__ off_b,
                                               float* __restrict__ out_h,
                                               float* __restrict__ gx,
                                               float* __restrict__ gy) {
    int g = blockIdx.x * 256 + threadIdx.x;
    int n = g >> 5, j = g & 31;
    if (n >= NN) return;
    float acc_h = 0.f;

#pragma unroll
    for (int half = 0; half < 2; ++half) {
        const int2* csr = half ? csr_b : csr_a;
        const int* off = half ? off_b : off_a;
        float* gout = half ? gy : gx;
        float acc_g = 0.f, sumw = 0.f;
        int k = off[n], e2 = off[n + 1];
        for (; k + 3 < e2; k += 4) {
            int2 s0 = csr[k], s1 = csr[k + 1], s2 = csr[k + 2], s3 = csr[k + 3];
            float m0 = emh[(size_t)s0.x * 32 + j];
            float m1 = emh[(size_t)s1.x * 32 + j];
            float m2 = emh[(size_t)s2.x * 32 + j];
            float m3 = emh[(size_t)s3.x * 32 + j];
            acc_h += (m0 + m1) + (m2 + m3);
            if (j < 16) {
                float w0 = __int_as_float(s0.y), w1 = __int_as_float(s1.y);
                float w2 = __int_as_float(s2.y), w3 = __int_as_float(s3.y);
                acc_g = fmaf(w0, e_feat[(size_t)s0.x * 16 + j], acc_g);
                acc_g = fmaf(w1, e_feat[(size_t)s1.x * 16 + j], acc_g);
                acc_g = fmaf(w2, e_feat[(size_t)s2.x * 16 + j], acc_g);
                acc_g = fmaf(w3, e_feat[(size_t)s3.x * 16 + j], acc_g);
                sumw += (w0 + w1) + (w2 + w3);
            }
        }
        for (; k < e2; ++k) {
            int2 s0 = csr[k];
            acc_h += emh[(size_t)s0.x * 32 + j];
            if (j < 16) {
                float w0 = __int_as_float(s0.y);
                acc_g = fmaf(w0, e_feat[(size_t)s0.x * 16 + j], acc_g);
                sumw += w0;
            }
        }
        if (j < 16) gout[(size_t)n * 16 + j] = acc_g - sumw * e_feat[(size_t)n * 16 + j];
    }
    out_h[(size_t)n * 32 + j] = fmaxf(acc_h, 0.f);
}

// ---------------- pull2: g2x, g2y (16 lanes/node, unroll 4) ----------------
__global__ __launch_bounds__(256) void pull2_k(const float* __restrict__ gx,
                                               const float* __restrict__ gy,
                                               const int2* __restrict__ csr_a,
                                               const int* __restrict__ off_a,
                                               const int2* __restrict__ csr_b,
                                               const int* __restrict__ off_b,
                                               float* __restrict__ g2x,
                                               float* __restrict__ g2y) {
    int g = blockIdx.x * 256 + threadIdx.x;
    int n = g >> 4, j = g & 15;
    if (n >= NN) return;

#pragma unroll
    for (int half = 0; half < 2; ++half) {
        const int2* csr = half ? csr_b : csr_a;
        const int* off = half ? off_b : off_a;
        const float* gin = half ? gy : gx;
        float* g2 = half ? g2y : g2x;
        float acc = 0.f, sumw = 0.f;
        int k = off[n], e2 = off[n + 1];
        for (; k + 3 < e2; k += 4) {
            int2 s0 = csr[k], s1 = csr[k + 1], s2 = csr[k + 2], s3 = csr[k + 3];
            float w0 = __int_as_float(s0.y), w1 = __int_as_float(s1.y);
            float w2 = __int_as_float(s2.y), w3 = __int_as_float(s3.y);
            acc = fmaf(w0, gin[(size_t)s0.x * 16 + j], acc);
            acc = fmaf(w1, gin[(size_t)s1.x * 16 + j], acc);
            acc = fmaf(w2, gin[(size_t)s2.x * 16 + j], acc);
            acc = fmaf(w3, gin[(size_t)s3.x * 16 + j], acc);
            sumw += (w0 + w1) + (w2 + w3);
        }
        for (; k < e2; ++k) {
            int2 s0 = csr[k];
            float w0 = __int_as_float(s0.y);
            acc = fmaf(w0, gin[(size_t)s0.x * 16 + j], acc);
            sumw += w0;
        }
        g2[(size_t)n * 16 + j] = acc - sumw * gin[(size_t)n * 16 + j];
    }
}

// ---------------- final head ----------------
__global__ __launch_bounds__(256) void final_k(const float* __restrict__ h,
                                               const float* __restrict__ gx,
                                               const float* __restrict__ gy,
                                               const float* __restrict__ g2x,
                                               const float* __restrict__ g2y,
                                               const float* __restrict__ rain0,
                                               const float* __restrict__ W_rin,
                                               const float* __restrict__ W_rout,
                                               float* __restrict__ out_rain) {
    __shared__ float Wl[96 * 128];
    __shared__ float Wo[128];
    __shared__ float hc[4][96];
    for (int i = threadIdx.x; i < 96 * 128; i += 256) Wl[i] = W_rin[i];
    if (threadIdx.x < 128) Wo[threadIdx.x] = W_rout[threadIdx.x];
    __syncthreads();
    const int wave = threadIdx.x >> 6;
    const int lane = threadIdx.x & 63;
    for (int base = blockIdx.x * 4; base < NN; base += gridDim.x * 4) {
        int n = base + wave;
        bool valid = n < NN;
        if (valid) {
            if (lane < 32) {
                hc[wave][lane] = h[(size_t)n * 32 + lane];
                float v1 = (lane < 16) ? g2x[(size_t)n * 16 + lane]
                                       : g2y[(size_t)n * 16 + lane - 16];
                hc[wave][64 + lane] = v1;
            } else {
                int l = lane - 32;
                float v = (l < 16) ? gx[(size_t)n * 16 + l]
                                   : gy[(size_t)n * 16 + l - 16];
                hc[wave][lane] = v;
            }
        }
        __syncthreads();
        if (valid) {
            float acc0 = 0.f, acc1 = 0.f;
#pragma unroll 8
            for (int k = 0; k < 96; ++k) {
                float hv = hc[wave][k];
                acc0 = fmaf(hv, Wl[k * 128 + lane], acc0);
                acc1 = fmaf(hv, Wl[k * 128 + 64 + lane], acc1);
            }
            float sum = fmaxf(acc0, 0.f) * Wo[lane] + fmaxf(acc1, 0.f) * Wo[64 + lane];
#pragma unroll
            for (int off = 32; off; off >>= 1) sum += __shfl_down(sum, off);
            if (lane == 0) out_rain[n] = rain0[n] + sum;
        }
        __syncthreads();
    }
}

extern "C" void kernel_launch(void* const* d_in, const int* in_sizes, int n_in,
                              void* d_out, int out_size, void* d_ws, size_t ws_size,
                              hipStream_t stream) {
    const float* h_feat  = (const float*)d_in[0];
    const float* e_feat  = (const float*)d_in[1];
    const float* rain0   = (const float*)d_in[2];
    const float* w_xx    = (const float*)d_in[3];
    const float* w_yy    = (const float*)d_in[4];
    const float* W_trans = (const float*)d_in[5];
    const float* W_rin   = (const float*)d_in[6];
    const float* W_rout  = (const float*)d_in[7];
    const int* src_xx    = (const int*)d_in[8];
    const int* dst_xx    = (const int*)d_in[9];
    const int* src_yy    = (const int*)d_in[10];
    const int* dst_yy    = (const int*)d_in[11];

    float* ws = (float*)d_ws;
    float* emh = ws;                           // NN*32 floats (reused as g2x/g2y)
    float* gx  = emh + (size_t)NN * 32;        // NN*16
    float* gy  = gx + (size_t)NN * 16;         // NN*16
    float* g2x = emh;                          // alias (emh dead after pull1)
    float* g2y = emh + (size_t)NN * 16;

    int2* csr_xx = (int2*)(gy + (size_t)NN * 16);  // EE int2
    int2* csr_yy = csr_xx + EE;                    // EE int2
    int* off_xx  = (int*)(csr_yy + EE);            // OFFP ints
    int* off_yy  = off_xx + OFFP;                  // OFFP ints
    int* cur_xx  = off_yy + OFFP;                  // NN ints
    int* cur_yy  = cur_xx + NN;                    // NN ints
    int* bsum    = cur_yy + NN;                    // 64
    int* bbase   = bsum + 64;                      // 64

    float* out_rain = (float*)d_out;           // NN
    float* out_h    = out_rain + NN;           // NN*32

    hipMemsetAsync(cur_xx, 0, (size_t)2 * NN * sizeof(int), stream);

    const int TB = (NN * 32 + 255) / 256;                  // 12500 trans blocks
    const int HB = (2 * EE / EPT + 255) / 256;             // 1563 hist blocks
    fused_th_k<<<TB + HB, 256, 0, stream>>>(h_feat, e_feat, W_trans, emh,
                                            dst_xx, dst_yy, cur_xx, cur_yy, TB);

    scanA_k<<<2 * NB, 1024, 0, stream>>>(cur_xx, cur_yy, bsum);
    scanB_k<<<1, 64, 0, stream>>>(bsum, bbase, off_xx, off_yy);
    scanC_k<<<2 * NB, 1024, 0, stream>>>(cur_xx, cur_yy, off_xx, off_yy, bbase);

    const int SB = ((2 * EE / EPT + 255) / 256) * NRANGE;  // 1563 * 8 blocks
    scatter_k<<<SB, 256, 0, stream>>>(
        dst_xx, src_xx, w_xx, dst_yy, src_yy, w_yy, cur_xx, cur_yy, csr_xx, csr_yy);

    pull1_k<<<(NN * 32 + 255) / 256, 256, 0, stream>>>(
        emh, e_feat, csr_xx, off_xx, csr_yy, off_yy, out_h, gx, gy);

    pull2_k<<<(NN * 16 + 255) / 256, 256, 0, stream>>>(
        gx, gy, csr_xx, off_xx, csr_yy, off_yy, g2x, g2y);

    final_k<<<1024, 256, 0, stream>>>(out_h, gx, gy, g2x, g2y, rain0, W_rin, W_rout,
                                      out_rain);
}

// Round 6
// 502.492 us; speedup vs baseline: 5.4842x; 1.2486x over previous
//
#include <hip/hip_runtime.h>
#include <hip/hip_bf16.h>

#define NN 100000
#define EE 1600000
#define SCAN_CHUNK 4096
#define NB ((NN + SCAN_CHUNK - 1) / SCAN_CHUNK)   // 25 blocks per array
#define OFFP (NN + 8)                             // padded off array (alignment)
#define EPT 8                                     // edges per thread (hist/scatter)
#define NRANGE 8                                  // dst ranges (== XCDs)
#define RSZ (NN / NRANGE)                         // 12500, exact
#define AP 104                                    // bf16 LDS row pad (208 B = 13*16)

typedef __attribute__((ext_vector_type(8))) short bf16x8;
typedef __attribute__((ext_vector_type(4))) float f32x4;

__device__ inline unsigned short f2bf(float f) {
    unsigned u = __float_as_uint(f);
    return (unsigned short)((u + 0x7FFFu + ((u >> 16) & 1u)) >> 16);
}

// ---- fused: emh=relu(cat(h,e)@W) in blocks [0,TB); dst-range-partitioned hist after ----
__global__ __launch_bounds__(256) void fused_th_k(const float* __restrict__ h_feat,
                                                  const float* __restrict__ e_feat,
                                                  const float* __restrict__ W_trans,
                                                  float* __restrict__ emh,
                                                  const int* __restrict__ dst_a,
                                                  const int* __restrict__ dst_b,
                                                  int* __restrict__ cur_a,
                                                  int* __restrict__ cur_b, int TB) {
    __shared__ float Wl[48 * 32];
    if ((int)blockIdx.x < TB) {
        for (int i = threadIdx.x; i < 48 * 32; i += 256) Wl[i] = W_trans[i];
        __syncthreads();
        int t = blockIdx.x * 256 + threadIdx.x;
        if (t >= NN * 32) return;
        int n = t >> 5, j = t & 31;
        const float* hrow = h_feat + (size_t)n * 32;
        const float* erow = e_feat + (size_t)n * 16;
        float acc = 0.f;
#pragma unroll 8
        for (int k = 0; k < 32; ++k) acc = fmaf(hrow[k], Wl[k * 32 + j], acc);
#pragma unroll 8
        for (int k = 0; k < 16; ++k) acc = fmaf(erow[k], Wl[(32 + k) * 32 + j], acc);
        emh[t] = fmaxf(acc, 0.f);
    } else {
        int idx = (int)blockIdx.x - TB;
        const int r = idx & (NRANGE - 1);
        const int lo = r * RSZ, hi = lo + RSZ;
        long t0 = ((long)(idx >> 3) * 256 + threadIdx.x) * EPT;
        const int* dst;
        int* cur;
        if (t0 < EE) {
            dst = dst_a; cur = cur_a;
        } else {
            t0 -= EE;
            if (t0 >= EE) return;
            dst = dst_b; cur = cur_b;
        }
        int4 d0 = *reinterpret_cast<const int4*>(dst + t0);
        int4 d1 = *reinterpret_cast<const int4*>(dst + t0 + 4);
        const int dd[8] = {d0.x, d0.y, d0.z, d0.w, d1.x, d1.y, d1.z, d1.w};
#pragma unroll
        for (int q = 0; q < 8; ++q)
            if (dd[q] >= lo && dd[q] < hi) atomicAdd(&cur[dd[q]], 1);
    }
}

// ---------------- scan phase A: per-block (4096-chunk) totals ----------------
__global__ __launch_bounds__(1024) void scanA_k(const int* __restrict__ cur_a,
                                                const int* __restrict__ cur_b,
                                                int* __restrict__ bsum) {
    __shared__ int wsum[16];
    int b = blockIdx.x;
    const int* arr = (b < NB) ? cur_a : cur_b;
    int i = (b % NB) * SCAN_CHUNK + threadIdx.x * 4;
    int4 v = make_int4(0, 0, 0, 0);
    if (i + 3 < NN) {
        v = *reinterpret_cast<const int4*>(arr + i);
    } else {
        if (i < NN) v.x = arr[i];
        if (i + 1 < NN) v.y = arr[i + 1];
        if (i + 2 < NN) v.z = arr[i + 2];
    }
    int tot = v.x + v.y + v.z + v.w;
#pragma unroll
    for (int d = 32; d; d >>= 1) tot += __shfl_down(tot, d);
    int lane = threadIdx.x & 63, w = threadIdx.x >> 6;
    if (lane == 0) wsum[w] = tot;
    __syncthreads();
    if (threadIdx.x == 0) {
        int s = 0;
#pragma unroll
        for (int q = 0; q < 16; ++q) s += wsum[q];
        bsum[b] = s;
    }
}

// ---------------- scan phase B: segmented exclusive scan of 2*NB block sums ------
__global__ __launch_bounds__(64) void scanB_k(const int* __restrict__ bsum,
                                              int* __restrict__ bbase,
                                              int* __restrict__ off_a,
                                              int* __restrict__ off_b) {
    int lane = threadIdx.x;
    int v = (lane < 2 * NB) ? bsum[lane] : 0;
    int seg = lane / NB;
    int inc = v;
#pragma unroll
    for (int d = 1; d < 64; d <<= 1) {
        int x = __shfl_up(inc, d);
        if (lane >= d && (lane - d) / NB == seg) inc += x;
    }
    int excl = inc - v;
    if (lane < 2 * NB) bbase[lane] = excl;
    if (lane == NB - 1) off_a[NN] = inc;
    if (lane == 2 * NB - 1) off_b[NN] = inc;
}

// ---------------- scan phase C: full exclusive scan, writes off[] and cur[] ------
__global__ __launch_bounds__(1024) void scanC_k(int* __restrict__ cur_a,
                                                int* __restrict__ cur_b,
                                                int* __restrict__ off_a,
                                                int* __restrict__ off_b,
                                                const int* __restrict__ bbase) {
    __shared__ int wsum[16];
    int b = blockIdx.x;
    int* cur = (b < NB) ? cur_a : cur_b;
    int* off = (b < NB) ? off_a : off_b;
    int base0 = bbase[b];
    int i = (b % NB) * SCAN_CHUNK + threadIdx.x * 4;
    int4 v = make_int4(0, 0, 0, 0);
    if (i + 3 < NN) {
        v = *reinterpret_cast<const int4*>(cur + i);
    } else {
        if (i < NN) v.x = cur[i];
        if (i + 1 < NN) v.y = cur[i + 1];
        if (i + 2 < NN) v.z = cur[i + 2];
    }
    int s1 = v.x, s2 = s1 + v.y, s3 = s2 + v.z, tot = s3 + v.w;
    int lane = threadIdx.x & 63, w = threadIdx.x >> 6;
    int inc = tot;
#pragma unroll
    for (int d = 1; d < 64; d <<= 1) {
        int x = __shfl_up(inc, d);
        if (lane >= d) inc += x;
    }
    if (lane == 63) wsum[w] = inc;
    int texcl = inc - tot;
    __syncthreads();
    if (threadIdx.x == 0) {
        int r = 0;
#pragma unroll
        for (int q = 0; q < 16; ++q) { int x = wsum[q]; wsum[q] = r; r += x; }
    }
    __syncthreads();
    int base = base0 + wsum[w] + texcl;
    if (i < NN)     { off[i] = base;          cur[i] = base; }
    if (i + 1 < NN) { off[i + 1] = base + s1; cur[i + 1] = base + s1; }
    if (i + 2 < NN) { off[i + 2] = base + s2; cur[i + 2] = base + s2; }
    if (i + 3 < NN) { off[i + 3] = base + s3; cur[i + 3] = base + s3; }
}

// ---------------- scatter: dst-range-partitioned (XCD-local under round-robin) ----
__global__ __launch_bounds__(256) void scatter_k(const int* __restrict__ dst_a,
                                                 const int* __restrict__ src_a,
                                                 const float* __restrict__ w_a,
                                                 const int* __restrict__ dst_b,
                                                 const int* __restrict__ src_b,
                                                 const float* __restrict__ w_b,
                                                 int* __restrict__ cur_a,
                                                 int* __restrict__ cur_b,
                                                 int2* __restrict__ csr_a,
                                                 int2* __restrict__ csr_b) {
    const int r = blockIdx.x & (NRANGE - 1);
    const int lo = r * RSZ;
    const int hi = lo + RSZ;
    long t0 = ((long)(blockIdx.x >> 3) * 256 + threadIdx.x) * EPT;
    const int* dst;
    const int* src;
    const float* wv;
    int* cur;
    int2* csr;
    if (t0 < EE) {
        dst = dst_a; src = src_a; wv = w_a; cur = cur_a; csr = csr_a;
    } else {
        t0 -= EE;
        if (t0 >= EE) return;
        dst = dst_b; src = src_b; wv = w_b; cur = cur_b; csr = csr_b;
    }
    int4 d0 = *reinterpret_cast<const int4*>(dst + t0);
    int4 d1 = *reinterpret_cast<const int4*>(dst + t0 + 4);
    const int dd[8] = {d0.x, d0.y, d0.z, d0.w, d1.x, d1.y, d1.z, d1.w};
#pragma unroll
    for (int q = 0; q < 8; ++q) {
        int d = dd[q];
        if (d >= lo && d < hi) {
            int p = atomicAdd(&cur[d], 1);
            csr[p] = make_int2(src[t0 + q], __float_as_int(wv[t0 + q]));
        }
    }
}

// ---------------- pull1: h, gx, gy (32 lanes/node, no atomics, unroll 4) --------
__global__ __launch_bounds__(256) void pull1_k(const float* __restrict__ emh,
                                               const float* __restrict__ e_feat,
                                               const int2* __restrict__ csr_a,
                                               const int* __restrict__ off_a,
                                               const int2* __restrict__ csr_b,
                                               const int* __restrict__ off_b,
                                               float* __restrict__ out_h,
                                               float* __restrict__ gx,
                                               float* __restrict__ gy) {
    int g = blockIdx.x * 256 + threadIdx.x;
    int n = g >> 5, j = g & 31;
    if (n >= NN) return;
    float acc_h = 0.f;

#pragma unroll
    for (int half = 0; half < 2; ++half) {
        const int2* csr = half ? csr_b : csr_a;
        const int* off = half ? off_b : off_a;
        float* gout = half ? gy : gx;
        float acc_g = 0.f, sumw = 0.f;
        int k = off[n], e2 = off[n + 1];
        for (; k + 3 < e2; k += 4) {
            int2 s0 = csr[k], s1 = csr[k + 1], s2 = csr[k + 2], s3 = csr[k + 3];
            float m0 = emh[(size_t)s0.x * 32 + j];
            float m1 = emh[(size_t)s1.x * 32 + j];
            float m2 = emh[(size_t)s2.x * 32 + j];
            float m3 = emh[(size_t)s3.x * 32 + j];
            acc_h += (m0 + m1) + (m2 + m3);
            if (j < 16) {
                float w0 = __int_as_float(s0.y), w1 = __int_as_float(s1.y);
                float w2 = __int_as_float(s2.y), w3 = __int_as_float(s3.y);
                acc_g = fmaf(w0, e_feat[(size_t)s0.x * 16 + j], acc_g);
                acc_g = fmaf(w1, e_feat[(size_t)s1.x * 16 + j], acc_g);
                acc_g = fmaf(w2, e_feat[(size_t)s2.x * 16 + j], acc_g);
                acc_g = fmaf(w3, e_feat[(size_t)s3.x * 16 + j], acc_g);
                sumw += (w0 + w1) + (w2 + w3);
            }
        }
        for (; k < e2; ++k) {
            int2 s0 = csr[k];
            acc_h += emh[(size_t)s0.x * 32 + j];
            if (j < 16) {
                float w0 = __int_as_float(s0.y);
                acc_g = fmaf(w0, e_feat[(size_t)s0.x * 16 + j], acc_g);
                sumw += w0;
            }
        }
        if (j < 16) gout[(size_t)n * 16 + j] = acc_g - sumw * e_feat[(size_t)n * 16 + j];
    }
    out_h[(size_t)n * 32 + j] = fmaxf(acc_h, 0.f);
}

// ---------------- pull2: g2x, g2y (16 lanes/node, unroll 4) ----------------
__global__ __launch_bounds__(256) void pull2_k(const float* __restrict__ gx,
                                               const float* __restrict__ gy,
                                               const int2* __restrict__ csr_a,
                                               const int* __restrict__ off_a,
                                               const int2* __restrict__ csr_b,
                                               const int* __restrict__ off_b,
                                               float* __restrict__ g2x,
                                               float* __restrict__ g2y) {
    int g = blockIdx.x * 256 + threadIdx.x;
    int n = g >> 4, j = g & 15;
    if (n >= NN) return;

#pragma unroll
    for (int half = 0; half < 2; ++half) {
        const int2* csr = half ? csr_b : csr_a;
        const int* off = half ? off_b : off_a;
        const float* gin = half ? gy : gx;
        float* g2 = half ? g2y : g2x;
        float acc = 0.f, sumw = 0.f;
        int k = off[n], e2 = off[n + 1];
        for (; k + 3 < e2; k += 4) {
            int2 s0 = csr[k], s1 = csr[k + 1], s2 = csr[k + 2], s3 = csr[k + 3];
            float w0 = __int_as_float(s0.y), w1 = __int_as_float(s1.y);
            float w2 = __int_as_float(s2.y), w3 = __int_as_float(s3.y);
            acc = fmaf(w0, gin[(size_t)s0.x * 16 + j], acc);
            acc = fmaf(w1, gin[(size_t)s1.x * 16 + j], acc);
            acc = fmaf(w2, gin[(size_t)s2.x * 16 + j], acc);
            acc = fmaf(w3, gin[(size_t)s3.x * 16 + j], acc);
            sumw += (w0 + w1) + (w2 + w3);
        }
        for (; k < e2; ++k) {
            int2 s0 = csr[k];
            float w0 = __int_as_float(s0.y);
            acc = fmaf(w0, gin[(size_t)s0.x * 16 + j], acc);
            sumw += w0;
        }
        g2[(size_t)n * 16 + j] = acc - sumw * gin[(size_t)n * 16 + j];
    }
}

// ---------------- final head: bf16 MFMA GEMM (64 nodes/block) ----------------
// rain = rain0 + relu(h_cat @ W_rin) @ W_rout, h_cat = [h|gx|gy|g2x|g2y] (96)
// A: [64][96] bf16 LDS (row pad 104); B: W_rin^T [128 col][96 k] bf16 LDS.
// Wave w owns 16 nodes; 8 col-tiles x 3 k-steps of mfma_f32_16x16x32_bf16.
__global__ __launch_bounds__(256) void final_mfma_k(const float* __restrict__ h,
                                                    const float* __restrict__ gx,
                                                    const float* __restrict__ gy,
                                                    const float* __restrict__ g2x,
                                                    const float* __restrict__ g2y,
                                                    const float* __restrict__ rain0,
                                                    const float* __restrict__ W_rin,
                                                    const float* __restrict__ W_rout,
                                                    float* __restrict__ out_rain) {
    __shared__ __align__(16) unsigned short Wt[128 * AP];  // 26.6 KB
    __shared__ __align__(16) unsigned short At[64 * AP];   // 13.3 KB
    __shared__ float Wo[128];
    const int tid = threadIdx.x;

    // stage W^T in bf16
    for (int i = tid; i < 3072; i += 256) {
        int k = i >> 5;            // 0..95
        int c = (i & 31) * 4;      // 0..124
        float4 wv = *reinterpret_cast<const float4*>(W_rin + k * 128 + c);
        Wt[(c + 0) * AP + k] = f2bf(wv.x);
        Wt[(c + 1) * AP + k] = f2bf(wv.y);
        Wt[(c + 2) * AP + k] = f2bf(wv.z);
        Wt[(c + 3) * AP + k] = f2bf(wv.w);
    }
    if (tid < 128) Wo[tid] = W_rout[tid];

    // stage A: 4 threads/node, 24 feats each (chunks aligned to float4 segments)
    {
        int n = tid >> 2, q = tid & 3;
        int node = blockIdx.x * 64 + n;
        float f[24];
#define LD4(di, p) { float4 v_ = *reinterpret_cast<const float4*>(p); \
                     f[di] = v_.x; f[di+1] = v_.y; f[di+2] = v_.z; f[di+3] = v_.w; }
        if (node < NN) {
            if (q == 0) {
                LD4(0,  h + (size_t)node * 32 + 0);
                LD4(4,  h + (size_t)node * 32 + 4);
                LD4(8,  h + (size_t)node * 32 + 8);
                LD4(12, h + (size_t)node * 32 + 12);
                LD4(16, h + (size_t)node * 32 + 16);
                LD4(20, h + (size_t)node * 32 + 20);
            } else if (q == 1) {
                LD4(0,  h + (size_t)node * 32 + 24);
                LD4(4,  h + (size_t)node * 32 + 28);
                LD4(8,  gx + (size_t)node * 16 + 0);
                LD4(12, gx + (size_t)node * 16 + 4);
                LD4(16, gx + (size_t)node * 16 + 8);
                LD4(20, gx + (size_t)node * 16 + 12);
            } else if (q == 2) {
                LD4(0,  gy + (size_t)node * 16 + 0);
                LD4(4,  gy + (size_t)node * 16 + 4);
                LD4(8,  gy + (size_t)node * 16 + 8);
                LD4(12, gy + (size_t)node * 16 + 12);
                LD4(16, g2x + (size_t)node * 16 + 0);
                LD4(20, g2x + (size_t)node * 16 + 4);
            } else {
                LD4(0,  g2x + (size_t)node * 16 + 8);
                LD4(4,  g2x + (size_t)node * 16 + 12);
                LD4(8,  g2y + (size_t)node * 16 + 0);
                LD4(12, g2y + (size_t)node * 16 + 4);
                LD4(16, g2y + (size_t)node * 16 + 8);
                LD4(20, g2y + (size_t)node * 16 + 12);
            }
        } else {
#pragma unroll
            for (int i = 0; i < 24; ++i) f[i] = 0.f;
        }
#undef LD4
        unsigned pk[12];
#pragma unroll
        for (int i = 0; i < 12; ++i)
            pk[i] = (unsigned)f2bf(f[2 * i]) | ((unsigned)f2bf(f[2 * i + 1]) << 16);
        char* dp = (char*)At + n * (AP * 2) + q * 48;
        *reinterpret_cast<uint4*>(dp + 0)  = make_uint4(pk[0], pk[1], pk[2], pk[3]);
        *reinterpret_cast<uint4*>(dp + 16) = make_uint4(pk[4], pk[5], pk[6], pk[7]);
        *reinterpret_cast<uint4*>(dp + 32) = make_uint4(pk[8], pk[9], pk[10], pk[11]);
    }
    __syncthreads();

    const int w = tid >> 6;
    const int l = tid & 63;
    const int col = l & 15;
    const int kg = l >> 4;
    const char* Ab = (const char*)At + (w * 16 + col) * (AP * 2) + kg * 16;
    const char* Bb = (const char*)Wt + col * (AP * 2) + kg * 16;

    f32x4 acc[8];
#pragma unroll
    for (int ct = 0; ct < 8; ++ct) acc[ct] = (f32x4){0.f, 0.f, 0.f, 0.f};

#pragma unroll
    for (int ks = 0; ks < 3; ++ks) {
        bf16x8 af = *reinterpret_cast<const bf16x8*>(Ab + ks * 64);
#pragma unroll
        for (int ct = 0; ct < 8; ++ct) {
            bf16x8 bfr = *reinterpret_cast<const bf16x8*>(Bb + ct * 16 * (AP * 2) + ks * 64);
            acc[ct] = __builtin_amdgcn_mfma_f32_16x16x32_bf16(af, bfr, acc[ct], 0, 0, 0);
        }
    }

    float s0 = 0.f, s1 = 0.f, s2 = 0.f, s3 = 0.f;
#pragma unroll
    for (int ct = 0; ct < 8; ++ct) {
        float wo = Wo[ct * 16 + col];
        s0 = fmaf(fmaxf(acc[ct][0], 0.f), wo, s0);
        s1 = fmaf(fmaxf(acc[ct][1], 0.f), wo, s1);
        s2 = fmaf(fmaxf(acc[ct][2], 0.f), wo, s2);
        s3 = fmaf(fmaxf(acc[ct][3], 0.f), wo, s3);
    }
#pragma unroll
    for (int m = 1; m < 16; m <<= 1) {
        s0 += __shfl_xor(s0, m);
        s1 += __shfl_xor(s1, m);
        s2 += __shfl_xor(s2, m);
        s3 += __shfl_xor(s3, m);
    }
    if (col == 0) {
        int row = blockIdx.x * 64 + w * 16 + kg * 4;
        if (row + 0 < NN) out_rain[row + 0] = rain0[row + 0] + s0;
        if (row + 1 < NN) out_rain[row + 1] = rain0[row + 1] + s1;
        if (row + 2 < NN) out_rain[row + 2] = rain0[row + 2] + s2;
        if (row + 3 < NN) out_rain[row + 3] = rain0[row + 3] + s3;
    }
}

extern "C" void kernel_launch(void* const* d_in, const int* in_sizes, int n_in,
                              void* d_out, int out_size, void* d_ws, size_t ws_size,
                              hipStream_t stream) {
    const float* h_feat  = (const float*)d_in[0];
    const float* e_feat  = (const float*)d_in[1];
    const float* rain0   = (const float*)d_in[2];
    const float* w_xx    = (const float*)d_in[3];
    const float* w_yy    = (const float*)d_in[4];
    const float* W_trans = (const float*)d_in[5];
    const float* W_rin   = (const float*)d_in[6];
    const float* W_rout  = (const float*)d_in[7];
    const int* src_xx    = (const int*)d_in[8];
    const int* dst_xx    = (const int*)d_in[9];
    const int* src_yy    = (const int*)d_in[10];
    const int* dst_yy    = (const int*)d_in[11];

    float* ws = (float*)d_ws;
    float* emh = ws;                           // NN*32 floats (reused as g2x/g2y)
    float* gx  = emh + (size_t)NN * 32;        // NN*16
    float* gy  = gx + (size_t)NN * 16;         // NN*16
    float* g2x = emh;                          // alias (emh dead after pull1)
    float* g2y = emh + (size_t)NN * 16;

    int2* csr_xx = (int2*)(gy + (size_t)NN * 16);  // EE int2
    int2* csr_yy = csr_xx + EE;                    // EE int2
    int* off_xx  = (int*)(csr_yy + EE);            // OFFP ints
    int* off_yy  = off_xx + OFFP;                  // OFFP ints
    int* cur_xx  = off_yy + OFFP;                  // NN ints
    int* cur_yy  = cur_xx + NN;                    // NN ints
    int* bsum    = cur_yy + NN;                    // 64
    int* bbase   = bsum + 64;                      // 64

    float* out_rain = (float*)d_out;           // NN
    float* out_h    = out_rain + NN;           // NN*32

    hipMemsetAsync(cur_xx, 0, (size_t)2 * NN * sizeof(int), stream);

    const int TB = (NN * 32 + 255) / 256;                  // 12500 trans blocks
    const int HB = (2 * EE / EPT + 255) / 256;             // 1563 hist chunk-blocks
    fused_th_k<<<TB + HB * NRANGE, 256, 0, stream>>>(h_feat, e_feat, W_trans, emh,
                                                     dst_xx, dst_yy, cur_xx, cur_yy, TB);

    scanA_k<<<2 * NB, 1024, 0, stream>>>(cur_xx, cur_yy, bsum);
    scanB_k<<<1, 64, 0, stream>>>(bsum, bbase, off_xx, off_yy);
    scanC_k<<<2 * NB, 1024, 0, stream>>>(cur_xx, cur_yy, off_xx, off_yy, bbase);

    const int SB = ((2 * EE / EPT + 255) / 256) * NRANGE;
    scatter_k<<<SB, 256, 0, stream>>>(
        dst_xx, src_xx, w_xx, dst_yy, src_yy, w_yy, cur_xx, cur_yy, csr_xx, csr_yy);

    pull1_k<<<(NN * 32 + 255) / 256, 256, 0, stream>>>(
        emh, e_feat, csr_xx, off_xx, csr_yy, off_yy, out_h, gx, gy);

    pull2_k<<<(NN * 16 + 255) / 256, 256, 0, stream>>>(
        gx, gy, csr_xx, off_xx, csr_yy, off_yy, g2x, g2y);

    final_mfma_k<<<(NN + 63) / 64, 256, 0, stream>>>(
        out_h, gx, gy, g2x, g2y, rain0, W_rin, W_rout, out_rain);
}

// Round 7
// 434.053 us; speedup vs baseline: 6.3490x; 1.1577x over previous
//
#include <hip/hip_runtime.h>
#include <hip/hip_bf16.h>

#define NN 100000
#define EE 1600000
#define SCAN_CHUNK 4096
#define NB ((NN + SCAN_CHUNK - 1) / SCAN_CHUNK)   // 25 scan blocks per type
#define OFFP (NN + 8)                             // padded off array
#define NRANGE 8                                  // dst ranges (== XCDs)
#define RSZ (NN / NRANGE)                         // 12500 nodes per range
#define C_CH 16                                   // edge chunks per type
#define CHUNK_E (EE / C_CH)                       // 100000 edges per chunk
#define AP 104                                    // bf16 LDS row pad (208 B)

typedef __attribute__((ext_vector_type(8))) short bf16x8;
typedef __attribute__((ext_vector_type(4))) float f32x4;

__device__ inline unsigned short f2bf(float f) {
    unsigned u = __float_as_uint(f);
    return (unsigned short)((u + 0x7FFFu + ((u >> 16) & 1u)) >> 16);
}

// ---------------- trans: emh = relu(cat(h,e) @ W_trans) ----------------
__global__ __launch_bounds__(256) void trans_k(const float* __restrict__ h_feat,
                                               const float* __restrict__ e_feat,
                                               const float* __restrict__ W_trans,
                                               float* __restrict__ emh) {
    __shared__ float Wl[48 * 32];
    for (int i = threadIdx.x; i < 48 * 32; i += 256) Wl[i] = W_trans[i];
    __syncthreads();
    int t = blockIdx.x * 256 + threadIdx.x;
    if (t >= NN * 32) return;
    int n = t >> 5, j = t & 31;
    const float* hrow = h_feat + (size_t)n * 32;
    const float* erow = e_feat + (size_t)n * 16;
    float acc = 0.f;
#pragma unroll 8
    for (int k = 0; k < 32; ++k) acc = fmaf(hrow[k], Wl[k * 32 + j], acc);
#pragma unroll 8
    for (int k = 0; k < 16; ++k) acc = fmaf(erow[k], Wl[(32 + k) * 32 + j], acc);
    emh[t] = fmaxf(acc, 0.f);
}

// ---------------- hist: LDS histogram, zero global atomics ----------------
// 256 blocks: t = bid>>7, r = bid&7, c = (bid>>3)&15.
// Block streams chunk c of type t, LDS-counts dst in range r, writes
// partial[t][c][r*RSZ .. ) as plain coalesced stores.
__global__ __launch_bounds__(256) void hist_k(const int* __restrict__ dst_a,
                                              const int* __restrict__ dst_b,
                                              int* __restrict__ partial) {
    __shared__ int bins[RSZ];
    for (int i = threadIdx.x; i < RSZ; i += 256) bins[i] = 0;
    __syncthreads();
    const int bid = blockIdx.x;
    const int t = bid >> 7;
    const int r = bid & 7;
    const int c = (bid >> 3) & 15;
    const int* dst = t ? dst_b : dst_a;
    const int lo = r * RSZ;
    const long base = (long)c * CHUNK_E;
    for (int i = threadIdx.x * 4; i < CHUNK_E; i += 1024) {
        int4 d = *reinterpret_cast<const int4*>(dst + base + i);
        int x;
        x = d.x - lo; if ((unsigned)x < RSZ) atomicAdd(&bins[x], 1);
        x = d.y - lo; if ((unsigned)x < RSZ) atomicAdd(&bins[x], 1);
        x = d.z - lo; if ((unsigned)x < RSZ) atomicAdd(&bins[x], 1);
        x = d.w - lo; if ((unsigned)x < RSZ) atomicAdd(&bins[x], 1);
    }
    __syncthreads();
    int* pout = partial + (long)(t * C_CH + c) * NN + lo;
    for (int i = threadIdx.x; i < RSZ; i += 256) pout[i] = bins[i];
}

// ---------------- scan phase A: per-4096-node-chunk totals ----------------
__global__ __launch_bounds__(1024) void scanA_k(const int* __restrict__ partial,
                                                int* __restrict__ bsum) {
    __shared__ int wsum[16];
    const int b = blockIdx.x;              // 0..2*NB-1
    const int t = (b >= NB) ? 1 : 0;
    const int i0 = (b % NB) * SCAN_CHUNK + threadIdx.x * 4;
    int4 s = make_int4(0, 0, 0, 0);
    if (i0 < NN) {
#pragma unroll
        for (int c = 0; c < C_CH; ++c) {
            int4 v = *reinterpret_cast<const int4*>(partial + (long)(t * C_CH + c) * NN + i0);
            s.x += v.x; s.y += v.y; s.z += v.z; s.w += v.w;
        }
    }
    int tot = s.x + s.y + s.z + s.w;
#pragma unroll
    for (int d = 32; d; d >>= 1) tot += __shfl_down(tot, d);
    int lane = threadIdx.x & 63, w = threadIdx.x >> 6;
    if (lane == 0) wsum[w] = tot;
    __syncthreads();
    if (threadIdx.x == 0) {
        int sm = 0;
#pragma unroll
        for (int q = 0; q < 16; ++q) sm += wsum[q];
        bsum[b] = sm;
    }
}

// ---------------- scan phase B: segmented exclusive scan of block sums ------
__global__ __launch_bounds__(64) void scanB_k(const int* __restrict__ bsum,
                                              int* __restrict__ bbase,
                                              int* __restrict__ off_a,
                                              int* __restrict__ off_b) {
    int lane = threadIdx.x;
    int v = (lane < 2 * NB) ? bsum[lane] : 0;
    int seg = lane / NB;
    int inc = v;
#pragma unroll
    for (int d = 1; d < 64; d <<= 1) {
        int x = __shfl_up(inc, d);
        if (lane >= d && (lane - d) / NB == seg) inc += x;
    }
    int excl = inc - v;
    if (lane < 2 * NB) bbase[lane] = excl;
    if (lane == NB - 1) off_a[NN] = inc;
    if (lane == 2 * NB - 1) off_b[NN] = inc;
}

// ---- scan phase C: off[] = exclusive node scan; partial -> per-chunk cursors ----
__global__ __launch_bounds__(1024) void scanC_k(int* __restrict__ partial,
                                                int* __restrict__ off_a,
                                                int* __restrict__ off_b,
                                                const int* __restrict__ bbase) {
    __shared__ int wsum[16];
    const int b = blockIdx.x;
    const int t = (b >= NB) ? 1 : 0;
    int* off = t ? off_b : off_a;
    const int base0 = bbase[b];
    const int i0 = (b % NB) * SCAN_CHUNK + threadIdx.x * 4;
    int4 s = make_int4(0, 0, 0, 0);
    if (i0 < NN) {
#pragma unroll
        for (int c = 0; c < C_CH; ++c) {
            int4 v = *reinterpret_cast<const int4*>(partial + (long)(t * C_CH + c) * NN + i0);
            s.x += v.x; s.y += v.y; s.z += v.z; s.w += v.w;
        }
    }
    int s1 = s.x, s2 = s1 + s.y, s3 = s2 + s.z, tot = s3 + s.w;
    int lane = threadIdx.x & 63, w = threadIdx.x >> 6;
    int inc = tot;
#pragma unroll
    for (int d = 1; d < 64; d <<= 1) {
        int x = __shfl_up(inc, d);
        if (lane >= d) inc += x;
    }
    if (lane == 63) wsum[w] = inc;
    int texcl = inc - tot;
    __syncthreads();
    if (threadIdx.x == 0) {
        int r = 0;
#pragma unroll
        for (int q = 0; q < 16; ++q) { int x = wsum[q]; wsum[q] = r; r += x; }
    }
    __syncthreads();
    const int base = base0 + wsum[w] + texcl;
    if (i0 < NN) {
        *reinterpret_cast<int4*>(off + i0) = make_int4(base, base + s1, base + s2, base + s3);
        int4 run = make_int4(base, base + s1, base + s2, base + s3);
#pragma unroll
        for (int c = 0; c < C_CH; ++c) {
            int* p = partial + (long)(t * C_CH + c) * NN + i0;
            int4 v = *reinterpret_cast<const int4*>(p);
            *reinterpret_cast<int4*>(p) = run;
            run.x += v.x; run.y += v.y; run.z += v.z; run.w += v.w;
        }
    }
}

// ---------------- scatter: LDS cursors, zero global atomics ----------------
// Same decode as hist. Cursors for range r, chunk c come from rewritten partial.
// csr window of range r is written only by blocks with bid%8==r (XCD-local).
__global__ __launch_bounds__(256) void scatter_k(const int* __restrict__ dst_a,
                                                 const int* __restrict__ src_a,
                                                 const float* __restrict__ w_a,
                                                 const int* __restrict__ dst_b,
                                                 const int* __restrict__ src_b,
                                                 const float* __restrict__ w_b,
                                                 const int* __restrict__ partial,
                                                 int2* __restrict__ csr_a,
                                                 int2* __restrict__ csr_b) {
    __shared__ int curs[RSZ];
    const int bid = blockIdx.x;
    const int t = bid >> 7;
    const int r = bid & 7;
    const int c = (bid >> 3) & 15;
    const int* dst = t ? dst_b : dst_a;
    const int* src = t ? src_b : src_a;
    const float* wv = t ? w_b : w_a;
    int2* csr = t ? csr_b : csr_a;
    const int lo = r * RSZ;
    const int* pin = partial + (long)(t * C_CH + c) * NN + lo;
    for (int i = threadIdx.x; i < RSZ; i += 256) curs[i] = pin[i];
    __syncthreads();
    const long base = (long)c * CHUNK_E;
    for (int i = threadIdx.x * 4; i < CHUNK_E; i += 1024) {
        int4 d = *reinterpret_cast<const int4*>(dst + base + i);
        int x;
        x = d.x - lo;
        if ((unsigned)x < RSZ) {
            int p = atomicAdd(&curs[x], 1);
            csr[p] = make_int2(src[base + i], __float_as_int(wv[base + i]));
        }
        x = d.y - lo;
        if ((unsigned)x < RSZ) {
            int p = atomicAdd(&curs[x], 1);
            csr[p] = make_int2(src[base + i + 1], __float_as_int(wv[base + i + 1]));
        }
        x = d.z - lo;
        if ((unsigned)x < RSZ) {
            int p = atomicAdd(&curs[x], 1);
            csr[p] = make_int2(src[base + i + 2], __float_as_int(wv[base + i + 2]));
        }
        x = d.w - lo;
        if ((unsigned)x < RSZ) {
            int p = atomicAdd(&curs[x], 1);
            csr[p] = make_int2(src[base + i + 3], __float_as_int(wv[base + i + 3]));
        }
    }
}

// ---------------- pull1: h, gx, gy (32 lanes/node, no atomics, unroll 4) --------
__global__ __launch_bounds__(256) void pull1_k(const float* __restrict__ emh,
                                               const float* __restrict__ e_feat,
                                               const int2* __restrict__ csr_a,
                                               const int* __restrict__ off_a,
                                               const int2* __restrict__ csr_b,
                                               const int* __restrict__ off_b,
                                               float* __restrict__ out_h,
                                               float* __restrict__ gx,
                                               float* __restrict__ gy) {
    int g = blockIdx.x * 256 + threadIdx.x;
    int n = g >> 5, j = g & 31;
    if (n >= NN) return;
    float acc_h = 0.f;

#pragma unroll
    for (int half = 0; half < 2; ++half) {
        const int2* csr = half ? csr_b : csr_a;
        const int* off = half ? off_b : off_a;
        float* gout = half ? gy : gx;
        float acc_g = 0.f, sumw = 0.f;
        int k = off[n], e2 = off[n + 1];
        for (; k + 3 < e2; k += 4) {
            int2 s0 = csr[k], s1 = csr[k + 1], s2 = csr[k + 2], s3 = csr[k + 3];
            float m0 = emh[(size_t)s0.x * 32 + j];
            float m1 = emh[(size_t)s1.x * 32 + j];
            float m2 = emh[(size_t)s2.x * 32 + j];
            float m3 = emh[(size_t)s3.x * 32 + j];
            acc_h += (m0 + m1) + (m2 + m3);
            if (j < 16) {
                float w0 = __int_as_float(s0.y), w1 = __int_as_float(s1.y);
                float w2 = __int_as_float(s2.y), w3 = __int_as_float(s3.y);
                acc_g = fmaf(w0, e_feat[(size_t)s0.x * 16 + j], acc_g);
                acc_g = fmaf(w1, e_feat[(size_t)s1.x * 16 + j], acc_g);
                acc_g = fmaf(w2, e_feat[(size_t)s2.x * 16 + j], acc_g);
                acc_g = fmaf(w3, e_feat[(size_t)s3.x * 16 + j], acc_g);
                sumw += (w0 + w1) + (w2 + w3);
            }
        }
        for (; k < e2; ++k) {
            int2 s0 = csr[k];
            acc_h += emh[(size_t)s0.x * 32 + j];
            if (j < 16) {
                float w0 = __int_as_float(s0.y);
                acc_g = fmaf(w0, e_feat[(size_t)s0.x * 16 + j], acc_g);
                sumw += w0;
            }
        }
        if (j < 16) gout[(size_t)n * 16 + j] = acc_g - sumw * e_feat[(size_t)n * 16 + j];
    }
    out_h[(size_t)n * 32 + j] = fmaxf(acc_h, 0.f);
}

// ---------------- pull2: g2x, g2y (16 lanes/node, unroll 4) ----------------
__global__ __launch_bounds__(256) void pull2_k(const float* __restrict__ gx,
                                               const float* __restrict__ gy,
                                               const int2* __restrict__ csr_a,
                                               const int* __restrict__ off_a,
                                               const int2* __restrict__ csr_b,
                                               const int* __restrict__ off_b,
                                               float* __restrict__ g2x,
                                               float* __restrict__ g2y) {
    int g = blockIdx.x * 256 + threadIdx.x;
    int n = g >> 4, j = g & 15;
    if (n >= NN) return;

#pragma unroll
    for (int half = 0; half < 2; ++half) {
        const int2* csr = half ? csr_b : csr_a;
        const int* off = half ? off_b : off_a;
        const float* gin = half ? gy : gx;
        float* g2 = half ? g2y : g2x;
        float acc = 0.f, sumw = 0.f;
        int k = off[n], e2 = off[n + 1];
        for (; k + 3 < e2; k += 4) {
            int2 s0 = csr[k], s1 = csr[k + 1], s2 = csr[k + 2], s3 = csr[k + 3];
            float w0 = __int_as_float(s0.y), w1 = __int_as_float(s1.y);
            float w2 = __int_as_float(s2.y), w3 = __int_as_float(s3.y);
            acc = fmaf(w0, gin[(size_t)s0.x * 16 + j], acc);
            acc = fmaf(w1, gin[(size_t)s1.x * 16 + j], acc);
            acc = fmaf(w2, gin[(size_t)s2.x * 16 + j], acc);
            acc = fmaf(w3, gin[(size_t)s3.x * 16 + j], acc);
            sumw += (w0 + w1) + (w2 + w3);
        }
        for (; k < e2; ++k) {
            int2 s0 = csr[k];
            float w0 = __int_as_float(s0.y);
            acc = fmaf(w0, gin[(size_t)s0.x * 16 + j], acc);
            sumw += w0;
        }
        g2[(size_t)n * 16 + j] = acc - sumw * gin[(size_t)n * 16 + j];
    }
}

// ---------------- final head: bf16 MFMA GEMM (64 nodes/block) ----------------
__global__ __launch_bounds__(256) void final_mfma_k(const float* __restrict__ h,
                                                    const float* __restrict__ gx,
                                                    const float* __restrict__ gy,
                                                    const float* __restrict__ g2x,
                                                    const float* __restrict__ g2y,
                                                    const float* __restrict__ rain0,
                                                    const float* __restrict__ W_rin,
                                                    const float* __restrict__ W_rout,
                                                    float* __restrict__ out_rain) {
    __shared__ __align__(16) unsigned short Wt[128 * AP];  // 26.6 KB
    __shared__ __align__(16) unsigned short At[64 * AP];   // 13.3 KB
    __shared__ float Wo[128];
    const int tid = threadIdx.x;

    for (int i = tid; i < 3072; i += 256) {
        int k = i >> 5;
        int c = (i & 31) * 4;
        float4 wv = *reinterpret_cast<const float4*>(W_rin + k * 128 + c);
        Wt[(c + 0) * AP + k] = f2bf(wv.x);
        Wt[(c + 1) * AP + k] = f2bf(wv.y);
        Wt[(c + 2) * AP + k] = f2bf(wv.z);
        Wt[(c + 3) * AP + k] = f2bf(wv.w);
    }
    if (tid < 128) Wo[tid] = W_rout[tid];

    {
        int n = tid >> 2, q = tid & 3;
        int node = blockIdx.x * 64 + n;
        float f[24];
#define LD4(di, p) { float4 v_ = *reinterpret_cast<const float4*>(p); \
                     f[di] = v_.x; f[di+1] = v_.y; f[di+2] = v_.z; f[di+3] = v_.w; }
        if (node < NN) {
            if (q == 0) {
                LD4(0,  h + (size_t)node * 32 + 0);
                LD4(4,  h + (size_t)node * 32 + 4);
                LD4(8,  h + (size_t)node * 32 + 8);
                LD4(12, h + (size_t)node * 32 + 12);
                LD4(16, h + (size_t)node * 32 + 16);
                LD4(20, h + (size_t)node * 32 + 20);
            } else if (q == 1) {
                LD4(0,  h + (size_t)node * 32 + 24);
                LD4(4,  h + (size_t)node * 32 + 28);
                LD4(8,  gx + (size_t)node * 16 + 0);
                LD4(12, gx + (size_t)node * 16 + 4);
                LD4(16, gx + (size_t)node * 16 + 8);
                LD4(20, gx + (size_t)node * 16 + 12);
            } else if (q == 2) {
                LD4(0,  gy + (size_t)node * 16 + 0);
                LD4(4,  gy + (size_t)node * 16 + 4);
                LD4(8,  gy + (size_t)node * 16 + 8);
                LD4(12, gy + (size_t)node * 16 + 12);
                LD4(16, g2x + (size_t)node * 16 + 0);
                LD4(20, g2x + (size_t)node * 16 + 4);
            } else {
                LD4(0,  g2x + (size_t)node * 16 + 8);
                LD4(4,  g2x + (size_t)node * 16 + 12);
                LD4(8,  g2y + (size_t)node * 16 + 0);
                LD4(12, g2y + (size_t)node * 16 + 4);
                LD4(16, g2y + (size_t)node * 16 + 8);
                LD4(20, g2y + (size_t)node * 16 + 12);
            }
        } else {
#pragma unroll
            for (int i = 0; i < 24; ++i) f[i] = 0.f;
        }
#undef LD4
        unsigned pk[12];
#pragma unroll
        for (int i = 0; i < 12; ++i)
            pk[i] = (unsigned)f2bf(f[2 * i]) | ((unsigned)f2bf(f[2 * i + 1]) << 16);
        char* dp = (char*)At + n * (AP * 2) + q * 48;
        *reinterpret_cast<uint4*>(dp + 0)  = make_uint4(pk[0], pk[1], pk[2], pk[3]);
        *reinterpret_cast<uint4*>(dp + 16) = make_uint4(pk[4], pk[5], pk[6], pk[7]);
        *reinterpret_cast<uint4*>(dp + 32) = make_uint4(pk[8], pk[9], pk[10], pk[11]);
    }
    __syncthreads();

    const int w = tid >> 6;
    const int l = tid & 63;
    const int col = l & 15;
    const int kg = l >> 4;
    const char* Ab = (const char*)At + (w * 16 + col) * (AP * 2) + kg * 16;
    const char* Bb = (const char*)Wt + col * (AP * 2) + kg * 16;

    f32x4 acc[8];
#pragma unroll
    for (int ct = 0; ct < 8; ++ct) acc[ct] = (f32x4){0.f, 0.f, 0.f, 0.f};

#pragma unroll
    for (int ks = 0; ks < 3; ++ks) {
        bf16x8 af = *reinterpret_cast<const bf16x8*>(Ab + ks * 64);
#pragma unroll
        for (int ct = 0; ct < 8; ++ct) {
            bf16x8 bfr = *reinterpret_cast<const bf16x8*>(Bb + ct * 16 * (AP * 2) + ks * 64);
            acc[ct] = __builtin_amdgcn_mfma_f32_16x16x32_bf16(af, bfr, acc[ct], 0, 0, 0);
        }
    }

    float s0 = 0.f, s1 = 0.f, s2 = 0.f, s3 = 0.f;
#pragma unroll
    for (int ct = 0; ct < 8; ++ct) {
        float wo = Wo[ct * 16 + col];
        s0 = fmaf(fmaxf(acc[ct][0], 0.f), wo, s0);
        s1 = fmaf(fmaxf(acc[ct][1], 0.f), wo, s1);
        s2 = fmaf(fmaxf(acc[ct][2], 0.f), wo, s2);
        s3 = fmaf(fmaxf(acc[ct][3], 0.f), wo, s3);
    }
#pragma unroll
    for (int m = 1; m < 16; m <<= 1) {
        s0 += __shfl_xor(s0, m);
        s1 += __shfl_xor(s1, m);
        s2 += __shfl_xor(s2, m);
        s3 += __shfl_xor(s3, m);
    }
    if (col == 0) {
        int row = blockIdx.x * 64 + w * 16 + kg * 4;
        if (row + 0 < NN) out_rain[row + 0] = rain0[row + 0] + s0;
        if (row + 1 < NN) out_rain[row + 1] = rain0[row + 1] + s1;
        if (row + 2 < NN) out_rain[row + 2] = rain0[row + 2] + s2;
        if (row + 3 < NN) out_rain[row + 3] = rain0[row + 3] + s3;
    }
}

extern "C" void kernel_launch(void* const* d_in, const int* in_sizes, int n_in,
                              void* d_out, int out_size, void* d_ws, size_t ws_size,
                              hipStream_t stream) {
    const float* h_feat  = (const float*)d_in[0];
    const float* e_feat  = (const float*)d_in[1];
    const float* rain0   = (const float*)d_in[2];
    const float* w_xx    = (const float*)d_in[3];
    const float* w_yy    = (const float*)d_in[4];
    const float* W_trans = (const float*)d_in[5];
    const float* W_rin   = (const float*)d_in[6];
    const float* W_rout  = (const float*)d_in[7];
    const int* src_xx    = (const int*)d_in[8];
    const int* dst_xx    = (const int*)d_in[9];
    const int* src_yy    = (const int*)d_in[10];
    const int* dst_yy    = (const int*)d_in[11];

    float* ws = (float*)d_ws;
    float* emh = ws;                           // NN*32 floats (reused as g2x/g2y)
    float* gx  = emh + (size_t)NN * 32;        // NN*16
    float* gy  = gx + (size_t)NN * 16;         // NN*16
    float* g2x = emh;                          // alias (emh dead after pull1)
    float* g2y = emh + (size_t)NN * 16;

    int2* csr_xx = (int2*)(gy + (size_t)NN * 16);  // EE int2
    int2* csr_yy = csr_xx + EE;                    // EE int2
    int* off_xx  = (int*)(csr_yy + EE);            // OFFP ints
    int* off_yy  = off_xx + OFFP;                  // OFFP ints
    int* partial = off_yy + OFFP;                  // 2*C_CH*NN ints (12.8MB)
    int* bsum    = partial + (size_t)2 * C_CH * NN; // 64
    int* bbase   = bsum + 64;                      // 64

    float* out_rain = (float*)d_out;           // NN
    float* out_h    = out_rain + NN;           // NN*32

    trans_k<<<(NN * 32 + 255) / 256, 256, 0, stream>>>(h_feat, e_feat, W_trans, emh);

    hist_k<<<2 * NRANGE * C_CH, 256, 0, stream>>>(dst_xx, dst_yy, partial);

    scanA_k<<<2 * NB, 1024, 0, stream>>>(partial, bsum);
    scanB_k<<<1, 64, 0, stream>>>(bsum, bbase, off_xx, off_yy);
    scanC_k<<<2 * NB, 1024, 0, stream>>>(partial, off_xx, off_yy, bbase);

    scatter_k<<<2 * NRANGE * C_CH, 256, 0, stream>>>(
        dst_xx, src_xx, w_xx, dst_yy, src_yy, w_yy, partial, csr_xx, csr_yy);

    pull1_k<<<(NN * 32 + 255) / 256, 256, 0, stream>>>(
        emh, e_feat, csr_xx, off_xx, csr_yy, off_yy, out_h, gx, gy);

    pull2_k<<<(NN * 16 + 255) / 256, 256, 0, stream>>>(
        gx, gy, csr_xx, off_xx, csr_yy, off_yy, g2x, g2y);

    final_mfma_k<<<(NN + 63) / 64, 256, 0, stream>>>(
        out_h, gx, gy, g2x, g2y, rain0, W_rin, W_rout, out_rain);
}

// Round 8
// 343.166 us; speedup vs baseline: 8.0305x; 1.2648x over previous
//
#include <hip/hip_runtime.h>
#include <hip/hip_bf16.h>

#define NN 100000
#define EE 1600000
#define SCAN_CHUNK 4096
#define NB ((NN + SCAN_CHUNK - 1) / SCAN_CHUNK)   // 25 scan blocks per type
#define OFFP (NN + 8)                             // padded off array
#define NRANGE 8                                  // dst ranges (== XCDs)
#define RSZ (NN / NRANGE)                         // 12500 nodes per range
#define C_CH 16                                   // edge chunks per type
#define CHUNK_E (EE / C_CH)                       // 100000 edges per chunk
#define AP 104                                    // bf16 LDS row pad (208 B)

typedef __attribute__((ext_vector_type(8))) short bf16x8;
typedef __attribute__((ext_vector_type(4))) float f32x4;

__device__ inline unsigned short f2bf(float f) {
    unsigned u = __float_as_uint(f);
    return (unsigned short)((u + 0x7FFFu + ((u >> 16) & 1u)) >> 16);
}

// ---------------- trans: emh = relu(cat(h,e) @ W_trans) ----------------
__global__ __launch_bounds__(256) void trans_k(const float* __restrict__ h_feat,
                                               const float* __restrict__ e_feat,
                                               const float* __restrict__ W_trans,
                                               float* __restrict__ emh) {
    __shared__ float Wl[48 * 32];
    for (int i = threadIdx.x; i < 48 * 32; i += 256) Wl[i] = W_trans[i];
    __syncthreads();
    int t = blockIdx.x * 256 + threadIdx.x;
    if (t >= NN * 32) return;
    int n = t >> 5, j = t & 31;
    const float* hrow = h_feat + (size_t)n * 32;
    const float* erow = e_feat + (size_t)n * 16;
    float acc = 0.f;
#pragma unroll 8
    for (int k = 0; k < 32; ++k) acc = fmaf(hrow[k], Wl[k * 32 + j], acc);
#pragma unroll 8
    for (int k = 0; k < 16; ++k) acc = fmaf(erow[k], Wl[(32 + k) * 32 + j], acc);
    emh[t] = fmaxf(acc, 0.f);
}

// ---------------- hist: LDS histogram, zero global atomics, 16 waves/block ------
// 256 blocks: t = bid>>7, r = bid&7, c = (bid>>3)&15.
__global__ __launch_bounds__(1024) void hist_k(const int* __restrict__ dst_a,
                                               const int* __restrict__ dst_b,
                                               int* __restrict__ partial) {
    __shared__ int bins[RSZ];
    for (int i = threadIdx.x; i < RSZ; i += 1024) bins[i] = 0;
    __syncthreads();
    const int bid = blockIdx.x;
    const int t = bid >> 7;
    const int r = bid & 7;
    const int c = (bid >> 3) & 15;
    const int* dst = t ? dst_b : dst_a;
    const int lo = r * RSZ;
    const long base = (long)c * CHUNK_E;
    for (int i = threadIdx.x * 4; i < CHUNK_E; i += 4096) {
        int4 d = *reinterpret_cast<const int4*>(dst + base + i);
        int x;
        x = d.x - lo; if ((unsigned)x < RSZ) atomicAdd(&bins[x], 1);
        x = d.y - lo; if ((unsigned)x < RSZ) atomicAdd(&bins[x], 1);
        x = d.z - lo; if ((unsigned)x < RSZ) atomicAdd(&bins[x], 1);
        x = d.w - lo; if ((unsigned)x < RSZ) atomicAdd(&bins[x], 1);
    }
    __syncthreads();
    int* pout = partial + (long)(t * C_CH + c) * NN + lo;
    for (int i = threadIdx.x; i < RSZ; i += 1024) pout[i] = bins[i];
}

// ---------------- scan phase A: per-4096-node-chunk totals ----------------
__global__ __launch_bounds__(1024) void scanA_k(const int* __restrict__ partial,
                                                int* __restrict__ bsum) {
    __shared__ int wsum[16];
    const int b = blockIdx.x;              // 0..2*NB-1
    const int t = (b >= NB) ? 1 : 0;
    const int i0 = (b % NB) * SCAN_CHUNK + threadIdx.x * 4;
    int4 s = make_int4(0, 0, 0, 0);
    if (i0 < NN) {
#pragma unroll
        for (int c = 0; c < C_CH; ++c) {
            int4 v = *reinterpret_cast<const int4*>(partial + (long)(t * C_CH + c) * NN + i0);
            s.x += v.x; s.y += v.y; s.z += v.z; s.w += v.w;
        }
    }
    int tot = s.x + s.y + s.z + s.w;
#pragma unroll
    for (int d = 32; d; d >>= 1) tot += __shfl_down(tot, d);
    int lane = threadIdx.x & 63, w = threadIdx.x >> 6;
    if (lane == 0) wsum[w] = tot;
    __syncthreads();
    if (threadIdx.x == 0) {
        int sm = 0;
#pragma unroll
        for (int q = 0; q < 16; ++q) sm += wsum[q];
        bsum[b] = sm;
    }
}

// ---------------- scan phase B: segmented exclusive scan of block sums ------
__global__ __launch_bounds__(64) void scanB_k(const int* __restrict__ bsum,
                                              int* __restrict__ bbase,
                                              int* __restrict__ off_a,
                                              int* __restrict__ off_b) {
    int lane = threadIdx.x;
    int v = (lane < 2 * NB) ? bsum[lane] : 0;
    int seg = lane / NB;
    int inc = v;
#pragma unroll
    for (int d = 1; d < 64; d <<= 1) {
        int x = __shfl_up(inc, d);
        if (lane >= d && (lane - d) / NB == seg) inc += x;
    }
    int excl = inc - v;
    if (lane < 2 * NB) bbase[lane] = excl;
    if (lane == NB - 1) off_a[NN] = inc;
    if (lane == 2 * NB - 1) off_b[NN] = inc;
}

// ---- scan phase C: off[] = exclusive node scan; partial -> per-chunk cursors ----
__global__ __launch_bounds__(1024) void scanC_k(int* __restrict__ partial,
                                                int* __restrict__ off_a,
                                                int* __restrict__ off_b,
                                                const int* __restrict__ bbase) {
    __shared__ int wsum[16];
    const int b = blockIdx.x;
    const int t = (b >= NB) ? 1 : 0;
    int* off = t ? off_b : off_a;
    const int base0 = bbase[b];
    const int i0 = (b % NB) * SCAN_CHUNK + threadIdx.x * 4;
    int4 s = make_int4(0, 0, 0, 0);
    if (i0 < NN) {
#pragma unroll
        for (int c = 0; c < C_CH; ++c) {
            int4 v = *reinterpret_cast<const int4*>(partial + (long)(t * C_CH + c) * NN + i0);
            s.x += v.x; s.y += v.y; s.z += v.z; s.w += v.w;
        }
    }
    int s1 = s.x, s2 = s1 + s.y, s3 = s2 + s.z, tot = s3 + s.w;
    int lane = threadIdx.x & 63, w = threadIdx.x >> 6;
    int inc = tot;
#pragma unroll
    for (int d = 1; d < 64; d <<= 1) {
        int x = __shfl_up(inc, d);
        if (lane >= d) inc += x;
    }
    if (lane == 63) wsum[w] = inc;
    int texcl = inc - tot;
    __syncthreads();
    if (threadIdx.x == 0) {
        int r = 0;
#pragma unroll
        for (int q = 0; q < 16; ++q) { int x = wsum[q]; wsum[q] = r; r += x; }
    }
    __syncthreads();
    const int base = base0 + wsum[w] + texcl;
    if (i0 < NN) {
        *reinterpret_cast<int4*>(off + i0) = make_int4(base, base + s1, base + s2, base + s3);
        int4 run = make_int4(base, base + s1, base + s2, base + s3);
#pragma unroll
        for (int c = 0; c < C_CH; ++c) {
            int* p = partial + (long)(t * C_CH + c) * NN + i0;
            int4 v = *reinterpret_cast<const int4*>(p);
            *reinterpret_cast<int4*>(p) = run;
            run.x += v.x; run.y += v.y; run.z += v.z; run.w += v.w;
        }
    }
}

// ---------------- scatter: LDS cursors, zero global atomics, 16 waves/block ------
__global__ __launch_bounds__(1024) void scatter_k(const int* __restrict__ dst_a,
                                                  const int* __restrict__ src_a,
                                                  const float* __restrict__ w_a,
                                                  const int* __restrict__ dst_b,
                                                  const int* __restrict__ src_b,
                                                  const float* __restrict__ w_b,
                                                  const int* __restrict__ partial,
                                                  int2* __restrict__ csr_a,
                                                  int2* __restrict__ csr_b) {
    __shared__ int curs[RSZ];
    const int bid = blockIdx.x;
    const int t = bid >> 7;
    const int r = bid & 7;
    const int c = (bid >> 3) & 15;
    const int* dst = t ? dst_b : dst_a;
    const int* src = t ? src_b : src_a;
    const float* wv = t ? w_b : w_a;
    int2* csr = t ? csr_b : csr_a;
    const int lo = r * RSZ;
    const int* pin = partial + (long)(t * C_CH + c) * NN + lo;
    for (int i = threadIdx.x; i < RSZ; i += 1024) curs[i] = pin[i];
    __syncthreads();
    const long base = (long)c * CHUNK_E;
    for (int i = threadIdx.x * 4; i < CHUNK_E; i += 4096) {
        int4 d = *reinterpret_cast<const int4*>(dst + base + i);
        int x;
        x = d.x - lo;
        if ((unsigned)x < RSZ) {
            int p = atomicAdd(&curs[x], 1);
            csr[p] = make_int2(src[base + i], __float_as_int(wv[base + i]));
        }
        x = d.y - lo;
        if ((unsigned)x < RSZ) {
            int p = atomicAdd(&curs[x], 1);
            csr[p] = make_int2(src[base + i + 1], __float_as_int(wv[base + i + 1]));
        }
        x = d.z - lo;
        if ((unsigned)x < RSZ) {
            int p = atomicAdd(&curs[x], 1);
            csr[p] = make_int2(src[base + i + 2], __float_as_int(wv[base + i + 2]));
        }
        x = d.w - lo;
        if ((unsigned)x < RSZ) {
            int p = atomicAdd(&curs[x], 1);
            csr[p] = make_int2(src[base + i + 3], __float_as_int(wv[base + i + 3]));
        }
    }
}

// ---------------- pull1: h, gx, gy (32 lanes/node, no atomics, unroll 4) --------
__global__ __launch_bounds__(256) void pull1_k(const float* __restrict__ emh,
                                               const float* __restrict__ e_feat,
                                               const int2* __restrict__ csr_a,
                                               const int* __restrict__ off_a,
                                               const int2* __restrict__ csr_b,
                                               const int* __restrict__ off_b,
                                               float* __restrict__ out_h,
                                               float* __restrict__ gx,
                                               float* __restrict__ gy) {
    int g = blockIdx.x * 256 + threadIdx.x;
    int n = g >> 5, j = g & 31;
    if (n >= NN) return;
    float acc_h = 0.f;

#pragma unroll
    for (int half = 0; half < 2; ++half) {
        const int2* csr = half ? csr_b : csr_a;
        const int* off = half ? off_b : off_a;
        float* gout = half ? gy : gx;
        float acc_g = 0.f, sumw = 0.f;
        int k = off[n], e2 = off[n + 1];
        for (; k + 3 < e2; k += 4) {
            int2 s0 = csr[k], s1 = csr[k + 1], s2 = csr[k + 2], s3 = csr[k + 3];
            float m0 = emh[(size_t)s0.x * 32 + j];
            float m1 = emh[(size_t)s1.x * 32 + j];
            float m2 = emh[(size_t)s2.x * 32 + j];
            float m3 = emh[(size_t)s3.x * 32 + j];
            acc_h += (m0 + m1) + (m2 + m3);
            if (j < 16) {
                float w0 = __int_as_float(s0.y), w1 = __int_as_float(s1.y);
                float w2 = __int_as_float(s2.y), w3 = __int_as_float(s3.y);
                acc_g = fmaf(w0, e_feat[(size_t)s0.x * 16 + j], acc_g);
                acc_g = fmaf(w1, e_feat[(size_t)s1.x * 16 + j], acc_g);
                acc_g = fmaf(w2, e_feat[(size_t)s2.x * 16 + j], acc_g);
                acc_g = fmaf(w3, e_feat[(size_t)s3.x * 16 + j], acc_g);
                sumw += (w0 + w1) + (w2 + w3);
            }
        }
        for (; k < e2; ++k) {
            int2 s0 = csr[k];
            acc_h += emh[(size_t)s0.x * 32 + j];
            if (j < 16) {
                float w0 = __int_as_float(s0.y);
                acc_g = fmaf(w0, e_feat[(size_t)s0.x * 16 + j], acc_g);
                sumw += w0;
            }
        }
        if (j < 16) gout[(size_t)n * 16 + j] = acc_g - sumw * e_feat[(size_t)n * 16 + j];
    }
    out_h[(size_t)n * 32 + j] = fmaxf(acc_h, 0.f);
}

// ---------------- pull2: g2x, g2y (16 lanes/node, unroll 4) ----------------
__global__ __launch_bounds__(256) void pull2_k(const float* __restrict__ gx,
                                               const float* __restrict__ gy,
                                               const int2* __restrict__ csr_a,
                                               const int* __restrict__ off_a,
                                               const int2* __restrict__ csr_b,
                                               const int* __restrict__ off_b,
                                               float* __restrict__ g2x,
                                               float* __restrict__ g2y) {
    int g = blockIdx.x * 256 + threadIdx.x;
    int n = g >> 4, j = g & 15;
    if (n >= NN) return;

#pragma unroll
    for (int half = 0; half < 2; ++half) {
        const int2* csr = half ? csr_b : csr_a;
        const int* off = half ? off_b : off_a;
        const float* gin = half ? gy : gx;
        float* g2 = half ? g2y : g2x;
        float acc = 0.f, sumw = 0.f;
        int k = off[n], e2 = off[n + 1];
        for (; k + 3 < e2; k += 4) {
            int2 s0 = csr[k], s1 = csr[k + 1], s2 = csr[k + 2], s3 = csr[k + 3];
            float w0 = __int_as_float(s0.y), w1 = __int_as_float(s1.y);
            float w2 = __int_as_float(s2.y), w3 = __int_as_float(s3.y);
            acc = fmaf(w0, gin[(size_t)s0.x * 16 + j], acc);
            acc = fmaf(w1, gin[(size_t)s1.x * 16 + j], acc);
            acc = fmaf(w2, gin[(size_t)s2.x * 16 + j], acc);
            acc = fmaf(w3, gin[(size_t)s3.x * 16 + j], acc);
            sumw += (w0 + w1) + (w2 + w3);
        }
        for (; k < e2; ++k) {
            int2 s0 = csr[k];
            float w0 = __int_as_float(s0.y);
            acc = fmaf(w0, gin[(size_t)s0.x * 16 + j], acc);
            sumw += w0;
        }
        g2[(size_t)n * 16 + j] = acc - sumw * gin[(size_t)n * 16 + j];
    }
}

// ---------------- final head: bf16 MFMA GEMM (64 nodes/block) ----------------
__global__ __launch_bounds__(256) void final_mfma_k(const float* __restrict__ h,
                                                    const float* __restrict__ gx,
                                                    const float* __restrict__ gy,
                                                    const float* __restrict__ g2x,
                                                    const float* __restrict__ g2y,
                                                    const float* __restrict__ rain0,
                                                    const float* __restrict__ W_rin,
                                                    const float* __restrict__ W_rout,
                                                    float* __restrict__ out_rain) {
    __shared__ __align__(16) unsigned short Wt[128 * AP];  // 26.6 KB
    __shared__ __align__(16) unsigned short At[64 * AP];   // 13.3 KB
    __shared__ float Wo[128];
    const int tid = threadIdx.x;

    for (int i = tid; i < 3072; i += 256) {
        int k = i >> 5;
        int c = (i & 31) * 4;
        float4 wv = *reinterpret_cast<const float4*>(W_rin + k * 128 + c);
        Wt[(c + 0) * AP + k] = f2bf(wv.x);
        Wt[(c + 1) * AP + k] = f2bf(wv.y);
        Wt[(c + 2) * AP + k] = f2bf(wv.z);
        Wt[(c + 3) * AP + k] = f2bf(wv.w);
    }
    if (tid < 128) Wo[tid] = W_rout[tid];

    {
        int n = tid >> 2, q = tid & 3;
        int node = blockIdx.x * 64 + n;
        float f[24];
#define LD4(di, p) { float4 v_ = *reinterpret_cast<const float4*>(p); \
                     f[di] = v_.x; f[di+1] = v_.y; f[di+2] = v_.z; f[di+3] = v_.w; }
        if (node < NN) {
            if (q == 0) {
                LD4(0,  h + (size_t)node * 32 + 0);
                LD4(4,  h + (size_t)node * 32 + 4);
                LD4(8,  h + (size_t)node * 32 + 8);
                LD4(12, h + (size_t)node * 32 + 12);
                LD4(16, h + (size_t)node * 32 + 16);
                LD4(20, h + (size_t)node * 32 + 20);
            } else if (q == 1) {
                LD4(0,  h + (size_t)node * 32 + 24);
                LD4(4,  h + (size_t)node * 32 + 28);
                LD4(8,  gx + (size_t)node * 16 + 0);
                LD4(12, gx + (size_t)node * 16 + 4);
                LD4(16, gx + (size_t)node * 16 + 8);
                LD4(20, gx + (size_t)node * 16 + 12);
            } else if (q == 2) {
                LD4(0,  gy + (size_t)node * 16 + 0);
                LD4(4,  gy + (size_t)node * 16 + 4);
                LD4(8,  gy + (size_t)node * 16 + 8);
                LD4(12, gy + (size_t)node * 16 + 12);
                LD4(16, g2x + (size_t)node * 16 + 0);
                LD4(20, g2x + (size_t)node * 16 + 4);
            } else {
                LD4(0,  g2x + (size_t)node * 16 + 8);
                LD4(4,  g2x + (size_t)node * 16 + 12);
                LD4(8,  g2y + (size_t)node * 16 + 0);
                LD4(12, g2y + (size_t)node * 16 + 4);
                LD4(16, g2y + (size_t)node * 16 + 8);
                LD4(20, g2y + (size_t)node * 16 + 12);
            }
        } else {
#pragma unroll
            for (int i = 0; i < 24; ++i) f[i] = 0.f;
        }
#undef LD4
        unsigned pk[12];
#pragma unroll
        for (int i = 0; i < 12; ++i)
            pk[i] = (unsigned)f2bf(f[2 * i]) | ((unsigned)f2bf(f[2 * i + 1]) << 16);
        char* dp = (char*)At + n * (AP * 2) + q * 48;
        *reinterpret_cast<uint4*>(dp + 0)  = make_uint4(pk[0], pk[1], pk[2], pk[3]);
        *reinterpret_cast<uint4*>(dp + 16) = make_uint4(pk[4], pk[5], pk[6], pk[7]);
        *reinterpret_cast<uint4*>(dp + 32) = make_uint4(pk[8], pk[9], pk[10], pk[11]);
    }
    __syncthreads();

    const int w = tid >> 6;
    const int l = tid & 63;
    const int col = l & 15;
    const int kg = l >> 4;
    const char* Ab = (const char*)At + (w * 16 + col) * (AP * 2) + kg * 16;
    const char* Bb = (const char*)Wt + col * (AP * 2) + kg * 16;

    f32x4 acc[8];
#pragma unroll
    for (int ct = 0; ct < 8; ++ct) acc[ct] = (f32x4){0.f, 0.f, 0.f, 0.f};

#pragma unroll
    for (int ks = 0; ks < 3; ++ks) {
        bf16x8 af = *reinterpret_cast<const bf16x8*>(Ab + ks * 64);
#pragma unroll
        for (int ct = 0; ct < 8; ++ct) {
            bf16x8 bfr = *reinterpret_cast<const bf16x8*>(Bb + ct * 16 * (AP * 2) + ks * 64);
            acc[ct] = __builtin_amdgcn_mfma_f32_16x16x32_bf16(af, bfr, acc[ct], 0, 0, 0);
        }
    }

    float s0 = 0.f, s1 = 0.f, s2 = 0.f, s3 = 0.f;
#pragma unroll
    for (int ct = 0; ct < 8; ++ct) {
        float wo = Wo[ct * 16 + col];
        s0 = fmaf(fmaxf(acc[ct][0], 0.f), wo, s0);
        s1 = fmaf(fmaxf(acc[ct][1], 0.f), wo, s1);
        s2 = fmaf(fmaxf(acc[ct][2], 0.f), wo, s2);
        s3 = fmaf(fmaxf(acc[ct][3], 0.f), wo, s3);
    }
#pragma unroll
    for (int m = 1; m < 16; m <<= 1) {
        s0 += __shfl_xor(s0, m);
        s1 += __shfl_xor(s1, m);
        s2 += __shfl_xor(s2, m);
        s3 += __shfl_xor(s3, m);
    }
    if (col == 0) {
        int row = blockIdx.x * 64 + w * 16 + kg * 4;
        if (row + 0 < NN) out_rain[row + 0] = rain0[row + 0] + s0;
        if (row + 1 < NN) out_rain[row + 1] = rain0[row + 1] + s1;
        if (row + 2 < NN) out_rain[row + 2] = rain0[row + 2] + s2;
        if (row + 3 < NN) out_rain[row + 3] = rain0[row + 3] + s3;
    }
}

extern "C" void kernel_launch(void* const* d_in, const int* in_sizes, int n_in,
                              void* d_out, int out_size, void* d_ws, size_t ws_size,
                              hipStream_t stream) {
    const float* h_feat  = (const float*)d_in[0];
    const float* e_feat  = (const float*)d_in[1];
    const float* rain0   = (const float*)d_in[2];
    const float* w_xx    = (const float*)d_in[3];
    const float* w_yy    = (const float*)d_in[4];
    const float* W_trans = (const float*)d_in[5];
    const float* W_rin   = (const float*)d_in[6];
    const float* W_rout  = (const float*)d_in[7];
    const int* src_xx    = (const int*)d_in[8];
    const int* dst_xx    = (const int*)d_in[9];
    const int* src_yy    = (const int*)d_in[10];
    const int* dst_yy    = (const int*)d_in[11];

    float* ws = (float*)d_ws;
    float* emh = ws;                           // NN*32 floats (reused as g2x/g2y)
    float* gx  = emh + (size_t)NN * 32;        // NN*16
    float* gy  = gx + (size_t)NN * 16;         // NN*16
    float* g2x = emh;                          // alias (emh dead after pull1)
    float* g2y = emh + (size_t)NN * 16;

    int2* csr_xx = (int2*)(gy + (size_t)NN * 16);  // EE int2
    int2* csr_yy = csr_xx + EE;                    // EE int2
    int* off_xx  = (int*)(csr_yy + EE);            // OFFP ints
    int* off_yy  = off_xx + OFFP;                  // OFFP ints
    int* partial = off_yy + OFFP;                  // 2*C_CH*NN ints (12.8MB)
    int* bsum    = partial + (size_t)2 * C_CH * NN; // 64
    int* bbase   = bsum + 64;                      // 64

    float* out_rain = (float*)d_out;           // NN
    float* out_h    = out_rain + NN;           // NN*32

    trans_k<<<(NN * 32 + 255) / 256, 256, 0, stream>>>(h_feat, e_feat, W_trans, emh);

    hist_k<<<2 * NRANGE * C_CH, 1024, 0, stream>>>(dst_xx, dst_yy, partial);

    scanA_k<<<2 * NB, 1024, 0, stream>>>(partial, bsum);
    scanB_k<<<1, 64, 0, stream>>>(bsum, bbase, off_xx, off_yy);
    scanC_k<<<2 * NB, 1024, 0, stream>>>(partial, off_xx, off_yy, bbase);

    scatter_k<<<2 * NRANGE * C_CH, 1024, 0, stream>>>(
        dst_xx, src_xx, w_xx, dst_yy, src_yy, w_yy, partial, csr_xx, csr_yy);

    pull1_k<<<(NN * 32 + 255) / 256, 256, 0, stream>>>(
        emh, e_feat, csr_xx, off_xx, csr_yy, off_yy, out_h, gx, gy);

    pull2_k<<<(NN * 16 + 255) / 256, 256, 0, stream>>>(
        gx, gy, csr_xx, off_xx, csr_yy, off_yy, g2x, g2y);

    final_mfma_k<<<(NN + 63) / 64, 256, 0, stream>>>(
        out_h, gx, gy, g2x, g2y, rain0, W_rin, W_rout, out_rain);
}

// Round 9
// 323.346 us; speedup vs baseline: 8.5227x; 1.0613x over previous
//
#include <hip/hip_runtime.h>
#include <hip/hip_bf16.h>

#define NN 100000
#define EE 1600000
#define SCAN_CHUNK 4096
#define NB ((NN + SCAN_CHUNK - 1) / SCAN_CHUNK)   // 25 scan blocks per type
#define OFFP (NN + 8)                             // padded off array
#define NRANGE 8                                  // dst ranges (== XCDs)
#define RSZ (NN / NRANGE)                         // 12500 nodes per range
#define C_CH 16                                   // edge chunks per type
#define CHUNK_E (EE / C_CH)                       // 100000 edges per chunk
#define AP 104                                    // bf16 LDS row pad (208 B)

typedef __attribute__((ext_vector_type(8))) short bf16x8;
typedef __attribute__((ext_vector_type(4))) float f32x4;

__device__ inline unsigned short f2bf(float f) {
    unsigned u = __float_as_uint(f);
    return (unsigned short)((u + 0x7FFFu + ((u >> 16) & 1u)) >> 16);
}
__device__ inline float bf2f(unsigned short u) {
    return __uint_as_float(((unsigned)u) << 16);
}

// ---- trans: emh_bf = bf16(relu(cat(h,e)@W)); ef_bf = bf16(e_feat) ----
__global__ __launch_bounds__(256) void trans_k(const float* __restrict__ h_feat,
                                               const float* __restrict__ e_feat,
                                               const float* __restrict__ W_trans,
                                               unsigned short* __restrict__ emh_bf,
                                               unsigned short* __restrict__ ef_bf) {
    __shared__ float Wl[48 * 32];
    for (int i = threadIdx.x; i < 48 * 32; i += 256) Wl[i] = W_trans[i];
    __syncthreads();
    int t = blockIdx.x * 256 + threadIdx.x;
    if (t >= NN * 32) return;
    int n = t >> 5, j = t & 31;
    const float* hrow = h_feat + (size_t)n * 32;
    const float* erow = e_feat + (size_t)n * 16;
    float acc = 0.f;
#pragma unroll 8
    for (int k = 0; k < 32; ++k) acc = fmaf(hrow[k], Wl[k * 32 + j], acc);
#pragma unroll 8
    for (int k = 0; k < 16; ++k) acc = fmaf(erow[k], Wl[(32 + k) * 32 + j], acc);
    emh_bf[t] = f2bf(fmaxf(acc, 0.f));
    if (j < 16) ef_bf[(size_t)n * 16 + j] = f2bf(erow[j]);
}

// ---------------- hist: LDS histogram, zero global atomics, 16 waves/block ------
__global__ __launch_bounds__(1024) void hist_k(const int* __restrict__ dst_a,
                                               const int* __restrict__ dst_b,
                                               int* __restrict__ partial) {
    __shared__ int bins[RSZ];
    for (int i = threadIdx.x; i < RSZ; i += 1024) bins[i] = 0;
    __syncthreads();
    const int bid = blockIdx.x;
    const int t = bid >> 7;
    const int r = bid & 7;
    const int c = (bid >> 3) & 15;
    const int* dst = t ? dst_b : dst_a;
    const int lo = r * RSZ;
    const long base = (long)c * CHUNK_E;
    for (int i = threadIdx.x * 4; i < CHUNK_E; i += 4096) {
        int4 d = *reinterpret_cast<const int4*>(dst + base + i);
        int x;
        x = d.x - lo; if ((unsigned)x < RSZ) atomicAdd(&bins[x], 1);
        x = d.y - lo; if ((unsigned)x < RSZ) atomicAdd(&bins[x], 1);
        x = d.z - lo; if ((unsigned)x < RSZ) atomicAdd(&bins[x], 1);
        x = d.w - lo; if ((unsigned)x < RSZ) atomicAdd(&bins[x], 1);
    }
    __syncthreads();
    int* pout = partial + (long)(t * C_CH + c) * NN + lo;
    for (int i = threadIdx.x; i < RSZ; i += 1024) pout[i] = bins[i];
}

// ---------------- scan phase A: per-4096-node-chunk totals ----------------
__global__ __launch_bounds__(1024) void scanA_k(const int* __restrict__ partial,
                                                int* __restrict__ bsum) {
    __shared__ int wsum[16];
    const int b = blockIdx.x;              // 0..2*NB-1
    const int t = (b >= NB) ? 1 : 0;
    const int i0 = (b % NB) * SCAN_CHUNK + threadIdx.x * 4;
    int4 s = make_int4(0, 0, 0, 0);
    if (i0 < NN) {
#pragma unroll
        for (int c = 0; c < C_CH; ++c) {
            int4 v = *reinterpret_cast<const int4*>(partial + (long)(t * C_CH + c) * NN + i0);
            s.x += v.x; s.y += v.y; s.z += v.z; s.w += v.w;
        }
    }
    int tot = s.x + s.y + s.z + s.w;
#pragma unroll
    for (int d = 32; d; d >>= 1) tot += __shfl_down(tot, d);
    int lane = threadIdx.x & 63, w = threadIdx.x >> 6;
    if (lane == 0) wsum[w] = tot;
    __syncthreads();
    if (threadIdx.x == 0) {
        int sm = 0;
#pragma unroll
        for (int q = 0; q < 16; ++q) sm += wsum[q];
        bsum[b] = sm;
    }
}

// ---------------- scan phase B: segmented exclusive scan of block sums ------
__global__ __launch_bounds__(64) void scanB_k(const int* __restrict__ bsum,
                                              int* __restrict__ bbase,
                                              int* __restrict__ off_a,
                                              int* __restrict__ off_b) {
    int lane = threadIdx.x;
    int v = (lane < 2 * NB) ? bsum[lane] : 0;
    int seg = lane / NB;
    int inc = v;
#pragma unroll
    for (int d = 1; d < 64; d <<= 1) {
        int x = __shfl_up(inc, d);
        if (lane >= d && (lane - d) / NB == seg) inc += x;
    }
    int excl = inc - v;
    if (lane < 2 * NB) bbase[lane] = excl;
    if (lane == NB - 1) off_a[NN] = inc;
    if (lane == 2 * NB - 1) off_b[NN] = inc;
}

// ---- scan phase C: off[] = exclusive node scan; partial -> per-chunk cursors ----
__global__ __launch_bounds__(1024) void scanC_k(int* __restrict__ partial,
                                                int* __restrict__ off_a,
                                                int* __restrict__ off_b,
                                                const int* __restrict__ bbase) {
    __shared__ int wsum[16];
    const int b = blockIdx.x;
    const int t = (b >= NB) ? 1 : 0;
    int* off = t ? off_b : off_a;
    const int base0 = bbase[b];
    const int i0 = (b % NB) * SCAN_CHUNK + threadIdx.x * 4;
    int4 s = make_int4(0, 0, 0, 0);
    if (i0 < NN) {
#pragma unroll
        for (int c = 0; c < C_CH; ++c) {
            int4 v = *reinterpret_cast<const int4*>(partial + (long)(t * C_CH + c) * NN + i0);
            s.x += v.x; s.y += v.y; s.z += v.z; s.w += v.w;
        }
    }
    int s1 = s.x, s2 = s1 + s.y, s3 = s2 + s.z, tot = s3 + s.w;
    int lane = threadIdx.x & 63, w = threadIdx.x >> 6;
    int inc = tot;
#pragma unroll
    for (int d = 1; d < 64; d <<= 1) {
        int x = __shfl_up(inc, d);
        if (lane >= d) inc += x;
    }
    if (lane == 63) wsum[w] = inc;
    int texcl = inc - tot;
    __syncthreads();
    if (threadIdx.x == 0) {
        int r = 0;
#pragma unroll
        for (int q = 0; q < 16; ++q) { int x = wsum[q]; wsum[q] = r; r += x; }
    }
    __syncthreads();
    const int base = base0 + wsum[w] + texcl;
    if (i0 < NN) {
        *reinterpret_cast<int4*>(off + i0) = make_int4(base, base + s1, base + s2, base + s3);
        int4 run = make_int4(base, base + s1, base + s2, base + s3);
#pragma unroll
        for (int c = 0; c < C_CH; ++c) {
            int* p = partial + (long)(t * C_CH + c) * NN + i0;
            int4 v = *reinterpret_cast<const int4*>(p);
            *reinterpret_cast<int4*>(p) = run;
            run.x += v.x; run.y += v.y; run.z += v.z; run.w += v.w;
        }
    }
}

// ---------------- scatter: LDS cursors, zero global atomics, 16 waves/block ------
__global__ __launch_bounds__(1024) void scatter_k(const int* __restrict__ dst_a,
                                                  const int* __restrict__ src_a,
                                                  const float* __restrict__ w_a,
                                                  const int* __restrict__ dst_b,
                                                  const int* __restrict__ src_b,
                                                  const float* __restrict__ w_b,
                                                  const int* __restrict__ partial,
                                                  int2* __restrict__ csr_a,
                                                  int2* __restrict__ csr_b) {
    __shared__ int curs[RSZ];
    const int bid = blockIdx.x;
    const int t = bid >> 7;
    const int r = bid & 7;
    const int c = (bid >> 3) & 15;
    const int* dst = t ? dst_b : dst_a;
    const int* src = t ? src_b : src_a;
    const float* wv = t ? w_b : w_a;
    int2* csr = t ? csr_b : csr_a;
    const int lo = r * RSZ;
    const int* pin = partial + (long)(t * C_CH + c) * NN + lo;
    for (int i = threadIdx.x; i < RSZ; i += 1024) curs[i] = pin[i];
    __syncthreads();
    const long base = (long)c * CHUNK_E;
    for (int i = threadIdx.x * 4; i < CHUNK_E; i += 4096) {
        int4 d = *reinterpret_cast<const int4*>(dst + base + i);
        int x;
        x = d.x - lo;
        if ((unsigned)x < RSZ) {
            int p = atomicAdd(&curs[x], 1);
            csr[p] = make_int2(src[base + i], __float_as_int(wv[base + i]));
        }
        x = d.y - lo;
        if ((unsigned)x < RSZ) {
            int p = atomicAdd(&curs[x], 1);
            csr[p] = make_int2(src[base + i + 1], __float_as_int(wv[base + i + 1]));
        }
        x = d.z - lo;
        if ((unsigned)x < RSZ) {
            int p = atomicAdd(&curs[x], 1);
            csr[p] = make_int2(src[base + i + 2], __float_as_int(wv[base + i + 2]));
        }
        x = d.w - lo;
        if ((unsigned)x < RSZ) {
            int p = atomicAdd(&curs[x], 1);
            csr[p] = make_int2(src[base + i + 3], __float_as_int(wv[base + i + 3]));
        }
    }
}

// ---- pull1: h, gx, gy. bf16 gathers, fp32 accumulate. 32 lanes/node ----
__global__ __launch_bounds__(256) void pull1_k(const unsigned short* __restrict__ emh_bf,
                                               const unsigned short* __restrict__ ef_bf,
                                               const float* __restrict__ e_feat,
                                               const int2* __restrict__ csr_a,
                                               const int* __restrict__ off_a,
                                               const int2* __restrict__ csr_b,
                                               const int* __restrict__ off_b,
                                               float* __restrict__ out_h,
                                               float* __restrict__ gx,
                                               float* __restrict__ gy,
                                               unsigned short* __restrict__ gx_bf,
                                               unsigned short* __restrict__ gy_bf) {
    int g = blockIdx.x * 256 + threadIdx.x;
    int n = g >> 5, j = g & 31;
    if (n >= NN) return;
    float acc_h = 0.f;

#pragma unroll
    for (int half = 0; half < 2; ++half) {
        const int2* csr = half ? csr_b : csr_a;
        const int* off = half ? off_b : off_a;
        float* gout = half ? gy : gx;
        unsigned short* gbf = half ? gy_bf : gx_bf;
        float acc_g = 0.f, sumw = 0.f;
        int k = off[n], e2 = off[n + 1];
        for (; k + 3 < e2; k += 4) {
            int2 s0 = csr[k], s1 = csr[k + 1], s2 = csr[k + 2], s3 = csr[k + 3];
            float m0 = bf2f(emh_bf[(size_t)s0.x * 32 + j]);
            float m1 = bf2f(emh_bf[(size_t)s1.x * 32 + j]);
            float m2 = bf2f(emh_bf[(size_t)s2.x * 32 + j]);
            float m3 = bf2f(emh_bf[(size_t)s3.x * 32 + j]);
            acc_h += (m0 + m1) + (m2 + m3);
            if (j < 16) {
                float w0 = __int_as_float(s0.y), w1 = __int_as_float(s1.y);
                float w2 = __int_as_float(s2.y), w3 = __int_as_float(s3.y);
                acc_g = fmaf(w0, bf2f(ef_bf[(size_t)s0.x * 16 + j]), acc_g);
                acc_g = fmaf(w1, bf2f(ef_bf[(size_t)s1.x * 16 + j]), acc_g);
                acc_g = fmaf(w2, bf2f(ef_bf[(size_t)s2.x * 16 + j]), acc_g);
                acc_g = fmaf(w3, bf2f(ef_bf[(size_t)s3.x * 16 + j]), acc_g);
                sumw += (w0 + w1) + (w2 + w3);
            }
        }
        for (; k < e2; ++k) {
            int2 s0 = csr[k];
            acc_h += bf2f(emh_bf[(size_t)s0.x * 32 + j]);
            if (j < 16) {
                float w0 = __int_as_float(s0.y);
                acc_g = fmaf(w0, bf2f(ef_bf[(size_t)s0.x * 16 + j]), acc_g);
                sumw += w0;
            }
        }
        if (j < 16) {
            float val = acc_g - sumw * e_feat[(size_t)n * 16 + j];
            gout[(size_t)n * 16 + j] = val;
            gbf[(size_t)n * 16 + j] = f2bf(val);
        }
    }
    out_h[(size_t)n * 32 + j] = fmaxf(acc_h, 0.f);
}

// ---- pull2: g2x, g2y. bf16 gathers, fp32 own-node + accumulate. 16 lanes/node ----
__global__ __launch_bounds__(256) void pull2_k(const float* __restrict__ gx,
                                               const float* __restrict__ gy,
                                               const unsigned short* __restrict__ gx_bf,
                                               const unsigned short* __restrict__ gy_bf,
                                               const int2* __restrict__ csr_a,
                                               const int* __restrict__ off_a,
                                               const int2* __restrict__ csr_b,
                                               const int* __restrict__ off_b,
                                               float* __restrict__ g2x,
                                               float* __restrict__ g2y) {
    int g = blockIdx.x * 256 + threadIdx.x;
    int n = g >> 4, j = g & 15;
    if (n >= NN) return;

#pragma unroll
    for (int half = 0; half < 2; ++half) {
        const int2* csr = half ? csr_b : csr_a;
        const int* off = half ? off_b : off_a;
        const float* gin = half ? gy : gx;
        const unsigned short* gbf = half ? gy_bf : gx_bf;
        float* g2 = half ? g2y : g2x;
        float acc = 0.f, sumw = 0.f;
        int k = off[n], e2 = off[n + 1];
        for (; k + 3 < e2; k += 4) {
            int2 s0 = csr[k], s1 = csr[k + 1], s2 = csr[k + 2], s3 = csr[k + 3];
            float w0 = __int_as_float(s0.y), w1 = __int_as_float(s1.y);
            float w2 = __int_as_float(s2.y), w3 = __int_as_float(s3.y);
            acc = fmaf(w0, bf2f(gbf[(size_t)s0.x * 16 + j]), acc);
            acc = fmaf(w1, bf2f(gbf[(size_t)s1.x * 16 + j]), acc);
            acc = fmaf(w2, bf2f(gbf[(size_t)s2.x * 16 + j]), acc);
            acc = fmaf(w3, bf2f(gbf[(size_t)s3.x * 16 + j]), acc);
            sumw += (w0 + w1) + (w2 + w3);
        }
        for (; k < e2; ++k) {
            int2 s0 = csr[k];
            float w0 = __int_as_float(s0.y);
            acc = fmaf(w0, bf2f(gbf[(size_t)s0.x * 16 + j]), acc);
            sumw += w0;
        }
        g2[(size_t)n * 16 + j] = acc - sumw * gin[(size_t)n * 16 + j];
    }
}

// ---------------- final head: bf16 MFMA GEMM (64 nodes/block) ----------------
__global__ __launch_bounds__(256) void final_mfma_k(const float* __restrict__ h,
                                                    const float* __restrict__ gx,
                                                    const float* __restrict__ gy,
                                                    const float* __restrict__ g2x,
                                                    const float* __restrict__ g2y,
                                                    const float* __restrict__ rain0,
                                                    const float* __restrict__ W_rin,
                                                    const float* __restrict__ W_rout,
                                                    float* __restrict__ out_rain) {
    __shared__ __align__(16) unsigned short Wt[128 * AP];  // 26.6 KB
    __shared__ __align__(16) unsigned short At[64 * AP];   // 13.3 KB
    __shared__ float Wo[128];
    const int tid = threadIdx.x;

    for (int i = tid; i < 3072; i += 256) {
        int k = i >> 5;
        int c = (i & 31) * 4;
        float4 wv = *reinterpret_cast<const float4*>(W_rin + k * 128 + c);
        Wt[(c + 0) * AP + k] = f2bf(wv.x);
        Wt[(c + 1) * AP + k] = f2bf(wv.y);
        Wt[(c + 2) * AP + k] = f2bf(wv.z);
        Wt[(c + 3) * AP + k] = f2bf(wv.w);
    }
    if (tid < 128) Wo[tid] = W_rout[tid];

    {
        int n = tid >> 2, q = tid & 3;
        int node = blockIdx.x * 64 + n;
        float f[24];
#define LD4(di, p) { float4 v_ = *reinterpret_cast<const float4*>(p); \
                     f[di] = v_.x; f[di+1] = v_.y; f[di+2] = v_.z; f[di+3] = v_.w; }
        if (node < NN) {
            if (q == 0) {
                LD4(0,  h + (size_t)node * 32 + 0);
                LD4(4,  h + (size_t)node * 32 + 4);
                LD4(8,  h + (size_t)node * 32 + 8);
                LD4(12, h + (size_t)node * 32 + 12);
                LD4(16, h + (size_t)node * 32 + 16);
                LD4(20, h + (size_t)node * 32 + 20);
            } else if (q == 1) {
                LD4(0,  h + (size_t)node * 32 + 24);
                LD4(4,  h + (size_t)node * 32 + 28);
                LD4(8,  gx + (size_t)node * 16 + 0);
                LD4(12, gx + (size_t)node * 16 + 4);
                LD4(16, gx + (size_t)node * 16 + 8);
                LD4(20, gx + (size_t)node * 16 + 12);
            } else if (q == 2) {
                LD4(0,  gy + (size_t)node * 16 + 0);
                LD4(4,  gy + (size_t)node * 16 + 4);
                LD4(8,  gy + (size_t)node * 16 + 8);
                LD4(12, gy + (size_t)node * 16 + 12);
                LD4(16, g2x + (size_t)node * 16 + 0);
                LD4(20, g2x + (size_t)node * 16 + 4);
            } else {
                LD4(0,  g2x + (size_t)node * 16 + 8);
                LD4(4,  g2x + (size_t)node * 16 + 12);
                LD4(8,  g2y + (size_t)node * 16 + 0);
                LD4(12, g2y + (size_t)node * 16 + 4);
                LD4(16, g2y + (size_t)node * 16 + 8);
                LD4(20, g2y + (size_t)node * 16 + 12);
            }
        } else {
#pragma unroll
            for (int i = 0; i < 24; ++i) f[i] = 0.f;
        }
#undef LD4
        unsigned pk[12];
#pragma unroll
        for (int i = 0; i < 12; ++i)
            pk[i] = (unsigned)f2bf(f[2 * i]) | ((unsigned)f2bf(f[2 * i + 1]) << 16);
        char* dp = (char*)At + n * (AP * 2) + q * 48;
        *reinterpret_cast<uint4*>(dp + 0)  = make_uint4(pk[0], pk[1], pk[2], pk[3]);
        *reinterpret_cast<uint4*>(dp + 16) = make_uint4(pk[4], pk[5], pk[6], pk[7]);
        *reinterpret_cast<uint4*>(dp + 32) = make_uint4(pk[8], pk[9], pk[10], pk[11]);
    }
    __syncthreads();

    const int w = tid >> 6;
    const int l = tid & 63;
    const int col = l & 15;
    const int kg = l >> 4;
    const char* Ab = (const char*)At + (w * 16 + col) * (AP * 2) + kg * 16;
    const char* Bb = (const char*)Wt + col * (AP * 2) + kg * 16;

    f32x4 acc[8];
#pragma unroll
    for (int ct = 0; ct < 8; ++ct) acc[ct] = (f32x4){0.f, 0.f, 0.f, 0.f};

#pragma unroll
    for (int ks = 0; ks < 3; ++ks) {
        bf16x8 af = *reinterpret_cast<const bf16x8*>(Ab + ks * 64);
#pragma unroll
        for (int ct = 0; ct < 8; ++ct) {
            bf16x8 bfr = *reinterpret_cast<const bf16x8*>(Bb + ct * 16 * (AP * 2) + ks * 64);
            acc[ct] = __builtin_amdgcn_mfma_f32_16x16x32_bf16(af, bfr, acc[ct], 0, 0, 0);
        }
    }

    float s0 = 0.f, s1 = 0.f, s2 = 0.f, s3 = 0.f;
#pragma unroll
    for (int ct = 0; ct < 8; ++ct) {
        float wo = Wo[ct * 16 + col];
        s0 = fmaf(fmaxf(acc[ct][0], 0.f), wo, s0);
        s1 = fmaf(fmaxf(acc[ct][1], 0.f), wo, s1);
        s2 = fmaf(fmaxf(acc[ct][2], 0.f), wo, s2);
        s3 = fmaf(fmaxf(acc[ct][3], 0.f), wo, s3);
    }
#pragma unroll
    for (int m = 1; m < 16; m <<= 1) {
        s0 += __shfl_xor(s0, m);
        s1 += __shfl_xor(s1, m);
        s2 += __shfl_xor(s2, m);
        s3 += __shfl_xor(s3, m);
    }
    if (col == 0) {
        int row = blockIdx.x * 64 + w * 16 + kg * 4;
        if (row + 0 < NN) out_rain[row + 0] = rain0[row + 0] + s0;
        if (row + 1 < NN) out_rain[row + 1] = rain0[row + 1] + s1;
        if (row + 2 < NN) out_rain[row + 2] = rain0[row + 2] + s2;
        if (row + 3 < NN) out_rain[row + 3] = rain0[row + 3] + s3;
    }
}

extern "C" void kernel_launch(void* const* d_in, const int* in_sizes, int n_in,
                              void* d_out, int out_size, void* d_ws, size_t ws_size,
                              hipStream_t stream) {
    const float* h_feat  = (const float*)d_in[0];
    const float* e_feat  = (const float*)d_in[1];
    const float* rain0   = (const float*)d_in[2];
    const float* w_xx    = (const float*)d_in[3];
    const float* w_yy    = (const float*)d_in[4];
    const float* W_trans = (const float*)d_in[5];
    const float* W_rin   = (const float*)d_in[6];
    const float* W_rout  = (const float*)d_in[7];
    const int* src_xx    = (const int*)d_in[8];
    const int* dst_xx    = (const int*)d_in[9];
    const int* src_yy    = (const int*)d_in[10];
    const int* dst_yy    = (const int*)d_in[11];

    // ws layout (bytes):
    unsigned short* emh_bf = (unsigned short*)d_ws;            // NN*32 bf16 = 6.4MB
    unsigned short* ef_bf  = emh_bf + (size_t)NN * 32;         // NN*16 = 3.2MB
    unsigned short* gx_bf  = ef_bf + (size_t)NN * 16;          // 3.2MB
    unsigned short* gy_bf  = gx_bf + (size_t)NN * 16;          // 3.2MB
    float* gx = (float*)(gy_bf + (size_t)NN * 16);             // 6.4MB (16MB offset)
    float* gy = gx + (size_t)NN * 16;                          // 6.4MB
    int2* csr_xx = (int2*)(gy + (size_t)NN * 16);              // 12.8MB
    int2* csr_yy = csr_xx + EE;                                // 12.8MB
    int* off_xx  = (int*)(csr_yy + EE);                        // OFFP ints
    int* off_yy  = off_xx + OFFP;                              // OFFP ints
    int* partial = off_yy + OFFP;                              // 2*C_CH*NN ints (12.8MB)
    float* g2x   = (float*)partial;                            // alias (partial dead после scatter)
    float* g2y   = g2x + (size_t)NN * 16;
    int* bsum    = partial + (size_t)2 * C_CH * NN;            // 64
    int* bbase   = bsum + 64;                                  // 64

    float* out_rain = (float*)d_out;           // NN
    float* out_h    = out_rain + NN;           // NN*32

    trans_k<<<(NN * 32 + 255) / 256, 256, 0, stream>>>(h_feat, e_feat, W_trans,
                                                       emh_bf, ef_bf);

    hist_k<<<2 * NRANGE * C_CH, 1024, 0, stream>>>(dst_xx, dst_yy, partial);

    scanA_k<<<2 * NB, 1024, 0, stream>>>(partial, bsum);
    scanB_k<<<1, 64, 0, stream>>>(bsum, bbase, off_xx, off_yy);
    scanC_k<<<2 * NB, 1024, 0, stream>>>(partial, off_xx, off_yy, bbase);

    scatter_k<<<2 * NRANGE * C_CH, 1024, 0, stream>>>(
        dst_xx, src_xx, w_xx, dst_yy, src_yy, w_yy, partial, csr_xx, csr_yy);

    pull1_k<<<(NN * 32 + 255) / 256, 256, 0, stream>>>(
        emh_bf, ef_bf, e_feat, csr_xx, off_xx, csr_yy, off_yy,
        out_h, gx, gy, gx_bf, gy_bf);

    pull2_k<<<(NN * 16 + 255) / 256, 256, 0, stream>>>(
        gx, gy, gx_bf, gy_bf, csr_xx, off_xx, csr_yy, off_yy, g2x, g2y);

    final_mfma_k<<<(NN + 63) / 64, 256, 0, stream>>>(
        out_h, gx, gy, g2x, g2y, rain0, W_rin, W_rout, out_rain);
}

// Round 10
// 318.240 us; speedup vs baseline: 8.6595x; 1.0160x over previous
//
#include <hip/hip_runtime.h>
#include <hip/hip_bf16.h>

#define NN 100000
#define EE 1600000
#define SCAN_CHUNK 4096
#define NB ((NN + SCAN_CHUNK - 1) / SCAN_CHUNK)   // 25 scan blocks per type
#define OFFP (NN + 8)                             // padded off array
#define NRANGE 16                                 // dst ranges (2 per XCD)
#define RSZ (NN / NRANGE)                         // 6250 nodes per range (exact)
#define C_CH 16                                   // edge chunks per type
#define CHUNK_E (EE / C_CH)                       // 100000 edges per chunk
#define AP 104                                    // bf16 LDS row pad (208 B)

typedef __attribute__((ext_vector_type(8))) short bf16x8;
typedef __attribute__((ext_vector_type(4))) float f32x4;

__device__ inline unsigned short f2bf(float f) {
    unsigned u = __float_as_uint(f);
    return (unsigned short)((u + 0x7FFFu + ((u >> 16) & 1u)) >> 16);
}
__device__ inline float bf2f(unsigned short u) {
    return __uint_as_float(((unsigned)u) << 16);
}

// ---- fused: blocks [0,TB) trans (emh_bf, ef_bf); blocks [TB,..) LDS hist ----
// hist decode: idx = bid-TB; t=idx>>8, r=idx&15, c=(idx>>4)&15.
// idx%8 == r%8 -> each range's partial rows written by one XCD (round-robin).
__global__ __launch_bounds__(1024) void fused_th_k(const float* __restrict__ h_feat,
                                                   const float* __restrict__ e_feat,
                                                   const float* __restrict__ W_trans,
                                                   unsigned short* __restrict__ emh_bf,
                                                   unsigned short* __restrict__ ef_bf,
                                                   const int* __restrict__ dst_a,
                                                   const int* __restrict__ dst_b,
                                                   int* __restrict__ partial, int TB) {
    __shared__ float Wl[48 * 32];
    __shared__ int bins[RSZ];
    if ((int)blockIdx.x < TB) {
        for (int i = threadIdx.x; i < 48 * 32; i += 1024) Wl[i] = W_trans[i];
        __syncthreads();
        int t = blockIdx.x * 1024 + threadIdx.x;
        if (t >= NN * 32) return;
        int n = t >> 5, j = t & 31;
        const float* hrow = h_feat + (size_t)n * 32;
        const float* erow = e_feat + (size_t)n * 16;
        float acc = 0.f;
#pragma unroll 8
        for (int k = 0; k < 32; ++k) acc = fmaf(hrow[k], Wl[k * 32 + j], acc);
#pragma unroll 8
        for (int k = 0; k < 16; ++k) acc = fmaf(erow[k], Wl[(32 + k) * 32 + j], acc);
        emh_bf[t] = f2bf(fmaxf(acc, 0.f));
        if (j < 16) ef_bf[(size_t)n * 16 + j] = f2bf(erow[j]);
    } else {
        for (int i = threadIdx.x; i < RSZ; i += 1024) bins[i] = 0;
        __syncthreads();
        const int idx = (int)blockIdx.x - TB;
        const int t = idx >> 8;
        const int r = idx & 15;
        const int c = (idx >> 4) & 15;
        const int* dst = t ? dst_b : dst_a;
        const int lo = r * RSZ;
        const long base = (long)c * CHUNK_E;
        for (int i = threadIdx.x * 4; i < CHUNK_E; i += 4096) {
            int4 d = *reinterpret_cast<const int4*>(dst + base + i);
            int x;
            x = d.x - lo; if ((unsigned)x < RSZ) atomicAdd(&bins[x], 1);
            x = d.y - lo; if ((unsigned)x < RSZ) atomicAdd(&bins[x], 1);
            x = d.z - lo; if ((unsigned)x < RSZ) atomicAdd(&bins[x], 1);
            x = d.w - lo; if ((unsigned)x < RSZ) atomicAdd(&bins[x], 1);
        }
        __syncthreads();
        int* pout = partial + (long)(t * C_CH + c) * NN + lo;
        for (int i = threadIdx.x; i < RSZ; i += 1024) pout[i] = bins[i];
    }
}

// ---------------- scan phase A: per-4096-node-chunk totals ----------------
__global__ __launch_bounds__(1024) void scanA_k(const int* __restrict__ partial,
                                                int* __restrict__ bsum) {
    __shared__ int wsum[16];
    const int b = blockIdx.x;              // 0..2*NB-1
    const int t = (b >= NB) ? 1 : 0;
    const int i0 = (b % NB) * SCAN_CHUNK + threadIdx.x * 4;
    int4 s = make_int4(0, 0, 0, 0);
    if (i0 < NN) {
#pragma unroll
        for (int c = 0; c < C_CH; ++c) {
            int4 v = *reinterpret_cast<const int4*>(partial + (long)(t * C_CH + c) * NN + i0);
            s.x += v.x; s.y += v.y; s.z += v.z; s.w += v.w;
        }
    }
    int tot = s.x + s.y + s.z + s.w;
#pragma unroll
    for (int d = 32; d; d >>= 1) tot += __shfl_down(tot, d);
    int lane = threadIdx.x & 63, w = threadIdx.x >> 6;
    if (lane == 0) wsum[w] = tot;
    __syncthreads();
    if (threadIdx.x == 0) {
        int sm = 0;
#pragma unroll
        for (int q = 0; q < 16; ++q) sm += wsum[q];
        bsum[b] = sm;
    }
}

// ---------------- scan phase B: segmented exclusive scan of block sums ------
__global__ __launch_bounds__(64) void scanB_k(const int* __restrict__ bsum,
                                              int* __restrict__ bbase,
                                              int* __restrict__ off_a,
                                              int* __restrict__ off_b) {
    int lane = threadIdx.x;
    int v = (lane < 2 * NB) ? bsum[lane] : 0;
    int seg = lane / NB;
    int inc = v;
#pragma unroll
    for (int d = 1; d < 64; d <<= 1) {
        int x = __shfl_up(inc, d);
        if (lane >= d && (lane - d) / NB == seg) inc += x;
    }
    int excl = inc - v;
    if (lane < 2 * NB) bbase[lane] = excl;
    if (lane == NB - 1) off_a[NN] = inc;
    if (lane == 2 * NB - 1) off_b[NN] = inc;
}

// ---- scan phase C: off[] = exclusive node scan; partial -> per-chunk cursors ----
__global__ __launch_bounds__(1024) void scanC_k(int* __restrict__ partial,
                                                int* __restrict__ off_a,
                                                int* __restrict__ off_b,
                                                const int* __restrict__ bbase) {
    __shared__ int wsum[16];
    const int b = blockIdx.x;
    const int t = (b >= NB) ? 1 : 0;
    int* off = t ? off_b : off_a;
    const int base0 = bbase[b];
    const int i0 = (b % NB) * SCAN_CHUNK + threadIdx.x * 4;
    int4 s = make_int4(0, 0, 0, 0);
    if (i0 < NN) {
#pragma unroll
        for (int c = 0; c < C_CH; ++c) {
            int4 v = *reinterpret_cast<const int4*>(partial + (long)(t * C_CH + c) * NN + i0);
            s.x += v.x; s.y += v.y; s.z += v.z; s.w += v.w;
        }
    }
    int s1 = s.x, s2 = s1 + s.y, s3 = s2 + s.z, tot = s3 + s.w;
    int lane = threadIdx.x & 63, w = threadIdx.x >> 6;
    int inc = tot;
#pragma unroll
    for (int d = 1; d < 64; d <<= 1) {
        int x = __shfl_up(inc, d);
        if (lane >= d) inc += x;
    }
    if (lane == 63) wsum[w] = inc;
    int texcl = inc - tot;
    __syncthreads();
    if (threadIdx.x == 0) {
        int r = 0;
#pragma unroll
        for (int q = 0; q < 16; ++q) { int x = wsum[q]; wsum[q] = r; r += x; }
    }
    __syncthreads();
    const int base = base0 + wsum[w] + texcl;
    if (i0 < NN) {
        *reinterpret_cast<int4*>(off + i0) = make_int4(base, base + s1, base + s2, base + s3);
        int4 run = make_int4(base, base + s1, base + s2, base + s3);
#pragma unroll
        for (int c = 0; c < C_CH; ++c) {
            int* p = partial + (long)(t * C_CH + c) * NN + i0;
            int4 v = *reinterpret_cast<const int4*>(p);
            *reinterpret_cast<int4*>(p) = run;
            run.x += v.x; run.y += v.y; run.z += v.z; run.w += v.w;
        }
    }
}

// ------ scatter: LDS cursors (25KB), zero global atomics, 2 blocks/CU ------
// 512 blocks: t=bid>>8, r=bid&15, c=(bid>>4)&15; bid%8==r%8 -> csr XCD-local.
__global__ __launch_bounds__(1024) void scatter_k(const int* __restrict__ dst_a,
                                                  const int* __restrict__ src_a,
                                                  const float* __restrict__ w_a,
                                                  const int* __restrict__ dst_b,
                                                  const int* __restrict__ src_b,
                                                  const float* __restrict__ w_b,
                                                  const int* __restrict__ partial,
                                                  int2* __restrict__ csr_a,
                                                  int2* __restrict__ csr_b) {
    __shared__ int curs[RSZ];
    const int bid = blockIdx.x;
    const int t = bid >> 8;
    const int r = bid & 15;
    const int c = (bid >> 4) & 15;
    const int* dst = t ? dst_b : dst_a;
    const int* src = t ? src_b : src_a;
    const float* wv = t ? w_b : w_a;
    int2* csr = t ? csr_b : csr_a;
    const int lo = r * RSZ;
    const int* pin = partial + (long)(t * C_CH + c) * NN + lo;
    for (int i = threadIdx.x; i < RSZ; i += 1024) curs[i] = pin[i];
    __syncthreads();
    const long base = (long)c * CHUNK_E;
    for (int i = threadIdx.x * 4; i < CHUNK_E; i += 4096) {
        int4 d = *reinterpret_cast<const int4*>(dst + base + i);
        int x;
        x = d.x - lo;
        if ((unsigned)x < RSZ) {
            int p = atomicAdd(&curs[x], 1);
            csr[p] = make_int2(src[base + i], __float_as_int(wv[base + i]));
        }
        x = d.y - lo;
        if ((unsigned)x < RSZ) {
            int p = atomicAdd(&curs[x], 1);
            csr[p] = make_int2(src[base + i + 1], __float_as_int(wv[base + i + 1]));
        }
        x = d.z - lo;
        if ((unsigned)x < RSZ) {
            int p = atomicAdd(&curs[x], 1);
            csr[p] = make_int2(src[base + i + 2], __float_as_int(wv[base + i + 2]));
        }
        x = d.w - lo;
        if ((unsigned)x < RSZ) {
            int p = atomicAdd(&curs[x], 1);
            csr[p] = make_int2(src[base + i + 3], __float_as_int(wv[base + i + 3]));
        }
    }
}

// ---- pull1: h, gx, gy. bf16 gathers, fp32 accumulate. 32 lanes/node ----
__global__ __launch_bounds__(256) void pull1_k(const unsigned short* __restrict__ emh_bf,
                                               const unsigned short* __restrict__ ef_bf,
                                               const float* __restrict__ e_feat,
                                               const int2* __restrict__ csr_a,
                                               const int* __restrict__ off_a,
                                               const int2* __restrict__ csr_b,
                                               const int* __restrict__ off_b,
                                               float* __restrict__ out_h,
                                               float* __restrict__ gx,
                                               float* __restrict__ gy,
                                               unsigned short* __restrict__ gx_bf,
                                               unsigned short* __restrict__ gy_bf) {
    int g = blockIdx.x * 256 + threadIdx.x;
    int n = g >> 5, j = g & 31;
    if (n >= NN) return;
    float acc_h = 0.f;

#pragma unroll
    for (int half = 0; half < 2; ++half) {
        const int2* csr = half ? csr_b : csr_a;
        const int* off = half ? off_b : off_a;
        float* gout = half ? gy : gx;
        unsigned short* gbf = half ? gy_bf : gx_bf;
        float acc_g = 0.f, sumw = 0.f;
        int k = off[n], e2 = off[n + 1];
        for (; k + 3 < e2; k += 4) {
            int2 s0 = csr[k], s1 = csr[k + 1], s2 = csr[k + 2], s3 = csr[k + 3];
            float m0 = bf2f(emh_bf[(size_t)s0.x * 32 + j]);
            float m1 = bf2f(emh_bf[(size_t)s1.x * 32 + j]);
            float m2 = bf2f(emh_bf[(size_t)s2.x * 32 + j]);
            float m3 = bf2f(emh_bf[(size_t)s3.x * 32 + j]);
            acc_h += (m0 + m1) + (m2 + m3);
            if (j < 16) {
                float w0 = __int_as_float(s0.y), w1 = __int_as_float(s1.y);
                float w2 = __int_as_float(s2.y), w3 = __int_as_float(s3.y);
                acc_g = fmaf(w0, bf2f(ef_bf[(size_t)s0.x * 16 + j]), acc_g);
                acc_g = fmaf(w1, bf2f(ef_bf[(size_t)s1.x * 16 + j]), acc_g);
                acc_g = fmaf(w2, bf2f(ef_bf[(size_t)s2.x * 16 + j]), acc_g);
                acc_g = fmaf(w3, bf2f(ef_bf[(size_t)s3.x * 16 + j]), acc_g);
                sumw += (w0 + w1) + (w2 + w3);
            }
        }
        for (; k < e2; ++k) {
            int2 s0 = csr[k];
            acc_h += bf2f(emh_bf[(size_t)s0.x * 32 + j]);
            if (j < 16) {
                float w0 = __int_as_float(s0.y);
                acc_g = fmaf(w0, bf2f(ef_bf[(size_t)s0.x * 16 + j]), acc_g);
                sumw += w0;
            }
        }
        if (j < 16) {
            float val = acc_g - sumw * e_feat[(size_t)n * 16 + j];
            gout[(size_t)n * 16 + j] = val;
            gbf[(size_t)n * 16 + j] = f2bf(val);
        }
    }
    out_h[(size_t)n * 32 + j] = fmaxf(acc_h, 0.f);
}

// ---- pull2: g2x, g2y. bf16 gathers, fp32 own-node + accumulate. 16 lanes/node ----
__global__ __launch_bounds__(256) void pull2_k(const float* __restrict__ gx,
                                               const float* __restrict__ gy,
                                               const unsigned short* __restrict__ gx_bf,
                                               const unsigned short* __restrict__ gy_bf,
                                               const int2* __restrict__ csr_a,
                                               const int* __restrict__ off_a,
                                               const int2* __restrict__ csr_b,
                                               const int* __restrict__ off_b,
                                               float* __restrict__ g2x,
                                               float* __restrict__ g2y) {
    int g = blockIdx.x * 256 + threadIdx.x;
    int n = g >> 4, j = g & 15;
    if (n >= NN) return;

#pragma unroll
    for (int half = 0; half < 2; ++half) {
        const int2* csr = half ? csr_b : csr_a;
        const int* off = half ? off_b : off_a;
        const float* gin = half ? gy : gx;
        const unsigned short* gbf = half ? gy_bf : gx_bf;
        float* g2 = half ? g2y : g2x;
        float acc = 0.f, sumw = 0.f;
        int k = off[n], e2 = off[n + 1];
        for (; k + 3 < e2; k += 4) {
            int2 s0 = csr[k], s1 = csr[k + 1], s2 = csr[k + 2], s3 = csr[k + 3];
            float w0 = __int_as_float(s0.y), w1 = __int_as_float(s1.y);
            float w2 = __int_as_float(s2.y), w3 = __int_as_float(s3.y);
            acc = fmaf(w0, bf2f(gbf[(size_t)s0.x * 16 + j]), acc);
            acc = fmaf(w1, bf2f(gbf[(size_t)s1.x * 16 + j]), acc);
            acc = fmaf(w2, bf2f(gbf[(size_t)s2.x * 16 + j]), acc);
            acc = fmaf(w3, bf2f(gbf[(size_t)s3.x * 16 + j]), acc);
            sumw += (w0 + w1) + (w2 + w3);
        }
        for (; k < e2; ++k) {
            int2 s0 = csr[k];
            float w0 = __int_as_float(s0.y);
            acc = fmaf(w0, bf2f(gbf[(size_t)s0.x * 16 + j]), acc);
            sumw += w0;
        }
        g2[(size_t)n * 16 + j] = acc - sumw * gin[(size_t)n * 16 + j];
    }
}

// ---------------- final head: bf16 MFMA GEMM (64 nodes/block) ----------------
__global__ __launch_bounds__(256) void final_mfma_k(const float* __restrict__ h,
                                                    const float* __restrict__ gx,
                                                    const float* __restrict__ gy,
                                                    const float* __restrict__ g2x,
                                                    const float* __restrict__ g2y,
                                                    const float* __restrict__ rain0,
                                                    const float* __restrict__ W_rin,
                                                    const float* __restrict__ W_rout,
                                                    float* __restrict__ out_rain) {
    __shared__ __align__(16) unsigned short Wt[128 * AP];  // 26.6 KB
    __shared__ __align__(16) unsigned short At[64 * AP];   // 13.3 KB
    __shared__ float Wo[128];
    const int tid = threadIdx.x;

    for (int i = tid; i < 3072; i += 256) {
        int k = i >> 5;
        int c = (i & 31) * 4;
        float4 wv = *reinterpret_cast<const float4*>(W_rin + k * 128 + c);
        Wt[(c + 0) * AP + k] = f2bf(wv.x);
        Wt[(c + 1) * AP + k] = f2bf(wv.y);
        Wt[(c + 2) * AP + k] = f2bf(wv.z);
        Wt[(c + 3) * AP + k] = f2bf(wv.w);
    }
    if (tid < 128) Wo[tid] = W_rout[tid];

    {
        int n = tid >> 2, q = tid & 3;
        int node = blockIdx.x * 64 + n;
        float f[24];
#define LD4(di, p) { float4 v_ = *reinterpret_cast<const float4*>(p); \
                     f[di] = v_.x; f[di+1] = v_.y; f[di+2] = v_.z; f[di+3] = v_.w; }
        if (node < NN) {
            if (q == 0) {
                LD4(0,  h + (size_t)node * 32 + 0);
                LD4(4,  h + (size_t)node * 32 + 4);
                LD4(8,  h + (size_t)node * 32 + 8);
                LD4(12, h + (size_t)node * 32 + 12);
                LD4(16, h + (size_t)node * 32 + 16);
                LD4(20, h + (size_t)node * 32 + 20);
            } else if (q == 1) {
                LD4(0,  h + (size_t)node * 32 + 24);
                LD4(4,  h + (size_t)node * 32 + 28);
                LD4(8,  gx + (size_t)node * 16 + 0);
                LD4(12, gx + (size_t)node * 16 + 4);
                LD4(16, gx + (size_t)node * 16 + 8);
                LD4(20, gx + (size_t)node * 16 + 12);
            } else if (q == 2) {
                LD4(0,  gy + (size_t)node * 16 + 0);
                LD4(4,  gy + (size_t)node * 16 + 4);
                LD4(8,  gy + (size_t)node * 16 + 8);
                LD4(12, gy + (size_t)node * 16 + 12);
                LD4(16, g2x + (size_t)node * 16 + 0);
                LD4(20, g2x + (size_t)node * 16 + 4);
            } else {
                LD4(0,  g2x + (size_t)node * 16 + 8);
                LD4(4,  g2x + (size_t)node * 16 + 12);
                LD4(8,  g2y + (size_t)node * 16 + 0);
                LD4(12, g2y + (size_t)node * 16 + 4);
                LD4(16, g2y + (size_t)node * 16 + 8);
                LD4(20, g2y + (size_t)node * 16 + 12);
            }
        } else {
#pragma unroll
            for (int i = 0; i < 24; ++i) f[i] = 0.f;
        }
#undef LD4
        unsigned pk[12];
#pragma unroll
        for (int i = 0; i < 12; ++i)
            pk[i] = (unsigned)f2bf(f[2 * i]) | ((unsigned)f2bf(f[2 * i + 1]) << 16);
        char* dp = (char*)At + n * (AP * 2) + q * 48;
        *reinterpret_cast<uint4*>(dp + 0)  = make_uint4(pk[0], pk[1], pk[2], pk[3]);
        *reinterpret_cast<uint4*>(dp + 16) = make_uint4(pk[4], pk[5], pk[6], pk[7]);
        *reinterpret_cast<uint4*>(dp + 32) = make_uint4(pk[8], pk[9], pk[10], pk[11]);
    }
    __syncthreads();

    const int w = tid >> 6;
    const int l = tid & 63;
    const int col = l & 15;
    const int kg = l >> 4;
    const char* Ab = (const char*)At + (w * 16 + col) * (AP * 2) + kg * 16;
    const char* Bb = (const char*)Wt + col * (AP * 2) + kg * 16;

    f32x4 acc[8];
#pragma unroll
    for (int ct = 0; ct < 8; ++ct) acc[ct] = (f32x4){0.f, 0.f, 0.f, 0.f};

#pragma unroll
    for (int ks = 0; ks < 3; ++ks) {
        bf16x8 af = *reinterpret_cast<const bf16x8*>(Ab + ks * 64);
#pragma unroll
        for (int ct = 0; ct < 8; ++ct) {
            bf16x8 bfr = *reinterpret_cast<const bf16x8*>(Bb + ct * 16 * (AP * 2) + ks * 64);
            acc[ct] = __builtin_amdgcn_mfma_f32_16x16x32_bf16(af, bfr, acc[ct], 0, 0, 0);
        }
    }

    float s0 = 0.f, s1 = 0.f, s2 = 0.f, s3 = 0.f;
#pragma unroll
    for (int ct = 0; ct < 8; ++ct) {
        float wo = Wo[ct * 16 + col];
        s0 = fmaf(fmaxf(acc[ct][0], 0.f), wo, s0);
        s1 = fmaf(fmaxf(acc[ct][1], 0.f), wo, s1);
        s2 = fmaf(fmaxf(acc[ct][2], 0.f), wo, s2);
        s3 = fmaf(fmaxf(acc[ct][3], 0.f), wo, s3);
    }
#pragma unroll
    for (int m = 1; m < 16; m <<= 1) {
        s0 += __shfl_xor(s0, m);
        s1 += __shfl_xor(s1, m);
        s2 += __shfl_xor(s2, m);
        s3 += __shfl_xor(s3, m);
    }
    if (col == 0) {
        int row = blockIdx.x * 64 + w * 16 + kg * 4;
        if (row + 0 < NN) out_rain[row + 0] = rain0[row + 0] + s0;
        if (row + 1 < NN) out_rain[row + 1] = rain0[row + 1] + s1;
        if (row + 2 < NN) out_rain[row + 2] = rain0[row + 2] + s2;
        if (row + 3 < NN) out_rain[row + 3] = rain0[row + 3] + s3;
    }
}

extern "C" void kernel_launch(void* const* d_in, const int* in_sizes, int n_in,
                              void* d_out, int out_size, void* d_ws, size_t ws_size,
                              hipStream_t stream) {
    const float* h_feat  = (const float*)d_in[0];
    const float* e_feat  = (const float*)d_in[1];
    const float* rain0   = (const float*)d_in[2];
    const float* w_xx    = (const float*)d_in[3];
    const float* w_yy    = (const float*)d_in[4];
    const float* W_trans = (const float*)d_in[5];
    const float* W_rin   = (const float*)d_in[6];
    const float* W_rout  = (const float*)d_in[7];
    const int* src_xx    = (const int*)d_in[8];
    const int* dst_xx    = (const int*)d_in[9];
    const int* src_yy    = (const int*)d_in[10];
    const int* dst_yy    = (const int*)d_in[11];

    // ws layout:
    unsigned short* emh_bf = (unsigned short*)d_ws;            // NN*32 bf16 = 6.4MB
    unsigned short* ef_bf  = emh_bf + (size_t)NN * 32;         // 3.2MB
    unsigned short* gx_bf  = ef_bf + (size_t)NN * 16;          // 3.2MB
    unsigned short* gy_bf  = gx_bf + (size_t)NN * 16;          // 3.2MB
    float* gx = (float*)(gy_bf + (size_t)NN * 16);             // 6.4MB
    float* gy = gx + (size_t)NN * 16;                          // 6.4MB
    int2* csr_xx = (int2*)(gy + (size_t)NN * 16);              // 12.8MB
    int2* csr_yy = csr_xx + EE;                                // 12.8MB
    int* off_xx  = (int*)(csr_yy + EE);                        // OFFP ints
    int* off_yy  = off_xx + OFFP;                              // OFFP ints
    int* partial = off_yy + OFFP;                              // 2*C_CH*NN ints (12.8MB)
    float* g2x   = (float*)partial;                            // alias (partial dead after scatter)
    float* g2y   = g2x + (size_t)NN * 16;
    int* bsum    = partial + (size_t)2 * C_CH * NN;            // 64
    int* bbase   = bsum + 64;                                  // 64

    float* out_rain = (float*)d_out;           // NN
    float* out_h    = out_rain + NN;           // NN*32

    const int TB = (NN * 32 + 1023) / 1024;                    // 3125 trans blocks
    const int HB = 2 * NRANGE * C_CH;                          // 512 hist blocks
    fused_th_k<<<TB + HB, 1024, 0, stream>>>(h_feat, e_feat, W_trans, emh_bf, ef_bf,
                                             dst_xx, dst_yy, partial, TB);

    scanA_k<<<2 * NB, 1024, 0, stream>>>(partial, bsum);
    scanB_k<<<1, 64, 0, stream>>>(bsum, bbase, off_xx, off_yy);
    scanC_k<<<2 * NB, 1024, 0, stream>>>(partial, off_xx, off_yy, bbase);

    scatter_k<<<2 * NRANGE * C_CH, 1024, 0, stream>>>(
        dst_xx, src_xx, w_xx, dst_yy, src_yy, w_yy, partial, csr_xx, csr_yy);

    pull1_k<<<(NN * 32 + 255) / 256, 256, 0, stream>>>(
        emh_bf, ef_bf, e_feat, csr_xx, off_xx, csr_yy, off_yy,
        out_h, gx, gy, gx_bf, gy_bf);

    pull2_k<<<(NN * 16 + 255) / 256, 256, 0, stream>>>(
        gx, gy, gx_bf, gy_bf, csr_xx, off_xx, csr_yy, off_yy, g2x, g2y);

    final_mfma_k<<<(NN + 63) / 64, 256, 0, stream>>>(
        out_h, gx, gy, g2x, g2y, rain0, W_rin, W_rout, out_rain);
}

// Round 11
// 316.265 us; speedup vs baseline: 8.7135x; 1.0062x over previous
//
#include <hip/hip_runtime.h>
#include <hip/hip_bf16.h>

#define NN 100000
#define EE 1600000
#define SCAN_CHUNK 4096
#define NB ((NN + SCAN_CHUNK - 1) / SCAN_CHUNK)   // 25 scan blocks per type
#define OFFP (NN + 8)                             // padded off array
#define NRANGE 8                                  // dst ranges (== XCDs)
#define RSZ (NN / NRANGE)                         // 12500 nodes per range
#define C_CH 16                                   // edge chunks per type
#define CHUNK_E (EE / C_CH)                       // 100000 edges per chunk
#define AP 104                                    // bf16 LDS row pad (208 B)

typedef __attribute__((ext_vector_type(8))) short bf16x8;
typedef __attribute__((ext_vector_type(4))) float f32x4;

__device__ inline unsigned short f2bf(float f) {
    unsigned u = __float_as_uint(f);
    return (unsigned short)((u + 0x7FFFu + ((u >> 16) & 1u)) >> 16);
}
__device__ inline float bf2f(unsigned short u) {
    return __uint_as_float(((unsigned)u) << 16);
}

// ---- fused: blocks [0,TB) trans (emh_bf, ef_bf); blocks [TB,..) LDS hist ----
// hist decode: idx = bid-TB; t=idx>>7, r=idx&7, c=(idx>>3)&15.
__global__ __launch_bounds__(1024) void fused_th_k(const float* __restrict__ h_feat,
                                                   const float* __restrict__ e_feat,
                                                   const float* __restrict__ W_trans,
                                                   unsigned short* __restrict__ emh_bf,
                                                   unsigned short* __restrict__ ef_bf,
                                                   const int* __restrict__ dst_a,
                                                   const int* __restrict__ dst_b,
                                                   int* __restrict__ partial, int TB) {
    __shared__ float Wl[48 * 32];
    __shared__ int bins[RSZ];
    if ((int)blockIdx.x < TB) {
        for (int i = threadIdx.x; i < 48 * 32; i += 1024) Wl[i] = W_trans[i];
        __syncthreads();
        int t = blockIdx.x * 1024 + threadIdx.x;
        if (t >= NN * 32) return;
        int n = t >> 5, j = t & 31;
        const float* hrow = h_feat + (size_t)n * 32;
        const float* erow = e_feat + (size_t)n * 16;
        float acc = 0.f;
#pragma unroll 8
        for (int k = 0; k < 32; ++k) acc = fmaf(hrow[k], Wl[k * 32 + j], acc);
#pragma unroll 8
        for (int k = 0; k < 16; ++k) acc = fmaf(erow[k], Wl[(32 + k) * 32 + j], acc);
        emh_bf[t] = f2bf(fmaxf(acc, 0.f));
        if (j < 16) ef_bf[(size_t)n * 16 + j] = f2bf(erow[j]);
    } else {
        for (int i = threadIdx.x; i < RSZ; i += 1024) bins[i] = 0;
        __syncthreads();
        const int idx = (int)blockIdx.x - TB;
        const int t = idx >> 7;
        const int r = idx & 7;
        const int c = (idx >> 3) & 15;
        const int* dst = t ? dst_b : dst_a;
        const int lo = r * RSZ;
        const long base = (long)c * CHUNK_E;
        for (int i = threadIdx.x * 4; i < CHUNK_E; i += 4096) {
            int4 d = *reinterpret_cast<const int4*>(dst + base + i);
            int x;
            x = d.x - lo; if ((unsigned)x < RSZ) atomicAdd(&bins[x], 1);
            x = d.y - lo; if ((unsigned)x < RSZ) atomicAdd(&bins[x], 1);
            x = d.z - lo; if ((unsigned)x < RSZ) atomicAdd(&bins[x], 1);
            x = d.w - lo; if ((unsigned)x < RSZ) atomicAdd(&bins[x], 1);
        }
        __syncthreads();
        int* pout = partial + (long)(t * C_CH + c) * NN + lo;
        for (int i = threadIdx.x; i < RSZ; i += 1024) pout[i] = bins[i];
    }
}

// ---------------- scan phase A: per-4096-node-chunk totals ----------------
__global__ __launch_bounds__(1024) void scanA_k(const int* __restrict__ partial,
                                                int* __restrict__ bsum) {
    __shared__ int wsum[16];
    const int b = blockIdx.x;              // 0..2*NB-1
    const int t = (b >= NB) ? 1 : 0;
    const int i0 = (b % NB) * SCAN_CHUNK + threadIdx.x * 4;
    int4 s = make_int4(0, 0, 0, 0);
    if (i0 < NN) {
#pragma unroll
        for (int c = 0; c < C_CH; ++c) {
            int4 v = *reinterpret_cast<const int4*>(partial + (long)(t * C_CH + c) * NN + i0);
            s.x += v.x; s.y += v.y; s.z += v.z; s.w += v.w;
        }
    }
    int tot = s.x + s.y + s.z + s.w;
#pragma unroll
    for (int d = 32; d; d >>= 1) tot += __shfl_down(tot, d);
    int lane = threadIdx.x & 63, w = threadIdx.x >> 6;
    if (lane == 0) wsum[w] = tot;
    __syncthreads();
    if (threadIdx.x == 0) {
        int sm = 0;
#pragma unroll
        for (int q = 0; q < 16; ++q) sm += wsum[q];
        bsum[b] = sm;
    }
}

// ---------------- scan phase B: segmented exclusive scan of block sums ------
__global__ __launch_bounds__(64) void scanB_k(const int* __restrict__ bsum,
                                              int* __restrict__ bbase,
                                              int* __restrict__ off_a,
                                              int* __restrict__ off_b) {
    int lane = threadIdx.x;
    int v = (lane < 2 * NB) ? bsum[lane] : 0;
    int seg = lane / NB;
    int inc = v;
#pragma unroll
    for (int d = 1; d < 64; d <<= 1) {
        int x = __shfl_up(inc, d);
        if (lane >= d && (lane - d) / NB == seg) inc += x;
    }
    int excl = inc - v;
    if (lane < 2 * NB) bbase[lane] = excl;
    if (lane == NB - 1) off_a[NN] = inc;
    if (lane == 2 * NB - 1) off_b[NN] = inc;
}

// ---- scan phase C: off[] = exclusive node scan; partial -> per-chunk cursors ----
__global__ __launch_bounds__(1024) void scanC_k(int* __restrict__ partial,
                                                int* __restrict__ off_a,
                                                int* __restrict__ off_b,
                                                const int* __restrict__ bbase) {
    __shared__ int wsum[16];
    const int b = blockIdx.x;
    const int t = (b >= NB) ? 1 : 0;
    int* off = t ? off_b : off_a;
    const int base0 = bbase[b];
    const int i0 = (b % NB) * SCAN_CHUNK + threadIdx.x * 4;
    int4 s = make_int4(0, 0, 0, 0);
    if (i0 < NN) {
#pragma unroll
        for (int c = 0; c < C_CH; ++c) {
            int4 v = *reinterpret_cast<const int4*>(partial + (long)(t * C_CH + c) * NN + i0);
            s.x += v.x; s.y += v.y; s.z += v.z; s.w += v.w;
        }
    }
    int s1 = s.x, s2 = s1 + s.y, s3 = s2 + s.z, tot = s3 + s.w;
    int lane = threadIdx.x & 63, w = threadIdx.x >> 6;
    int inc = tot;
#pragma unroll
    for (int d = 1; d < 64; d <<= 1) {
        int x = __shfl_up(inc, d);
        if (lane >= d) inc += x;
    }
    if (lane == 63) wsum[w] = inc;
    int texcl = inc - tot;
    __syncthreads();
    if (threadIdx.x == 0) {
        int r = 0;
#pragma unroll
        for (int q = 0; q < 16; ++q) { int x = wsum[q]; wsum[q] = r; r += x; }
    }
    __syncthreads();
    const int base = base0 + wsum[w] + texcl;
    if (i0 < NN) {
        *reinterpret_cast<int4*>(off + i0) = make_int4(base, base + s1, base + s2, base + s3);
        int4 run = make_int4(base, base + s1, base + s2, base + s3);
#pragma unroll
        for (int c = 0; c < C_CH; ++c) {
            int* p = partial + (long)(t * C_CH + c) * NN + i0;
            int4 v = *reinterpret_cast<const int4*>(p);
            *reinterpret_cast<int4*>(p) = run;
            run.x += v.x; run.y += v.y; run.z += v.z; run.w += v.w;
        }
    }
}

// ------ scatter: LDS cursors, zero global atomics, UNCONDITIONAL vec loads ------
// 256 blocks: t=bid>>7, r=bid&7, c=(bid>>3)&15; bid%8==r -> csr XCD-local.
// dst/src/w all loaded as int4 BEFORE the range test: no global loads on the
// divergent path -> hit branch is {LDS atomic, store} only.
__global__ __launch_bounds__(1024) void scatter_k(const int* __restrict__ dst_a,
                                                  const int* __restrict__ src_a,
                                                  const float* __restrict__ w_a,
                                                  const int* __restrict__ dst_b,
                                                  const int* __restrict__ src_b,
                                                  const float* __restrict__ w_b,
                                                  const int* __restrict__ partial,
                                                  int2* __restrict__ csr_a,
                                                  int2* __restrict__ csr_b) {
    __shared__ int curs[RSZ];
    const int bid = blockIdx.x;
    const int t = bid >> 7;
    const int r = bid & 7;
    const int c = (bid >> 3) & 15;
    const int* dst = t ? dst_b : dst_a;
    const int* src = t ? src_b : src_a;
    const float* wv = t ? w_b : w_a;
    int2* csr = t ? csr_b : csr_a;
    const int lo = r * RSZ;
    const int* pin = partial + (long)(t * C_CH + c) * NN + lo;
    for (int i = threadIdx.x; i < RSZ; i += 1024) curs[i] = pin[i];
    __syncthreads();
    const long base = (long)c * CHUNK_E;
    for (int i = threadIdx.x * 4; i < CHUNK_E; i += 4096) {
        int4 d = *reinterpret_cast<const int4*>(dst + base + i);
        int4 s = *reinterpret_cast<const int4*>(src + base + i);
        float4 w = *reinterpret_cast<const float4*>(wv + base + i);
        int x;
        x = d.x - lo;
        if ((unsigned)x < RSZ) {
            int p = atomicAdd(&curs[x], 1);
            csr[p] = make_int2(s.x, __float_as_int(w.x));
        }
        x = d.y - lo;
        if ((unsigned)x < RSZ) {
            int p = atomicAdd(&curs[x], 1);
            csr[p] = make_int2(s.y, __float_as_int(w.y));
        }
        x = d.z - lo;
        if ((unsigned)x < RSZ) {
            int p = atomicAdd(&curs[x], 1);
            csr[p] = make_int2(s.z, __float_as_int(w.z));
        }
        x = d.w - lo;
        if ((unsigned)x < RSZ) {
            int p = atomicAdd(&curs[x], 1);
            csr[p] = make_int2(s.w, __float_as_int(w.w));
        }
    }
}

// ---- pull1: h, gx, gy. bf16 gathers, fp32 accumulate. 32 lanes/node ----
__global__ __launch_bounds__(256) void pull1_k(const unsigned short* __restrict__ emh_bf,
                                               const unsigned short* __restrict__ ef_bf,
                                               const float* __restrict__ e_feat,
                                               const int2* __restrict__ csr_a,
                                               const int* __restrict__ off_a,
                                               const int2* __restrict__ csr_b,
                                               const int* __restrict__ off_b,
                                               float* __restrict__ out_h,
                                               float* __restrict__ gx,
                                               float* __restrict__ gy,
                                               unsigned short* __restrict__ gx_bf,
                                               unsigned short* __restrict__ gy_bf) {
    int g = blockIdx.x * 256 + threadIdx.x;
    int n = g >> 5, j = g & 31;
    if (n >= NN) return;
    float acc_h = 0.f;

#pragma unroll
    for (int half = 0; half < 2; ++half) {
        const int2* csr = half ? csr_b : csr_a;
        const int* off = half ? off_b : off_a;
        float* gout = half ? gy : gx;
        unsigned short* gbf = half ? gy_bf : gx_bf;
        float acc_g = 0.f, sumw = 0.f;
        int k = off[n], e2 = off[n + 1];
        for (; k + 3 < e2; k += 4) {
            int2 s0 = csr[k], s1 = csr[k + 1], s2 = csr[k + 2], s3 = csr[k + 3];
            float m0 = bf2f(emh_bf[(size_t)s0.x * 32 + j]);
            float m1 = bf2f(emh_bf[(size_t)s1.x * 32 + j]);
            float m2 = bf2f(emh_bf[(size_t)s2.x * 32 + j]);
            float m3 = bf2f(emh_bf[(size_t)s3.x * 32 + j]);
            acc_h += (m0 + m1) + (m2 + m3);
            if (j < 16) {
                float w0 = __int_as_float(s0.y), w1 = __int_as_float(s1.y);
                float w2 = __int_as_float(s2.y), w3 = __int_as_float(s3.y);
                acc_g = fmaf(w0, bf2f(ef_bf[(size_t)s0.x * 16 + j]), acc_g);
                acc_g = fmaf(w1, bf2f(ef_bf[(size_t)s1.x * 16 + j]), acc_g);
                acc_g = fmaf(w2, bf2f(ef_bf[(size_t)s2.x * 16 + j]), acc_g);
                acc_g = fmaf(w3, bf2f(ef_bf[(size_t)s3.x * 16 + j]), acc_g);
                sumw += (w0 + w1) + (w2 + w3);
            }
        }
        for (; k < e2; ++k) {
            int2 s0 = csr[k];
            acc_h += bf2f(emh_bf[(size_t)s0.x * 32 + j]);
            if (j < 16) {
                float w0 = __int_as_float(s0.y);
                acc_g = fmaf(w0, bf2f(ef_bf[(size_t)s0.x * 16 + j]), acc_g);
                sumw += w0;
            }
        }
        if (j < 16) {
            float val = acc_g - sumw * e_feat[(size_t)n * 16 + j];
            gout[(size_t)n * 16 + j] = val;
            gbf[(size_t)n * 16 + j] = f2bf(val);
        }
    }
    out_h[(size_t)n * 32 + j] = fmaxf(acc_h, 0.f);
}

// ---- pull2: g2x, g2y. bf16 gathers, fp32 own-node + accumulate. 16 lanes/node ----
__global__ __launch_bounds__(256) void pull2_k(const float* __restrict__ gx,
                                               const float* __restrict__ gy,
                                               const unsigned short* __restrict__ gx_bf,
                                               const unsigned short* __restrict__ gy_bf,
                                               const int2* __restrict__ csr_a,
                                               const int* __restrict__ off_a,
                                               const int2* __restrict__ csr_b,
                                               const int* __restrict__ off_b,
                                               float* __restrict__ g2x,
                                               float* __restrict__ g2y) {
    int g = blockIdx.x * 256 + threadIdx.x;
    int n = g >> 4, j = g & 15;
    if (n >= NN) return;

#pragma unroll
    for (int half = 0; half < 2; ++half) {
        const int2* csr = half ? csr_b : csr_a;
        const int* off = half ? off_b : off_a;
        const float* gin = half ? gy : gx;
        const unsigned short* gbf = half ? gy_bf : gx_bf;
        float* g2 = half ? g2y : g2x;
        float acc = 0.f, sumw = 0.f;
        int k = off[n], e2 = off[n + 1];
        for (; k + 3 < e2; k += 4) {
            int2 s0 = csr[k], s1 = csr[k + 1], s2 = csr[k + 2], s3 = csr[k + 3];
            float w0 = __int_as_float(s0.y), w1 = __int_as_float(s1.y);
            float w2 = __int_as_float(s2.y), w3 = __int_as_float(s3.y);
            acc = fmaf(w0, bf2f(gbf[(size_t)s0.x * 16 + j]), acc);
            acc = fmaf(w1, bf2f(gbf[(size_t)s1.x * 16 + j]), acc);
            acc = fmaf(w2, bf2f(gbf[(size_t)s2.x * 16 + j]), acc);
            acc = fmaf(w3, bf2f(gbf[(size_t)s3.x * 16 + j]), acc);
            sumw += (w0 + w1) + (w2 + w3);
        }
        for (; k < e2; ++k) {
            int2 s0 = csr[k];
            float w0 = __int_as_float(s0.y);
            acc = fmaf(w0, bf2f(gbf[(size_t)s0.x * 16 + j]), acc);
            sumw += w0;
        }
        g2[(size_t)n * 16 + j] = acc - sumw * gin[(size_t)n * 16 + j];
    }
}

// ---------------- final head: bf16 MFMA GEMM (64 nodes/block) ----------------
__global__ __launch_bounds__(256) void final_mfma_k(const float* __restrict__ h,
                                                    const float* __restrict__ gx,
                                                    const float* __restrict__ gy,
                                                    const float* __restrict__ g2x,
                                                    const float* __restrict__ g2y,
                                                    const float* __restrict__ rain0,
                                                    const float* __restrict__ W_rin,
                                                    const float* __restrict__ W_rout,
                                                    float* __restrict__ out_rain) {
    __shared__ __align__(16) unsigned short Wt[128 * AP];  // 26.6 KB
    __shared__ __align__(16) unsigned short At[64 * AP];   // 13.3 KB
    __shared__ float Wo[128];
    const int tid = threadIdx.x;

    for (int i = tid; i < 3072; i += 256) {
        int k = i >> 5;
        int c = (i & 31) * 4;
        float4 wv = *reinterpret_cast<const float4*>(W_rin + k * 128 + c);
        Wt[(c + 0) * AP + k] = f2bf(wv.x);
        Wt[(c + 1) * AP + k] = f2bf(wv.y);
        Wt[(c + 2) * AP + k] = f2bf(wv.z);
        Wt[(c + 3) * AP + k] = f2bf(wv.w);
    }
    if (tid < 128) Wo[tid] = W_rout[tid];

    {
        int n = tid >> 2, q = tid & 3;
        int node = blockIdx.x * 64 + n;
        float f[24];
#define LD4(di, p) { float4 v_ = *reinterpret_cast<const float4*>(p); \
                     f[di] = v_.x; f[di+1] = v_.y; f[di+2] = v_.z; f[di+3] = v_.w; }
        if (node < NN) {
            if (q == 0) {
                LD4(0,  h + (size_t)node * 32 + 0);
                LD4(4,  h + (size_t)node * 32 + 4);
                LD4(8,  h + (size_t)node * 32 + 8);
                LD4(12, h + (size_t)node * 32 + 12);
                LD4(16, h + (size_t)node * 32 + 16);
                LD4(20, h + (size_t)node * 32 + 20);
            } else if (q == 1) {
                LD4(0,  h + (size_t)node * 32 + 24);
                LD4(4,  h + (size_t)node * 32 + 28);
                LD4(8,  gx + (size_t)node * 16 + 0);
                LD4(12, gx + (size_t)node * 16 + 4);
                LD4(16, gx + (size_t)node * 16 + 8);
                LD4(20, gx + (size_t)node * 16 + 12);
            } else if (q == 2) {
                LD4(0,  gy + (size_t)node * 16 + 0);
                LD4(4,  gy + (size_t)node * 16 + 4);
                LD4(8,  gy + (size_t)node * 16 + 8);
                LD4(12, gy + (size_t)node * 16 + 12);
                LD4(16, g2x + (size_t)node * 16 + 0);
                LD4(20, g2x + (size_t)node * 16 + 4);
            } else {
                LD4(0,  g2x + (size_t)node * 16 + 8);
                LD4(4,  g2x + (size_t)node * 16 + 12);
                LD4(8,  g2y + (size_t)node * 16 + 0);
                LD4(12, g2y + (size_t)node * 16 + 4);
                LD4(16, g2y + (size_t)node * 16 + 8);
                LD4(20, g2y + (size_t)node * 16 + 12);
            }
        } else {
#pragma unroll
            for (int i = 0; i < 24; ++i) f[i] = 0.f;
        }
#undef LD4
        unsigned pk[12];
#pragma unroll
        for (int i = 0; i < 12; ++i)
            pk[i] = (unsigned)f2bf(f[2 * i]) | ((unsigned)f2bf(f[2 * i + 1]) << 16);
        char* dp = (char*)At + n * (AP * 2) + q * 48;
        *reinterpret_cast<uint4*>(dp + 0)  = make_uint4(pk[0], pk[1], pk[2], pk[3]);
        *reinterpret_cast<uint4*>(dp + 16) = make_uint4(pk[4], pk[5], pk[6], pk[7]);
        *reinterpret_cast<uint4*>(dp + 32) = make_uint4(pk[8], pk[9], pk[10], pk[11]);
    }
    __syncthreads();

    const int w = tid >> 6;
    const int l = tid & 63;
    const int col = l & 15;
    const int kg = l >> 4;
    const char* Ab = (const char*)At + (w * 16 + col) * (AP * 2) + kg * 16;
    const char* Bb = (const char*)Wt + col * (AP * 2) + kg * 16;

    f32x4 acc[8];
#pragma unroll
    for (int ct = 0; ct < 8; ++ct) acc[ct] = (f32x4){0.f, 0.f, 0.f, 0.f};

#pragma unroll
    for (int ks = 0; ks < 3; ++ks) {
        bf16x8 af = *reinterpret_cast<const bf16x8*>(Ab + ks * 64);
#pragma unroll
        for (int ct = 0; ct < 8; ++ct) {
            bf16x8 bfr = *reinterpret_cast<const bf16x8*>(Bb + ct * 16 * (AP * 2) + ks * 64);
            acc[ct] = __builtin_amdgcn_mfma_f32_16x16x32_bf16(af, bfr, acc[ct], 0, 0, 0);
        }
    }

    float s0 = 0.f, s1 = 0.f, s2 = 0.f, s3 = 0.f;
#pragma unroll
    for (int ct = 0; ct < 8; ++ct) {
        float wo = Wo[ct * 16 + col];
        s0 = fmaf(fmaxf(acc[ct][0], 0.f), wo, s0);
        s1 = fmaf(fmaxf(acc[ct][1], 0.f), wo, s1);
        s2 = fmaf(fmaxf(acc[ct][2], 0.f), wo, s2);
        s3 = fmaf(fmaxf(acc[ct][3], 0.f), wo, s3);
    }
#pragma unroll
    for (int m = 1; m < 16; m <<= 1) {
        s0 += __shfl_xor(s0, m);
        s1 += __shfl_xor(s1, m);
        s2 += __shfl_xor(s2, m);
        s3 += __shfl_xor(s3, m);
    }
    if (col == 0) {
        int row = blockIdx.x * 64 + w * 16 + kg * 4;
        if (row + 0 < NN) out_rain[row + 0] = rain0[row + 0] + s0;
        if (row + 1 < NN) out_rain[row + 1] = rain0[row + 1] + s1;
        if (row + 2 < NN) out_rain[row + 2] = rain0[row + 2] + s2;
        if (row + 3 < NN) out_rain[row + 3] = rain0[row + 3] + s3;
    }
}

extern "C" void kernel_launch(void* const* d_in, const int* in_sizes, int n_in,
                              void* d_out, int out_size, void* d_ws, size_t ws_size,
                              hipStream_t stream) {
    const float* h_feat  = (const float*)d_in[0];
    const float* e_feat  = (const float*)d_in[1];
    const float* rain0   = (const float*)d_in[2];
    const float* w_xx    = (const float*)d_in[3];
    const float* w_yy    = (const float*)d_in[4];
    const float* W_trans = (const float*)d_in[5];
    const float* W_rin   = (const float*)d_in[6];
    const float* W_rout  = (const float*)d_in[7];
    const int* src_xx    = (const int*)d_in[8];
    const int* dst_xx    = (const int*)d_in[9];
    const int* src_yy    = (const int*)d_in[10];
    const int* dst_yy    = (const int*)d_in[11];

    // ws layout:
    unsigned short* emh_bf = (unsigned short*)d_ws;            // NN*32 bf16 = 6.4MB
    unsigned short* ef_bf  = emh_bf + (size_t)NN * 32;         // 3.2MB
    unsigned short* gx_bf  = ef_bf + (size_t)NN * 16;          // 3.2MB
    unsigned short* gy_bf  = gx_bf + (size_t)NN * 16;          // 3.2MB
    float* gx = (float*)(gy_bf + (size_t)NN * 16);             // 6.4MB
    float* gy = gx + (size_t)NN * 16;                          // 6.4MB
    int2* csr_xx = (int2*)(gy + (size_t)NN * 16);              // 12.8MB
    int2* csr_yy = csr_xx + EE;                                // 12.8MB
    int* off_xx  = (int*)(csr_yy + EE);                        // OFFP ints
    int* off_yy  = off_xx + OFFP;                              // OFFP ints
    int* partial = off_yy + OFFP;                              // 2*C_CH*NN ints (12.8MB)
    float* g2x   = (float*)partial;                            // alias (partial dead after scatter)
    float* g2y   = g2x + (size_t)NN * 16;
    int* bsum    = partial + (size_t)2 * C_CH * NN;            // 64
    int* bbase   = bsum + 64;                                  // 64

    float* out_rain = (float*)d_out;           // NN
    float* out_h    = out_rain + NN;           // NN*32

    const int TB = (NN * 32 + 1023) / 1024;                    // 3125 trans blocks
    const int HB = 2 * NRANGE * C_CH;                          // 256 hist blocks
    fused_th_k<<<TB + HB, 1024, 0, stream>>>(h_feat, e_feat, W_trans, emh_bf, ef_bf,
                                             dst_xx, dst_yy, partial, TB);

    scanA_k<<<2 * NB, 1024, 0, stream>>>(partial, bsum);
    scanB_k<<<1, 64, 0, stream>>>(bsum, bbase, off_xx, off_yy);
    scanC_k<<<2 * NB, 1024, 0, stream>>>(partial, off_xx, off_yy, bbase);

    scatter_k<<<2 * NRANGE * C_CH, 1024, 0, stream>>>(
        dst_xx, src_xx, w_xx, dst_yy, src_yy, w_yy, partial, csr_xx, csr_yy);

    pull1_k<<<(NN * 32 + 255) / 256, 256, 0, stream>>>(
        emh_bf, ef_bf, e_feat, csr_xx, off_xx, csr_yy, off_yy,
        out_h, gx, gy, gx_bf, gy_bf);

    pull2_k<<<(NN * 16 + 255) / 256, 256, 0, stream>>>(
        gx, gy, gx_bf, gy_bf, csr_xx, off_xx, csr_yy, off_yy, g2x, g2y);

    final_mfma_k<<<(NN + 63) / 64, 256, 0, stream>>>(
        out_h, gx, gy, g2x, g2y, rain0, W_rin, W_rout, out_rain);
}

// Round 12
// 301.517 us; speedup vs baseline: 9.1397x; 1.0489x over previous
//
#include <hip/hip_runtime.h>
#include <hip/hip_bf16.h>

#define NN 100000
#define EE 1600000
#define SCAN_CHUNK 4096
#define NB ((NN + SCAN_CHUNK - 1) / SCAN_CHUNK)   // 25 scan blocks per type
#define OFFP (NN + 8)                             // padded off array
#define NRANGE 4                                  // dst ranges (XCD-aligned pairs)
#define RSZ (NN / NRANGE)                         // 25000 nodes per range (exact)
#define C_CH 16                                   // edge chunks per type
#define CHUNK_E (EE / C_CH)                       // 100000 edges per chunk
#define AP 104                                    // bf16 LDS row pad (208 B)

typedef __attribute__((ext_vector_type(8))) short bf16x8;
typedef __attribute__((ext_vector_type(4))) float f32x4;

__device__ inline unsigned short f2bf(float f) {
    unsigned u = __float_as_uint(f);
    return (unsigned short)((u + 0x7FFFu + ((u >> 16) & 1u)) >> 16);
}
__device__ inline float bf2f(unsigned short u) {
    return __uint_as_float(((unsigned)u) << 16);
}

// ---- fused: blocks [0,TB) trans (emh_bf, ef_bf); blocks [TB,..) LDS hist ----
// hist decode (XCD-aligned): idx = bid-TB; q=idx&7 -> t=q>>2, p=q&3; c=idx>>3.
// idx%8 constant per (t,p) -> each range's partial rows written by ONE XCD.
__global__ __launch_bounds__(1024) void fused_th_k(const float* __restrict__ h_feat,
                                                   const float* __restrict__ e_feat,
                                                   const float* __restrict__ W_trans,
                                                   unsigned short* __restrict__ emh_bf,
                                                   unsigned short* __restrict__ ef_bf,
                                                   const int* __restrict__ dst_a,
                                                   const int* __restrict__ dst_b,
                                                   int* __restrict__ partial, int TB) {
    __shared__ float Wl[48 * 32];
    __shared__ int bins[RSZ];          // 100 KB
    if ((int)blockIdx.x < TB) {
        for (int i = threadIdx.x; i < 48 * 32; i += 1024) Wl[i] = W_trans[i];
        __syncthreads();
        int t = blockIdx.x * 1024 + threadIdx.x;
        if (t >= NN * 32) return;
        int n = t >> 5, j = t & 31;
        const float* hrow = h_feat + (size_t)n * 32;
        const float* erow = e_feat + (size_t)n * 16;
        float acc = 0.f;
#pragma unroll 8
        for (int k = 0; k < 32; ++k) acc = fmaf(hrow[k], Wl[k * 32 + j], acc);
#pragma unroll 8
        for (int k = 0; k < 16; ++k) acc = fmaf(erow[k], Wl[(32 + k) * 32 + j], acc);
        emh_bf[t] = f2bf(fmaxf(acc, 0.f));
        if (j < 16) ef_bf[(size_t)n * 16 + j] = f2bf(erow[j]);
    } else {
        for (int i = threadIdx.x; i < RSZ; i += 1024) bins[i] = 0;
        __syncthreads();
        const int idx = (int)blockIdx.x - TB;
        const int q = idx & 7;
        const int t = q >> 2;
        const int p = q & 3;
        const int c = idx >> 3;
        const int* dst = t ? dst_b : dst_a;
        const int lo = p * RSZ;
        const long base = (long)c * CHUNK_E;
        for (int i = threadIdx.x * 4; i < CHUNK_E; i += 4096) {
            int4 d = *reinterpret_cast<const int4*>(dst + base + i);
            int x;
            x = d.x - lo; if ((unsigned)x < RSZ) atomicAdd(&bins[x], 1);
            x = d.y - lo; if ((unsigned)x < RSZ) atomicAdd(&bins[x], 1);
            x = d.z - lo; if ((unsigned)x < RSZ) atomicAdd(&bins[x], 1);
            x = d.w - lo; if ((unsigned)x < RSZ) atomicAdd(&bins[x], 1);
        }
        __syncthreads();
        int* pout = partial + (long)(t * C_CH + c) * NN + lo;
        for (int i = threadIdx.x; i < RSZ; i += 1024) pout[i] = bins[i];
    }
}

// ---------------- scan phase A: per-4096-node-chunk totals ----------------
__global__ __launch_bounds__(1024) void scanA_k(const int* __restrict__ partial,
                                                int* __restrict__ bsum) {
    __shared__ int wsum[16];
    const int b = blockIdx.x;              // 0..2*NB-1
    const int t = (b >= NB) ? 1 : 0;
    const int i0 = (b % NB) * SCAN_CHUNK + threadIdx.x * 4;
    int4 s = make_int4(0, 0, 0, 0);
    if (i0 < NN) {
#pragma unroll
        for (int c = 0; c < C_CH; ++c) {
            int4 v = *reinterpret_cast<const int4*>(partial + (long)(t * C_CH + c) * NN + i0);
            s.x += v.x; s.y += v.y; s.z += v.z; s.w += v.w;
        }
    }
    int tot = s.x + s.y + s.z + s.w;
#pragma unroll
    for (int d = 32; d; d >>= 1) tot += __shfl_down(tot, d);
    int lane = threadIdx.x & 63, w = threadIdx.x >> 6;
    if (lane == 0) wsum[w] = tot;
    __syncthreads();
    if (threadIdx.x == 0) {
        int sm = 0;
#pragma unroll
        for (int q = 0; q < 16; ++q) sm += wsum[q];
        bsum[b] = sm;
    }
}

// ---------------- scan phase B: segmented exclusive scan of block sums ------
__global__ __launch_bounds__(64) void scanB_k(const int* __restrict__ bsum,
                                              int* __restrict__ bbase,
                                              int* __restrict__ off_a,
                                              int* __restrict__ off_b) {
    int lane = threadIdx.x;
    int v = (lane < 2 * NB) ? bsum[lane] : 0;
    int seg = lane / NB;
    int inc = v;
#pragma unroll
    for (int d = 1; d < 64; d <<= 1) {
        int x = __shfl_up(inc, d);
        if (lane >= d && (lane - d) / NB == seg) inc += x;
    }
    int excl = inc - v;
    if (lane < 2 * NB) bbase[lane] = excl;
    if (lane == NB - 1) off_a[NN] = inc;
    if (lane == 2 * NB - 1) off_b[NN] = inc;
}

// ---- scan phase C: off[] = exclusive node scan; partial -> per-chunk cursors ----
__global__ __launch_bounds__(1024) void scanC_k(int* __restrict__ partial,
                                                int* __restrict__ off_a,
                                                int* __restrict__ off_b,
                                                const int* __restrict__ bbase) {
    __shared__ int wsum[16];
    const int b = blockIdx.x;
    const int t = (b >= NB) ? 1 : 0;
    int* off = t ? off_b : off_a;
    const int base0 = bbase[b];
    const int i0 = (b % NB) * SCAN_CHUNK + threadIdx.x * 4;
    int4 s = make_int4(0, 0, 0, 0);
    if (i0 < NN) {
#pragma unroll
        for (int c = 0; c < C_CH; ++c) {
            int4 v = *reinterpret_cast<const int4*>(partial + (long)(t * C_CH + c) * NN + i0);
            s.x += v.x; s.y += v.y; s.z += v.z; s.w += v.w;
        }
    }
    int s1 = s.x, s2 = s1 + s.y, s3 = s2 + s.z, tot = s3 + s.w;
    int lane = threadIdx.x & 63, w = threadIdx.x >> 6;
    int inc = tot;
#pragma unroll
    for (int d = 1; d < 64; d <<= 1) {
        int x = __shfl_up(inc, d);
        if (lane >= d) inc += x;
    }
    if (lane == 63) wsum[w] = inc;
    int texcl = inc - tot;
    __syncthreads();
    if (threadIdx.x == 0) {
        int r = 0;
#pragma unroll
        for (int q = 0; q < 16; ++q) { int x = wsum[q]; wsum[q] = r; r += x; }
    }
    __syncthreads();
    const int base = base0 + wsum[w] + texcl;
    if (i0 < NN) {
        *reinterpret_cast<int4*>(off + i0) = make_int4(base, base + s1, base + s2, base + s3);
        int4 run = make_int4(base, base + s1, base + s2, base + s3);
#pragma unroll
        for (int c = 0; c < C_CH; ++c) {
            int* p = partial + (long)(t * C_CH + c) * NN + i0;
            int4 v = *reinterpret_cast<const int4*>(p);
            *reinterpret_cast<int4*>(p) = run;
            run.x += v.x; run.y += v.y; run.z += v.z; run.w += v.w;
        }
    }
}

// ------ scatter: LDS cursors (100KB), zero global atomics, XCD-aligned ------
// 128 blocks: q=bid&7 -> t=q>>2, p=q&3; c=bid>>3. bid%8 constant per (t,p)
// -> each csr range window written by ONE XCD.
__global__ __launch_bounds__(1024) void scatter_k(const int* __restrict__ dst_a,
                                                  const int* __restrict__ src_a,
                                                  const float* __restrict__ w_a,
                                                  const int* __restrict__ dst_b,
                                                  const int* __restrict__ src_b,
                                                  const float* __restrict__ w_b,
                                                  const int* __restrict__ partial,
                                                  int2* __restrict__ csr_a,
                                                  int2* __restrict__ csr_b) {
    __shared__ int curs[RSZ];          // 100 KB
    const int bid = blockIdx.x;
    const int q = bid & 7;
    const int t = q >> 2;
    const int p = q & 3;
    const int c = bid >> 3;
    const int* dst = t ? dst_b : dst_a;
    const int* src = t ? src_b : src_a;
    const float* wv = t ? w_b : w_a;
    int2* csr = t ? csr_b : csr_a;
    const int lo = p * RSZ;
    const int* pin = partial + (long)(t * C_CH + c) * NN + lo;
    for (int i = threadIdx.x; i < RSZ; i += 1024) curs[i] = pin[i];
    __syncthreads();
    const long base = (long)c * CHUNK_E;
    for (int i = threadIdx.x * 4; i < CHUNK_E; i += 4096) {
        int4 d = *reinterpret_cast<const int4*>(dst + base + i);
        int4 s = *reinterpret_cast<const int4*>(src + base + i);
        float4 w = *reinterpret_cast<const float4*>(wv + base + i);
        int x;
        x = d.x - lo;
        if ((unsigned)x < RSZ) {
            int pp = atomicAdd(&curs[x], 1);
            csr[pp] = make_int2(s.x, __float_as_int(w.x));
        }
        x = d.y - lo;
        if ((unsigned)x < RSZ) {
            int pp = atomicAdd(&curs[x], 1);
            csr[pp] = make_int2(s.y, __float_as_int(w.y));
        }
        x = d.z - lo;
        if ((unsigned)x < RSZ) {
            int pp = atomicAdd(&curs[x], 1);
            csr[pp] = make_int2(s.z, __float_as_int(w.z));
        }
        x = d.w - lo;
        if ((unsigned)x < RSZ) {
            int pp = atomicAdd(&curs[x], 1);
            csr[pp] = make_int2(s.w, __float_as_int(w.w));
        }
    }
}

// ---- pull1: h, gx, gy. bf16 gathers, fp32 accumulate. 32 lanes/node ----
__global__ __launch_bounds__(256) void pull1_k(const unsigned short* __restrict__ emh_bf,
                                               const unsigned short* __restrict__ ef_bf,
                                               const float* __restrict__ e_feat,
                                               const int2* __restrict__ csr_a,
                                               const int* __restrict__ off_a,
                                               const int2* __restrict__ csr_b,
                                               const int* __restrict__ off_b,
                                               float* __restrict__ out_h,
                                               float* __restrict__ gx,
                                               float* __restrict__ gy,
                                               unsigned short* __restrict__ gx_bf,
                                               unsigned short* __restrict__ gy_bf) {
    int g = blockIdx.x * 256 + threadIdx.x;
    int n = g >> 5, j = g & 31;
    if (n >= NN) return;
    float acc_h = 0.f;

#pragma unroll
    for (int half = 0; half < 2; ++half) {
        const int2* csr = half ? csr_b : csr_a;
        const int* off = half ? off_b : off_a;
        float* gout = half ? gy : gx;
        unsigned short* gbf = half ? gy_bf : gx_bf;
        float acc_g = 0.f, sumw = 0.f;
        int k = off[n], e2 = off[n + 1];
        for (; k + 3 < e2; k += 4) {
            int2 s0 = csr[k], s1 = csr[k + 1], s2 = csr[k + 2], s3 = csr[k + 3];
            float m0 = bf2f(emh_bf[(size_t)s0.x * 32 + j]);
            float m1 = bf2f(emh_bf[(size_t)s1.x * 32 + j]);
            float m2 = bf2f(emh_bf[(size_t)s2.x * 32 + j]);
            float m3 = bf2f(emh_bf[(size_t)s3.x * 32 + j]);
            acc_h += (m0 + m1) + (m2 + m3);
            if (j < 16) {
                float w0 = __int_as_float(s0.y), w1 = __int_as_float(s1.y);
                float w2 = __int_as_float(s2.y), w3 = __int_as_float(s3.y);
                acc_g = fmaf(w0, bf2f(ef_bf[(size_t)s0.x * 16 + j]), acc_g);
                acc_g = fmaf(w1, bf2f(ef_bf[(size_t)s1.x * 16 + j]), acc_g);
                acc_g = fmaf(w2, bf2f(ef_bf[(size_t)s2.x * 16 + j]), acc_g);
                acc_g = fmaf(w3, bf2f(ef_bf[(size_t)s3.x * 16 + j]), acc_g);
                sumw += (w0 + w1) + (w2 + w3);
            }
        }
        for (; k < e2; ++k) {
            int2 s0 = csr[k];
            acc_h += bf2f(emh_bf[(size_t)s0.x * 32 + j]);
            if (j < 16) {
                float w0 = __int_as_float(s0.y);
                acc_g = fmaf(w0, bf2f(ef_bf[(size_t)s0.x * 16 + j]), acc_g);
                sumw += w0;
            }
        }
        if (j < 16) {
            float val = acc_g - sumw * e_feat[(size_t)n * 16 + j];
            gout[(size_t)n * 16 + j] = val;
            gbf[(size_t)n * 16 + j] = f2bf(val);
        }
    }
    out_h[(size_t)n * 32 + j] = fmaxf(acc_h, 0.f);
}

// ---- pull2: g2x, g2y. bf16 gathers, fp32 own-node + accumulate. 16 lanes/node ----
__global__ __launch_bounds__(256) void pull2_k(const float* __restrict__ gx,
                                               const float* __restrict__ gy,
                                               const unsigned short* __restrict__ gx_bf,
                                               const unsigned short* __restrict__ gy_bf,
                                               const int2* __restrict__ csr_a,
                                               const int* __restrict__ off_a,
                                               const int2* __restrict__ csr_b,
                                               const int* __restrict__ off_b,
                                               float* __restrict__ g2x,
                                               float* __restrict__ g2y) {
    int g = blockIdx.x * 256 + threadIdx.x;
    int n = g >> 4, j = g & 15;
    if (n >= NN) return;

#pragma unroll
    for (int half = 0; half < 2; ++half) {
        const int2* csr = half ? csr_b : csr_a;
        const int* off = half ? off_b : off_a;
        const float* gin = half ? gy : gx;
        const unsigned short* gbf = half ? gy_bf : gx_bf;
        float* g2 = half ? g2y : g2x;
        float acc = 0.f, sumw = 0.f;
        int k = off[n], e2 = off[n + 1];
        for (; k + 3 < e2; k += 4) {
            int2 s0 = csr[k], s1 = csr[k + 1], s2 = csr[k + 2], s3 = csr[k + 3];
            float w0 = __int_as_float(s0.y), w1 = __int_as_float(s1.y);
            float w2 = __int_as_float(s2.y), w3 = __int_as_float(s3.y);
            acc = fmaf(w0, bf2f(gbf[(size_t)s0.x * 16 + j]), acc);
            acc = fmaf(w1, bf2f(gbf[(size_t)s1.x * 16 + j]), acc);
            acc = fmaf(w2, bf2f(gbf[(size_t)s2.x * 16 + j]), acc);
            acc = fmaf(w3, bf2f(gbf[(size_t)s3.x * 16 + j]), acc);
            sumw += (w0 + w1) + (w2 + w3);
        }
        for (; k < e2; ++k) {
            int2 s0 = csr[k];
            float w0 = __int_as_float(s0.y);
            acc = fmaf(w0, bf2f(gbf[(size_t)s0.x * 16 + j]), acc);
            sumw += w0;
        }
        g2[(size_t)n * 16 + j] = acc - sumw * gin[(size_t)n * 16 + j];
    }
}

// ---------------- final head: bf16 MFMA GEMM (64 nodes/block) ----------------
__global__ __launch_bounds__(256) void final_mfma_k(const float* __restrict__ h,
                                                    const float* __restrict__ gx,
                                                    const float* __restrict__ gy,
                                                    const float* __restrict__ g2x,
                                                    const float* __restrict__ g2y,
                                                    const float* __restrict__ rain0,
                                                    const float* __restrict__ W_rin,
                                                    const float* __restrict__ W_rout,
                                                    float* __restrict__ out_rain) {
    __shared__ __align__(16) unsigned short Wt[128 * AP];  // 26.6 KB
    __shared__ __align__(16) unsigned short At[64 * AP];   // 13.3 KB
    __shared__ float Wo[128];
    const int tid = threadIdx.x;

    for (int i = tid; i < 3072; i += 256) {
        int k = i >> 5;
        int c = (i & 31) * 4;
        float4 wv = *reinterpret_cast<const float4*>(W_rin + k * 128 + c);
        Wt[(c + 0) * AP + k] = f2bf(wv.x);
        Wt[(c + 1) * AP + k] = f2bf(wv.y);
        Wt[(c + 2) * AP + k] = f2bf(wv.z);
        Wt[(c + 3) * AP + k] = f2bf(wv.w);
    }
    if (tid < 128) Wo[tid] = W_rout[tid];

    {
        int n = tid >> 2, q = tid & 3;
        int node = blockIdx.x * 64 + n;
        float f[24];
#define LD4(di, p) { float4 v_ = *reinterpret_cast<const float4*>(p); \
                     f[di] = v_.x; f[di+1] = v_.y; f[di+2] = v_.z; f[di+3] = v_.w; }
        if (node < NN) {
            if (q == 0) {
                LD4(0,  h + (size_t)node * 32 + 0);
                LD4(4,  h + (size_t)node * 32 + 4);
                LD4(8,  h + (size_t)node * 32 + 8);
                LD4(12, h + (size_t)node * 32 + 12);
                LD4(16, h + (size_t)node * 32 + 16);
                LD4(20, h + (size_t)node * 32 + 20);
            } else if (q == 1) {
                LD4(0,  h + (size_t)node * 32 + 24);
                LD4(4,  h + (size_t)node * 32 + 28);
                LD4(8,  gx + (size_t)node * 16 + 0);
                LD4(12, gx + (size_t)node * 16 + 4);
                LD4(16, gx + (size_t)node * 16 + 8);
                LD4(20, gx + (size_t)node * 16 + 12);
            } else if (q == 2) {
                LD4(0,  gy + (size_t)node * 16 + 0);
                LD4(4,  gy + (size_t)node * 16 + 4);
                LD4(8,  gy + (size_t)node * 16 + 8);
                LD4(12, gy + (size_t)node * 16 + 12);
                LD4(16, g2x + (size_t)node * 16 + 0);
                LD4(20, g2x + (size_t)node * 16 + 4);
            } else {
                LD4(0,  g2x + (size_t)node * 16 + 8);
                LD4(4,  g2x + (size_t)node * 16 + 12);
                LD4(8,  g2y + (size_t)node * 16 + 0);
                LD4(12, g2y + (size_t)node * 16 + 4);
                LD4(16, g2y + (size_t)node * 16 + 8);
                LD4(20, g2y + (size_t)node * 16 + 12);
            }
        } else {
#pragma unroll
            for (int i = 0; i < 24; ++i) f[i] = 0.f;
        }
#undef LD4
        unsigned pk[12];
#pragma unroll
        for (int i = 0; i < 12; ++i)
            pk[i] = (unsigned)f2bf(f[2 * i]) | ((unsigned)f2bf(f[2 * i + 1]) << 16);
        char* dp = (char*)At + n * (AP * 2) + q * 48;
        *reinterpret_cast<uint4*>(dp + 0)  = make_uint4(pk[0], pk[1], pk[2], pk[3]);
        *reinterpret_cast<uint4*>(dp + 16) = make_uint4(pk[4], pk[5], pk[6], pk[7]);
        *reinterpret_cast<uint4*>(dp + 32) = make_uint4(pk[8], pk[9], pk[10], pk[11]);
    }
    __syncthreads();

    const int w = tid >> 6;
    const int l = tid & 63;
    const int col = l & 15;
    const int kg = l >> 4;
    const char* Ab = (const char*)At + (w * 16 + col) * (AP * 2) + kg * 16;
    const char* Bb = (const char*)Wt + col * (AP * 2) + kg * 16;

    f32x4 acc[8];
#pragma unroll
    for (int ct = 0; ct < 8; ++ct) acc[ct] = (f32x4){0.f, 0.f, 0.f, 0.f};

#pragma unroll
    for (int ks = 0; ks < 3; ++ks) {
        bf16x8 af = *reinterpret_cast<const bf16x8*>(Ab + ks * 64);
#pragma unroll
        for (int ct = 0; ct < 8; ++ct) {
            bf16x8 bfr = *reinterpret_cast<const bf16x8*>(Bb + ct * 16 * (AP * 2) + ks * 64);
            acc[ct] = __builtin_amdgcn_mfma_f32_16x16x32_bf16(af, bfr, acc[ct], 0, 0, 0);
        }
    }

    float s0 = 0.f, s1 = 0.f, s2 = 0.f, s3 = 0.f;
#pragma unroll
    for (int ct = 0; ct < 8; ++ct) {
        float wo = Wo[ct * 16 + col];
        s0 = fmaf(fmaxf(acc[ct][0], 0.f), wo, s0);
        s1 = fmaf(fmaxf(acc[ct][1], 0.f), wo, s1);
        s2 = fmaf(fmaxf(acc[ct][2], 0.f), wo, s2);
        s3 = fmaf(fmaxf(acc[ct][3], 0.f), wo, s3);
    }
#pragma unroll
    for (int m = 1; m < 16; m <<= 1) {
        s0 += __shfl_xor(s0, m);
        s1 += __shfl_xor(s1, m);
        s2 += __shfl_xor(s2, m);
        s3 += __shfl_xor(s3, m);
    }
    if (col == 0) {
        int row = blockIdx.x * 64 + w * 16 + kg * 4;
        if (row + 0 < NN) out_rain[row + 0] = rain0[row + 0] + s0;
        if (row + 1 < NN) out_rain[row + 1] = rain0[row + 1] + s1;
        if (row + 2 < NN) out_rain[row + 2] = rain0[row + 2] + s2;
        if (row + 3 < NN) out_rain[row + 3] = rain0[row + 3] + s3;
    }
}

extern "C" void kernel_launch(void* const* d_in, const int* in_sizes, int n_in,
                              void* d_out, int out_size, void* d_ws, size_t ws_size,
                              hipStream_t stream) {
    const float* h_feat  = (const float*)d_in[0];
    const float* e_feat  = (const float*)d_in[1];
    const float* rain0   = (const float*)d_in[2];
    const float* w_xx    = (const float*)d_in[3];
    const float* w_yy    = (const float*)d_in[4];
    const float* W_trans = (const float*)d_in[5];
    const float* W_rin   = (const float*)d_in[6];
    const float* W_rout  = (const float*)d_in[7];
    const int* src_xx    = (const int*)d_in[8];
    const int* dst_xx    = (const int*)d_in[9];
    const int* src_yy    = (const int*)d_in[10];
    const int* dst_yy    = (const int*)d_in[11];

    // ws layout:
    unsigned short* emh_bf = (unsigned short*)d_ws;            // NN*32 bf16 = 6.4MB
    unsigned short* ef_bf  = emh_bf + (size_t)NN * 32;         // 3.2MB
    unsigned short* gx_bf  = ef_bf + (size_t)NN * 16;          // 3.2MB
    unsigned short* gy_bf  = gx_bf + (size_t)NN * 16;          // 3.2MB
    float* gx = (float*)(gy_bf + (size_t)NN * 16);             // 6.4MB
    float* gy = gx + (size_t)NN * 16;                          // 6.4MB
    int2* csr_xx = (int2*)(gy + (size_t)NN * 16);              // 12.8MB
    int2* csr_yy = csr_xx + EE;                                // 12.8MB
    int* off_xx  = (int*)(csr_yy + EE);                        // OFFP ints
    int* off_yy  = off_xx + OFFP;                              // OFFP ints
    int* partial = off_yy + OFFP;                              // 2*C_CH*NN ints (12.8MB)
    float* g2x   = (float*)partial;                            // alias (partial dead after scatter)
    float* g2y   = g2x + (size_t)NN * 16;
    int* bsum    = partial + (size_t)2 * C_CH * NN;            // 64
    int* bbase   = bsum + 64;                                  // 64

    float* out_rain = (float*)d_out;           // NN
    float* out_h    = out_rain + NN;           // NN*32

    const int TB = (NN * 32 + 1023) / 1024;                    // 3125 trans blocks
    const int HB = 2 * NRANGE * C_CH;                          // 128 hist blocks
    fused_th_k<<<TB + HB, 1024, 0, stream>>>(h_feat, e_feat, W_trans, emh_bf, ef_bf,
                                             dst_xx, dst_yy, partial, TB);

    scanA_k<<<2 * NB, 1024, 0, stream>>>(partial, bsum);
    scanB_k<<<1, 64, 0, stream>>>(bsum, bbase, off_xx, off_yy);
    scanC_k<<<2 * NB, 1024, 0, stream>>>(partial, off_xx, off_yy, bbase);

    scatter_k<<<2 * NRANGE * C_CH, 1024, 0, stream>>>(
        dst_xx, src_xx, w_xx, dst_yy, src_yy, w_yy, partial, csr_xx, csr_yy);

    pull1_k<<<(NN * 32 + 255) / 256, 256, 0, stream>>>(
        emh_bf, ef_bf, e_feat, csr_xx, off_xx, csr_yy, off_yy,
        out_h, gx, gy, gx_bf, gy_bf);

    pull2_k<<<(NN * 16 + 255) / 256, 256, 0, stream>>>(
        gx, gy, gx_bf, gy_bf, csr_xx, off_xx, csr_yy, off_yy, g2x, g2y);

    final_mfma_k<<<(NN + 63) / 64, 256, 0, stream>>>(
        out_h, gx, gy, g2x, g2y, rain0, W_rin, W_rout, out_rain);
}